// Round 1
// baseline (689.852 us; speedup 1.0000x reference)
//
#include <hip/hip_runtime.h>

// ---------------- GEMM: C[M,NO] = op(A[M,K]) @ B[K,NO] (+bias) ----------------
constexpr int TM = 64, TN = 64, KTILE = 32;

__global__ __launch_bounds__(256) void gemm_tiled(
    const float* __restrict__ A, const float* __restrict__ B,
    const float* __restrict__ bias, float* __restrict__ C,
    int M, int K, int NO, int leakyA)
{
  __shared__ float As[KTILE][TM];
  __shared__ float Bs[KTILE][TN + 1];
  const int tid  = threadIdx.x;
  const int row0 = blockIdx.x * TM, col0 = blockIdx.y * TN;
  const int tr = (tid >> 4) << 2;   // 0..60
  const int tc = (tid & 15) << 2;   // 0..60
  float acc[4][4] = {};

  for (int k0 = 0; k0 < K; k0 += KTILE) {
#pragma unroll
    for (int i = 0; i < 8; ++i) {            // A tile 64x32
      int idx = tid + i * 256;
      int kk = idx & 31, mm = idx >> 5;
      int gr = row0 + mm;
      float v = (gr < M) ? A[(size_t)gr * K + k0 + kk] : 0.f;
      if (leakyA) v = v >= 0.f ? v : 0.2f * v;
      As[kk][mm] = v;
    }
#pragma unroll
    for (int i = 0; i < 8; ++i) {            // B tile 32x64
      int idx = tid + i * 256;
      int nn = idx & 63, kk = idx >> 6;
      Bs[kk][nn] = B[(size_t)(k0 + kk) * NO + col0 + nn];
    }
    __syncthreads();
#pragma unroll
    for (int k = 0; k < KTILE; ++k) {
      float a0 = As[k][tr + 0], a1 = As[k][tr + 1], a2 = As[k][tr + 2], a3 = As[k][tr + 3];
      float b0 = Bs[k][tc + 0], b1 = Bs[k][tc + 1], b2 = Bs[k][tc + 2], b3 = Bs[k][tc + 3];
      acc[0][0] += a0 * b0; acc[0][1] += a0 * b1; acc[0][2] += a0 * b2; acc[0][3] += a0 * b3;
      acc[1][0] += a1 * b0; acc[1][1] += a1 * b1; acc[1][2] += a1 * b2; acc[1][3] += a1 * b3;
      acc[2][0] += a2 * b0; acc[2][1] += a2 * b1; acc[2][2] += a2 * b2; acc[2][3] += a2 * b3;
      acc[3][0] += a3 * b0; acc[3][1] += a3 * b1; acc[3][2] += a3 * b2; acc[3][3] += a3 * b3;
    }
    __syncthreads();
  }
#pragma unroll
  for (int i = 0; i < 4; ++i) {
    int gr = row0 + tr + i;
    if (gr < M) {
#pragma unroll
      for (int j = 0; j < 4; ++j) {
        int gc = col0 + tc + j;
        float v = acc[i][j];
        if (bias) v += bias[gc];
        C[(size_t)gr * NO + gc] = v;
      }
    }
  }
}

// ---------------- CSR build (shared by both conv layers) ----------------
__global__ void count_k(const int* __restrict__ ei, int E, int* __restrict__ cnt) {
  int e = blockIdx.x * 256 + threadIdx.x;
  if (e < E) atomicAdd(&cnt[ei[E + e]], 1);
}

__global__ __launch_bounds__(1024) void scan_block(const int* __restrict__ cnt,
                                                   int* __restrict__ off,
                                                   int* __restrict__ bsum, int n) {
  __shared__ int sh[1024];
  int i = blockIdx.x * 1024 + threadIdx.x;
  int v = (i < n) ? cnt[i] : 0;
  sh[threadIdx.x] = v;
  __syncthreads();
  for (int o = 1; o < 1024; o <<= 1) {
    int t = (threadIdx.x >= o) ? sh[threadIdx.x - o] : 0;
    __syncthreads();
    sh[threadIdx.x] += t;
    __syncthreads();
  }
  if (i < n) off[i] = sh[threadIdx.x] - v;  // local exclusive
  if (threadIdx.x == 1023) bsum[blockIdx.x] = sh[1023];
}

__global__ void scan_partials(int* __restrict__ bsum, int nb, int* __restrict__ off, int n) {
  int run = 0;
  for (int b = 0; b < nb; ++b) { int t = bsum[b]; bsum[b] = run; run += t; }
  off[n] = run;
}

__global__ __launch_bounds__(1024) void scan_add(int* __restrict__ off, int* __restrict__ cursor,
                                                 const int* __restrict__ bsum, int n) {
  int i = blockIdx.x * 1024 + threadIdx.x;
  if (i < n) { int v = off[i] + bsum[blockIdx.x]; off[i] = v; cursor[i] = v; }
}

__global__ void scatter_k(const int* __restrict__ ei, int E,
                          int* __restrict__ cursor, int* __restrict__ csr) {
  int e = blockIdx.x * 256 + threadIdx.x;
  if (e < E) {
    int d = ei[E + e];
    int p = atomicAdd(&cursor[d], 1);
    csr[p] = ei[e];
  }
}

// ---------------- attention coefficient dots ----------------
// conv1: wave per node; lane l owns channels 2l,2l+1; head h = l>>4.
__global__ __launch_bounds__(256) void att1_k(const float* __restrict__ h1,
                                              const float* __restrict__ att_s,
                                              const float* __restrict__ att_d,
                                              float* __restrict__ a_s, float* __restrict__ a_d, int n) {
  int w = threadIdx.x >> 6, l = threadIdx.x & 63;
  int node = blockIdx.x * 4 + w;
  if (node >= n) return;
  int h = l >> 4;
  int c = l * 2;
  float2 v  = *(const float2*)&h1[(size_t)node * 128 + c];
  float2 as = *(const float2*)&att_s[h * 32 + (c & 31)];
  float2 ad = *(const float2*)&att_d[h * 32 + (c & 31)];
  float ps = v.x * as.x + v.y * as.y;
  float pd = v.x * ad.x + v.y * ad.y;
  for (int o = 1; o < 16; o <<= 1) { ps += __shfl_xor(ps, o, 64); pd += __shfl_xor(pd, o, 64); }
  if ((l & 15) == 0) { a_s[node * 4 + h] = ps; a_d[node * 4 + h] = pd; }
}

// conv2: wave per node; lane = channel (64).
__global__ __launch_bounds__(256) void att2_k(const float* __restrict__ h2,
                                              const float* __restrict__ att_s,
                                              const float* __restrict__ att_d,
                                              float* __restrict__ a_s, float* __restrict__ a_d, int n) {
  int w = threadIdx.x >> 6, l = threadIdx.x & 63;
  int node = blockIdx.x * 4 + w;
  if (node >= n) return;
  float v = h2[(size_t)node * 64 + l];
  float ps = v * att_s[l], pd = v * att_d[l];
  for (int o = 1; o < 64; o <<= 1) { ps += __shfl_xor(ps, o, 64); pd += __shfl_xor(pd, o, 64); }
  if (l == 0) { a_s[node] = ps; a_d[node] = pd; }
}

// ---------------- aggregation: wave per dst, single-pass online softmax ----------------
__global__ __launch_bounds__(256) void aggr1_k(const float* __restrict__ h1,
                                               const float* __restrict__ xres,
                                               const float* __restrict__ a_s,
                                               const float* __restrict__ a_d,
                                               const int* __restrict__ off,
                                               const int* __restrict__ csr,
                                               const float* __restrict__ b1,
                                               float* __restrict__ hpre, int n) {
  int w = threadIdx.x >> 6, l = threadIdx.x & 63;
  int d = blockIdx.x * 4 + w;
  if (d >= n) return;
  int h = l >> 4;
  int c = l * 2;
  float adh = a_d[d * 4 + h];
  float m = -3e38f, lsum = 0.f;
  float accx = 0.f, accy = 0.f;
  int s0 = off[d], s1 = off[d + 1];
  for (int p = s0; p <= s1; ++p) {               // p == s1 -> self loop
    int s = (p < s1) ? csr[p] : d;
    float a = a_s[s * 4 + h] + adh;
    a = a >= 0.f ? a : 0.2f * a;
    float mn = fmaxf(m, a);
    float sc = __expf(m - mn);
    float pe = __expf(a - mn);
    lsum = lsum * sc + pe;
    float2 hv = *(const float2*)&h1[(size_t)s * 128 + c];
    accx = accx * sc + pe * hv.x;
    accy = accy * sc + pe * hv.y;
    m = mn;
  }
  float inv = 1.f / (lsum + 1e-16f);
  float2 xr = *(const float2*)&xres[(size_t)d * 128 + c];
  hpre[(size_t)d * 128 + c]     = accx * inv + b1[c]     + xr.x;
  hpre[(size_t)d * 128 + c + 1] = accy * inv + b1[c + 1] + xr.y;
}

__global__ __launch_bounds__(256) void aggr2_k(const float* __restrict__ h2,
                                               const float* __restrict__ hres,
                                               const float* __restrict__ a_s,
                                               const float* __restrict__ a_d,
                                               const int* __restrict__ off,
                                               const int* __restrict__ csr,
                                               const float* __restrict__ b2,
                                               float* __restrict__ out, int n) {
  int w = threadIdx.x >> 6, l = threadIdx.x & 63;
  int d = blockIdx.x * 4 + w;
  if (d >= n) return;
  float adh = a_d[d];
  float m = -3e38f, lsum = 0.f, acc = 0.f;
  int s0 = off[d], s1 = off[d + 1];
  for (int p = s0; p <= s1; ++p) {
    int s = (p < s1) ? csr[p] : d;
    float a = a_s[s] + adh;
    a = a >= 0.f ? a : 0.2f * a;
    float mn = fmaxf(m, a);
    float sc = __expf(m - mn);
    float pe = __expf(a - mn);
    lsum = lsum * sc + pe;
    acc = acc * sc + pe * h2[(size_t)s * 64 + l];
    m = mn;
  }
  float inv = 1.f / (lsum + 1e-16f);
  float z = acc * inv + b2[l] + hres[(size_t)d * 64 + l];
  out[(size_t)d * 64 + l] = z >= 0.f ? z : 0.2f * z;
}

// ---------------- launch ----------------
extern "C" void kernel_launch(void* const* d_in, const int* in_sizes, int n_in,
                              void* d_out, int out_size, void* d_ws, size_t ws_size,
                              hipStream_t stream) {
  const float* x        = (const float*)d_in[0];
  const int*   ei       = (const int*)d_in[1];
  const float* W1       = (const float*)d_in[2];
  const float* att_src1 = (const float*)d_in[3];
  const float* att_dst1 = (const float*)d_in[4];
  const float* b1       = (const float*)d_in[5];
  const float* W2       = (const float*)d_in[6];
  const float* att_src2 = (const float*)d_in[7];
  const float* att_dst2 = (const float*)d_in[8];
  const float* b2       = (const float*)d_in[9];
  const float* res1_w   = (const float*)d_in[10];
  const float* res1_b   = (const float*)d_in[11];
  const float* fc_w     = (const float*)d_in[12];
  const float* fc_b     = (const float*)d_in[13];
  float* out = (float*)d_out;

  const int N = in_sizes[0] / 256;
  const int E = in_sizes[1] / 2;

  // workspace layout
  float* ws   = (float*)d_ws;
  float* h1   = ws;                          // N*128
  float* xres = h1   + (size_t)N * 128;      // N*128
  float* hpre = xres + (size_t)N * 128;      // N*128
  float* as1  = hpre + (size_t)N * 128;      // N*4
  float* ad1  = as1  + (size_t)N * 4;        // N*4
  // aliases (valid after conv1 consumers finish)
  float* h2   = h1;     // N*64
  float* hres = xres;   // N*64
  float* as2  = as1;    // N
  float* ad2  = ad1;    // N
  int* ip     = (int*)(ad1 + (size_t)N * 4);
  int* cnt    = ip;               // N
  int* offp   = cnt + N;          // N+1
  int* cursor = offp + N + 1;     // N
  int* csr    = cursor + N;       // E
  int* bsum   = csr + E;          // 64

  const int nb = (N + 1023) / 1024;

  // ---- CSR build (once; both layers share the graph) ----
  hipMemsetAsync(cnt, 0, (size_t)N * 4, stream);
  count_k<<<(E + 255) / 256, 256, 0, stream>>>(ei, E, cnt);
  scan_block<<<nb, 1024, 0, stream>>>(cnt, offp, bsum, N);
  scan_partials<<<1, 1, 0, stream>>>(bsum, nb, offp, N);
  scan_add<<<nb, 1024, 0, stream>>>(offp, cursor, bsum, N);
  scatter_k<<<(E + 255) / 256, 256, 0, stream>>>(ei, E, cursor, csr);

  const int mblk = (N + TM - 1) / TM;

  // ---- layer 1 GEMMs ----
  gemm_tiled<<<dim3(mblk, 2), 256, 0, stream>>>(x, W1, nullptr, h1, N, 256, 128, 0);
  gemm_tiled<<<dim3(mblk, 2), 256, 0, stream>>>(x, res1_w, res1_b, xres, N, 256, 128, 0);

  // ---- conv1 attention + aggregation ----
  att1_k<<<(N + 3) / 4, 256, 0, stream>>>(h1, att_src1, att_dst1, as1, ad1, N);
  aggr1_k<<<(N + 3) / 4, 256, 0, stream>>>(h1, xres, as1, ad1, offp, csr, b1, hpre, N);

  // ---- layer 2 GEMMs (h2 = leaky(hpre)@W2 ; hres = hpre@fc_w + fc_b) ----
  gemm_tiled<<<dim3(mblk, 1), 256, 0, stream>>>(hpre, fc_w, fc_b, hres, N, 128, 64, 0);
  gemm_tiled<<<dim3(mblk, 1), 256, 0, stream>>>(hpre, W2, nullptr, h2, N, 128, 64, 1);

  // ---- conv2 attention + aggregation (writes final output) ----
  att2_k<<<(N + 3) / 4, 256, 0, stream>>>(h2, att_src2, att_dst2, as2, ad2, N);
  aggr2_k<<<(N + 3) / 4, 256, 0, stream>>>(h2, hres, as2, ad2, offp, csr, b2, out, N);
}

// Round 2
// 414.900 us; speedup vs baseline: 1.6627x; 1.6627x over previous
//
#include <hip/hip_runtime.h>

typedef __attribute__((ext_vector_type(8))) short short8;
typedef __attribute__((ext_vector_type(4))) float f32x4;

__device__ __forceinline__ ushort rne_bf16(float f) {
  uint u = __float_as_uint(f);
  uint r = (u + 0x7FFFu + ((u >> 16) & 1u)) >> 16;
  return (ushort)r;
}
__device__ __forceinline__ float bf16_lo(uint pair) { return __uint_as_float(pair << 16); }
__device__ __forceinline__ float bf16_hi(uint pair) { return __uint_as_float(pair & 0xffff0000u); }

// ---------------- casts / weight prep ----------------
__global__ __launch_bounds__(256) void cast_bf16_k(const float* __restrict__ in,
                                                   ushort* __restrict__ out, long n) {
  long i = ((long)blockIdx.x * 256 + threadIdx.x) * 8;
  if (i >= n) return;
  float4 a = *(const float4*)&in[i];
  float4 b = *(const float4*)&in[i + 4];
  ushort o[8] = {rne_bf16(a.x), rne_bf16(a.y), rne_bf16(a.z), rne_bf16(a.w),
                 rne_bf16(b.x), rne_bf16(b.y), rne_bf16(b.z), rne_bf16(b.w)};
  *(uint4*)&out[i] = *(const uint4*)o;
}

// out[n*K+k] = bf16(in[k*NO+n])  (B transposed to N-major for MFMA staging)
__global__ __launch_bounds__(256) void transpose_cast_k(const float* __restrict__ in,
                                                        ushort* __restrict__ out, int K, int NO) {
  int i = blockIdx.x * 256 + threadIdx.x;
  if (i >= K * NO) return;
  int n = i / K, k = i % K;
  out[i] = rne_bf16(in[(size_t)k * NO + n]);
}

// ---------------- bf16 MFMA GEMM: C[M,NO] = A[M,K] @ Bt[NO,K]^T ----------------
// BM=128, BK=64, 4 waves in 2x2; wave covers 64 x (BN/2).
// MODE 0: NO=256 split -> cols<128 to h1_bf (ushort), cols>=128 to xres f32 (+bias)
// MODE 1: f32 out + bias
// MODE 2: bf16 out (ushort)
template<int BN, int MODE>
__global__ __launch_bounds__(256) void mfma_gemm(
    const ushort* __restrict__ Abf, const ushort* __restrict__ Btb,
    const float* __restrict__ bias, void* __restrict__ out0,
    float* __restrict__ out1, int M, int K)
{
  constexpr int BM = 128, BK = 64;
  constexpr int LDA = BK + 8;              // +16B pad: kills bank conflicts
  constexpr int WN = BN / 2;
  constexpr int NREP = WN / 16;
  constexpr int B_ISS = BN / 32;
  __shared__ ushort As[BM * LDA];
  __shared__ ushort Bs[BN * LDA];

  const int tid = threadIdx.x;
  const int w = tid >> 6, l = tid & 63;
  const int wr = w >> 1, wc = w & 1;
  const int row0 = blockIdx.x * BM, col0 = blockIdx.y * BN;
  const int l15 = l & 15, lg = l >> 4;

  f32x4 acc[4][NREP] = {};

  for (int k0 = 0; k0 < K; k0 += BK) {
    float4 ra[4], rb[B_ISS];
#pragma unroll
    for (int i = 0; i < 4; ++i) {
      int ci = i * 256 + tid, row = ci >> 3, ch = ci & 7;
      int gr = row0 + row; if (gr >= M) gr = M - 1;
      ra[i] = *(const float4*)(Abf + (size_t)gr * K + k0 + ch * 8);
    }
#pragma unroll
    for (int i = 0; i < B_ISS; ++i) {
      int ci = i * 256 + tid, row = ci >> 3, ch = ci & 7;
      rb[i] = *(const float4*)(Btb + (size_t)(col0 + row) * K + k0 + ch * 8);
    }
    __syncthreads();
#pragma unroll
    for (int i = 0; i < 4; ++i) {
      int ci = i * 256 + tid, row = ci >> 3, ch = ci & 7;
      *(float4*)&As[row * LDA + ch * 8] = ra[i];
    }
#pragma unroll
    for (int i = 0; i < B_ISS; ++i) {
      int ci = i * 256 + tid, row = ci >> 3, ch = ci & 7;
      *(float4*)&Bs[row * LDA + ch * 8] = rb[i];
    }
    __syncthreads();

    short8 aF[4][2], bF[NREP][2];
#pragma unroll
    for (int m = 0; m < 4; ++m)
#pragma unroll
      for (int kk = 0; kk < 2; ++kk)
        aF[m][kk] = *(const short8*)&As[(wr * 64 + m * 16 + l15) * LDA + kk * 32 + lg * 8];
#pragma unroll
    for (int n = 0; n < NREP; ++n)
#pragma unroll
      for (int kk = 0; kk < 2; ++kk)
        bF[n][kk] = *(const short8*)&Bs[(wc * WN + n * 16 + l15) * LDA + kk * 32 + lg * 8];
#pragma unroll
    for (int m = 0; m < 4; ++m)
#pragma unroll
      for (int n = 0; n < NREP; ++n)
#pragma unroll
        for (int kk = 0; kk < 2; ++kk)
          acc[m][n] = __builtin_amdgcn_mfma_f32_16x16x32_bf16(aF[m][kk], bF[n][kk], acc[m][n], 0, 0, 0);
    __syncthreads();
  }

#pragma unroll
  for (int m = 0; m < 4; ++m) {
#pragma unroll
    for (int n = 0; n < NREP; ++n) {
#pragma unroll
      for (int j = 0; j < 4; ++j) {
        int gr = row0 + wr * 64 + m * 16 + lg * 4 + j;
        if (gr >= M) continue;
        int gc = col0 + wc * WN + n * 16 + l15;
        float v = acc[m][n][j];
        if (MODE == 0) {
          if (gc < 128) ((ushort*)out0)[(size_t)gr * 128 + gc] = rne_bf16(v);
          else          out1[(size_t)gr * 128 + gc - 128] = v + bias[gc - 128];
        } else if (MODE == 1) {
          ((float*)out0)[(size_t)gr * 64 + gc] = v + bias[gc];
        } else {
          ((ushort*)out0)[(size_t)gr * 64 + gc] = rne_bf16(v);
        }
      }
    }
  }
}

// ---------------- CSR build ----------------
__global__ void count_k(const int* __restrict__ ei, int E, int* __restrict__ cnt) {
  int e = blockIdx.x * 256 + threadIdx.x;
  if (e < E) atomicAdd(&cnt[ei[E + e]], 1);
}

__global__ __launch_bounds__(1024) void scan_block(const int* __restrict__ cnt,
                                                   int* __restrict__ off,
                                                   int* __restrict__ bsum, int n) {
  __shared__ int sh[1024];
  int i = blockIdx.x * 1024 + threadIdx.x;
  int v = (i < n) ? cnt[i] : 0;
  sh[threadIdx.x] = v;
  __syncthreads();
  for (int o = 1; o < 1024; o <<= 1) {
    int t = (threadIdx.x >= o) ? sh[threadIdx.x - o] : 0;
    __syncthreads();
    sh[threadIdx.x] += t;
    __syncthreads();
  }
  if (i < n) off[i] = sh[threadIdx.x] - v;
  if (threadIdx.x == 1023) bsum[blockIdx.x] = sh[1023];
}

__global__ void scan_partials(int* __restrict__ bsum, int nb, int* __restrict__ off, int n) {
  int run = 0;
  for (int b = 0; b < nb; ++b) { int t = bsum[b]; bsum[b] = run; run += t; }
  off[n] = run;
}

__global__ __launch_bounds__(1024) void scan_add(int* __restrict__ off, int* __restrict__ cursor,
                                                 const int* __restrict__ bsum, int n) {
  int i = blockIdx.x * 1024 + threadIdx.x;
  if (i < n) { int v = off[i] + bsum[blockIdx.x]; off[i] = v; cursor[i] = v; }
}

__global__ void scatter_k(const int* __restrict__ ei, int E,
                          int* __restrict__ cursor, int* __restrict__ csr) {
  int e = blockIdx.x * 256 + threadIdx.x;
  if (e < E) {
    int d = ei[E + e];
    int p = atomicAdd(&cursor[d], 1);
    csr[p] = ei[e];
  }
}

// ---------------- attention dots (bf16 features) ----------------
__global__ __launch_bounds__(256) void att1_k(const uint* __restrict__ h1u,
                                              const float* __restrict__ att_s,
                                              const float* __restrict__ att_d,
                                              float* __restrict__ a_s, float* __restrict__ a_d, int n) {
  int w = threadIdx.x >> 6, l = threadIdx.x & 63;
  int node = blockIdx.x * 4 + w;
  if (node >= n) return;
  int h = l >> 4, c = l * 2;
  uint pair = h1u[(size_t)node * 64 + l];
  float vx = bf16_lo(pair), vy = bf16_hi(pair);
  float2 as = *(const float2*)&att_s[h * 32 + (c & 31)];
  float2 ad = *(const float2*)&att_d[h * 32 + (c & 31)];
  float ps = vx * as.x + vy * as.y;
  float pd = vx * ad.x + vy * ad.y;
  for (int o = 1; o < 16; o <<= 1) { ps += __shfl_xor(ps, o, 64); pd += __shfl_xor(pd, o, 64); }
  if ((l & 15) == 0) { a_s[node * 4 + h] = ps; a_d[node * 4 + h] = pd; }
}

__global__ __launch_bounds__(256) void att2_k(const ushort* __restrict__ h2b,
                                              const float* __restrict__ att_s,
                                              const float* __restrict__ att_d,
                                              float* __restrict__ a_s, float* __restrict__ a_d, int n) {
  int w = threadIdx.x >> 6, l = threadIdx.x & 63;
  int node = blockIdx.x * 4 + w;
  if (node >= n) return;
  float v = __uint_as_float((uint)h2b[(size_t)node * 64 + l] << 16);
  float ps = v * att_s[l], pd = v * att_d[l];
  for (int o = 1; o < 64; o <<= 1) { ps += __shfl_xor(ps, o, 64); pd += __shfl_xor(pd, o, 64); }
  if (l == 0) { a_s[node] = ps; a_d[node] = pd; }
}

// ---------------- aggregation: wave per dst, single-pass online softmax ----------------
__global__ __launch_bounds__(256) void aggr1_k(const uint* __restrict__ h1u,
                                               const float* __restrict__ xres,
                                               const float* __restrict__ a_s,
                                               const float* __restrict__ a_d,
                                               const int* __restrict__ off,
                                               const int* __restrict__ csr,
                                               const float* __restrict__ b1,
                                               uint* __restrict__ hpre_bf,
                                               uint* __restrict__ hlk_bf, int n) {
  int w = threadIdx.x >> 6, l = threadIdx.x & 63;
  int d = blockIdx.x * 4 + w;
  if (d >= n) return;
  int h = l >> 4, c = l * 2;
  float adh = a_d[d * 4 + h];
  float m = -3e38f, lsum = 0.f, accx = 0.f, accy = 0.f;
  int s0 = off[d], s1 = off[d + 1];
  for (int p = s0; p <= s1; ++p) {               // p == s1 -> self loop
    int s = (p < s1) ? csr[p] : d;
    float a = a_s[s * 4 + h] + adh;
    a = a >= 0.f ? a : 0.2f * a;
    float mn = fmaxf(m, a);
    float sc = __expf(m - mn);
    float pe = __expf(a - mn);
    lsum = lsum * sc + pe;
    uint pair = h1u[(size_t)s * 64 + l];
    accx = accx * sc + pe * bf16_lo(pair);
    accy = accy * sc + pe * bf16_hi(pair);
    m = mn;
  }
  float inv = 1.f / (lsum + 1e-16f);
  float2 xr = *(const float2*)&xres[(size_t)d * 128 + c];
  float vx = accx * inv + b1[c] + xr.x;
  float vy = accy * inv + b1[c + 1] + xr.y;
  hpre_bf[(size_t)d * 64 + l] = (uint)rne_bf16(vx) | ((uint)rne_bf16(vy) << 16);
  float lx = vx >= 0.f ? vx : 0.2f * vx;
  float ly = vy >= 0.f ? vy : 0.2f * vy;
  hlk_bf[(size_t)d * 64 + l] = (uint)rne_bf16(lx) | ((uint)rne_bf16(ly) << 16);
}

__global__ __launch_bounds__(256) void aggr2_k(const ushort* __restrict__ h2b,
                                               const float* __restrict__ hres,
                                               const float* __restrict__ a_s,
                                               const float* __restrict__ a_d,
                                               const int* __restrict__ off,
                                               const int* __restrict__ csr,
                                               const float* __restrict__ b2,
                                               float* __restrict__ out, int n) {
  int w = threadIdx.x >> 6, l = threadIdx.x & 63;
  int d = blockIdx.x * 4 + w;
  if (d >= n) return;
  float adh = a_d[d];
  float m = -3e38f, lsum = 0.f, acc = 0.f;
  int s0 = off[d], s1 = off[d + 1];
  for (int p = s0; p <= s1; ++p) {
    int s = (p < s1) ? csr[p] : d;
    float a = a_s[s] + adh;
    a = a >= 0.f ? a : 0.2f * a;
    float mn = fmaxf(m, a);
    float sc = __expf(m - mn);
    float pe = __expf(a - mn);
    lsum = lsum * sc + pe;
    acc = acc * sc + pe * __uint_as_float((uint)h2b[(size_t)s * 64 + l] << 16);
    m = mn;
  }
  float inv = 1.f / (lsum + 1e-16f);
  float z = acc * inv + b2[l] + hres[(size_t)d * 64 + l];
  out[(size_t)d * 64 + l] = z >= 0.f ? z : 0.2f * z;
}

// ---------------- launch ----------------
extern "C" void kernel_launch(void* const* d_in, const int* in_sizes, int n_in,
                              void* d_out, int out_size, void* d_ws, size_t ws_size,
                              hipStream_t stream) {
  const float* x        = (const float*)d_in[0];
  const int*   ei       = (const int*)d_in[1];
  const float* W1       = (const float*)d_in[2];
  const float* att_src1 = (const float*)d_in[3];
  const float* att_dst1 = (const float*)d_in[4];
  const float* b1       = (const float*)d_in[5];
  const float* W2       = (const float*)d_in[6];
  const float* att_src2 = (const float*)d_in[7];
  const float* att_dst2 = (const float*)d_in[8];
  const float* b2       = (const float*)d_in[9];
  const float* res1_w   = (const float*)d_in[10];
  const float* res1_b   = (const float*)d_in[11];
  const float* fc_w     = (const float*)d_in[12];
  const float* fc_b     = (const float*)d_in[13];
  float* out = (float*)d_out;

  const int N = in_sizes[0] / 256;
  const int E = in_sizes[1] / 2;

  // workspace layout (bf16-centric; aliases exploit stream ordering)
  ushort* x_bf  = (ushort*)d_ws;                 // N*256 bf16
  ushort* h1bf  = x_bf + (size_t)N * 256;        // N*128 bf16
  float*  xres  = (float*)(h1bf + (size_t)N * 128);  // N*128 f32
  float*  as1   = xres + (size_t)N * 128;        // N*4
  float*  ad1   = as1 + (size_t)N * 4;           // N*4
  ushort* Wt1   = (ushort*)(ad1 + (size_t)N * 4);// 256*256
  ushort* fcT   = Wt1 + 256 * 256;               // 64*128
  ushort* W2T   = fcT + 64 * 128;                // 64*128
  int* cnt      = (int*)(W2T + 64 * 128);        // N
  int* offp     = cnt + N;                       // N+1
  int* cursor   = offp + N + 1;                  // N
  int* csr      = cursor + N;                    // E
  int* bsum     = csr + E;                       // 64
  // aliases (regions dead by the time these are written)
  uint*   hpre_bf = (uint*)x_bf;                 // N*64 uints (N*128 bf16)
  uint*   hlk_bf  = (uint*)(x_bf + (size_t)N * 128);
  ushort* h2bf    = h1bf;                        // N*64 bf16
  float*  hres    = xres;                        // N*64 f32
  float*  as2 = as1, *ad2 = ad1;

  const int nb = (N + 1023) / 1024;
  const int mblk = (N + 127) / 128;

  // ---- casts + weight prep ----
  cast_bf16_k<<<(N * 256 / 8 + 255) / 256, 256, 0, stream>>>(x, x_bf, (long)N * 256);
  transpose_cast_k<<<(256 * 128 + 255) / 256, 256, 0, stream>>>(W1, Wt1, 256, 128);
  transpose_cast_k<<<(256 * 128 + 255) / 256, 256, 0, stream>>>(res1_w, Wt1 + 128 * 256, 256, 128);
  transpose_cast_k<<<(128 * 64 + 255) / 256, 256, 0, stream>>>(fc_w, fcT, 128, 64);
  transpose_cast_k<<<(128 * 64 + 255) / 256, 256, 0, stream>>>(W2, W2T, 128, 64);

  // ---- CSR build (shared by both layers) ----
  hipMemsetAsync(cnt, 0, (size_t)N * 4, stream);
  count_k<<<(E + 255) / 256, 256, 0, stream>>>(ei, E, cnt);
  scan_block<<<nb, 1024, 0, stream>>>(cnt, offp, bsum, N);
  scan_partials<<<1, 1, 0, stream>>>(bsum, nb, offp, N);
  scan_add<<<nb, 1024, 0, stream>>>(offp, cursor, bsum, N);
  scatter_k<<<(E + 255) / 256, 256, 0, stream>>>(ei, E, cursor, csr);

  // ---- layer 1: fused x@[W1|res1_w] ----
  mfma_gemm<128, 0><<<dim3(mblk, 2), 256, 0, stream>>>(x_bf, Wt1, res1_b, h1bf, xres, N, 256);

  att1_k<<<(N + 3) / 4, 256, 0, stream>>>((const uint*)h1bf, att_src1, att_dst1, as1, ad1, N);
  aggr1_k<<<(N + 3) / 4, 256, 0, stream>>>((const uint*)h1bf, xres, as1, ad1, offp, csr, b1,
                                           hpre_bf, hlk_bf, N);

  // ---- layer 2 GEMMs (hres first: reads hpre, writes xres-alias) ----
  mfma_gemm<64, 1><<<dim3(mblk, 1), 256, 0, stream>>>((const ushort*)hpre_bf, fcT, fc_b, hres, nullptr, N, 128);
  mfma_gemm<64, 2><<<dim3(mblk, 1), 256, 0, stream>>>((const ushort*)hlk_bf, W2T, nullptr, h2bf, nullptr, N, 128);

  att2_k<<<(N + 3) / 4, 256, 0, stream>>>(h2bf, att_src2, att_dst2, as2, ad2, N);
  aggr2_k<<<(N + 3) / 4, 256, 0, stream>>>(h2bf, hres, as2, ad2, offp, csr, b2, out, N);
}

// Round 3
// 310.747 us; speedup vs baseline: 2.2200x; 1.3352x over previous
//
#include <hip/hip_runtime.h>

typedef __attribute__((ext_vector_type(8))) short short8;
typedef __attribute__((ext_vector_type(4))) float f32x4;

__device__ __forceinline__ ushort rne_bf16(float f) {
  uint u = __float_as_uint(f);
  uint r = (u + 0x7FFFu + ((u >> 16) & 1u)) >> 16;
  return (ushort)r;
}
__device__ __forceinline__ float bf16_lo(uint pair) { return __uint_as_float(pair << 16); }
__device__ __forceinline__ float bf16_hi(uint pair) { return __uint_as_float(pair & 0xffff0000u); }
__device__ __forceinline__ float lrelu(float a) { return a >= 0.f ? a : 0.2f * a; }

// ---------------- casts / weight prep ----------------
__global__ __launch_bounds__(256) void cast_bf16_k(const float* __restrict__ in,
                                                   ushort* __restrict__ out, long n) {
  long i = ((long)blockIdx.x * 256 + threadIdx.x) * 8;
  if (i >= n) return;
  float4 a = *(const float4*)&in[i];
  float4 b = *(const float4*)&in[i + 4];
  ushort o[8] = {rne_bf16(a.x), rne_bf16(a.y), rne_bf16(a.z), rne_bf16(a.w),
                 rne_bf16(b.x), rne_bf16(b.y), rne_bf16(b.z), rne_bf16(b.w)};
  *(uint4*)&out[i] = *(const uint4*)o;
}

__global__ __launch_bounds__(256) void transpose_cast_k(const float* __restrict__ in,
                                                        ushort* __restrict__ out, int K, int NO) {
  int i = blockIdx.x * 256 + threadIdx.x;
  if (i >= K * NO) return;
  int n = i / K, k = i % K;
  out[i] = rne_bf16(in[(size_t)k * NO + n]);
}

// ---------------- bf16 MFMA GEMM ----------------
template<int BN, int MODE>
__global__ __launch_bounds__(256) void mfma_gemm(
    const ushort* __restrict__ Abf, const ushort* __restrict__ Btb,
    const float* __restrict__ bias, void* __restrict__ out0,
    float* __restrict__ out1, int M, int K)
{
  constexpr int BM = 128, BK = 64;
  constexpr int LDA = BK + 8;
  constexpr int WN = BN / 2;
  constexpr int NREP = WN / 16;
  constexpr int B_ISS = BN / 32;
  __shared__ ushort As[BM * LDA];
  __shared__ ushort Bs[BN * LDA];

  const int tid = threadIdx.x;
  const int w = tid >> 6, l = tid & 63;
  const int wr = w >> 1, wc = w & 1;
  const int row0 = blockIdx.x * BM, col0 = blockIdx.y * BN;
  const int l15 = l & 15, lg = l >> 4;

  f32x4 acc[4][NREP] = {};

  for (int k0 = 0; k0 < K; k0 += BK) {
    float4 ra[4], rb[B_ISS];
#pragma unroll
    for (int i = 0; i < 4; ++i) {
      int ci = i * 256 + tid, row = ci >> 3, ch = ci & 7;
      int gr = row0 + row; if (gr >= M) gr = M - 1;
      ra[i] = *(const float4*)(Abf + (size_t)gr * K + k0 + ch * 8);
    }
#pragma unroll
    for (int i = 0; i < B_ISS; ++i) {
      int ci = i * 256 + tid, row = ci >> 3, ch = ci & 7;
      rb[i] = *(const float4*)(Btb + (size_t)(col0 + row) * K + k0 + ch * 8);
    }
    __syncthreads();
#pragma unroll
    for (int i = 0; i < 4; ++i) {
      int ci = i * 256 + tid, row = ci >> 3, ch = ci & 7;
      *(float4*)&As[row * LDA + ch * 8] = ra[i];
    }
#pragma unroll
    for (int i = 0; i < B_ISS; ++i) {
      int ci = i * 256 + tid, row = ci >> 3, ch = ci & 7;
      *(float4*)&Bs[row * LDA + ch * 8] = rb[i];
    }
    __syncthreads();

    short8 aF[4][2], bF[NREP][2];
#pragma unroll
    for (int m = 0; m < 4; ++m)
#pragma unroll
      for (int kk = 0; kk < 2; ++kk)
        aF[m][kk] = *(const short8*)&As[(wr * 64 + m * 16 + l15) * LDA + kk * 32 + lg * 8];
#pragma unroll
    for (int n = 0; n < NREP; ++n)
#pragma unroll
      for (int kk = 0; kk < 2; ++kk)
        bF[n][kk] = *(const short8*)&Bs[(wc * WN + n * 16 + l15) * LDA + kk * 32 + lg * 8];
#pragma unroll
    for (int m = 0; m < 4; ++m)
#pragma unroll
      for (int n = 0; n < NREP; ++n)
#pragma unroll
        for (int kk = 0; kk < 2; ++kk)
          acc[m][n] = __builtin_amdgcn_mfma_f32_16x16x32_bf16(aF[m][kk], bF[n][kk], acc[m][n], 0, 0, 0);
    __syncthreads();
  }

#pragma unroll
  for (int m = 0; m < 4; ++m) {
#pragma unroll
    for (int n = 0; n < NREP; ++n) {
#pragma unroll
      for (int j = 0; j < 4; ++j) {
        int gr = row0 + wr * 64 + m * 16 + lg * 4 + j;
        if (gr >= M) continue;
        int gc = col0 + wc * WN + n * 16 + l15;
        float v = acc[m][n][j];
        if (MODE == 0) {
          if (gc < 128) ((ushort*)out0)[(size_t)gr * 128 + gc] = rne_bf16(v);
          else          out1[(size_t)gr * 128 + gc - 128] = v + bias[gc - 128];
        } else if (MODE == 1) {
          ((float*)out0)[(size_t)gr * 64 + gc] = v + bias[gc];
        } else {
          ((ushort*)out0)[(size_t)gr * 64 + gc] = rne_bf16(v);
        }
      }
    }
  }
}

// ---------------- CSR build ----------------
__global__ void count_k(const int* __restrict__ ei, int E, int* __restrict__ cnt) {
  int e = blockIdx.x * 256 + threadIdx.x;
  if (e < E) atomicAdd(&cnt[ei[E + e]], 1);
}

__global__ __launch_bounds__(1024) void scan_block(const int* __restrict__ cnt,
                                                   int* __restrict__ off,
                                                   int* __restrict__ bsum, int n) {
  __shared__ int sh[1024];
  int i = blockIdx.x * 1024 + threadIdx.x;
  int v = (i < n) ? cnt[i] : 0;
  sh[threadIdx.x] = v;
  __syncthreads();
  for (int o = 1; o < 1024; o <<= 1) {
    int t = (threadIdx.x >= o) ? sh[threadIdx.x - o] : 0;
    __syncthreads();
    sh[threadIdx.x] += t;
    __syncthreads();
  }
  if (i < n) off[i] = sh[threadIdx.x] - v;
  if (threadIdx.x == 1023) bsum[blockIdx.x] = sh[1023];
}

__global__ void scan_partials(int* __restrict__ bsum, int nb, int* __restrict__ off, int n) {
  int run = 0;
  for (int b = 0; b < nb; ++b) { int t = bsum[b]; bsum[b] = run; run += t; }
  off[n] = run;
}

__global__ __launch_bounds__(1024) void scan_add(int* __restrict__ off, int* __restrict__ cursor,
                                                 const int* __restrict__ bsum, int n) {
  int i = blockIdx.x * 1024 + threadIdx.x;
  if (i < n) { int v = off[i] + bsum[blockIdx.x]; off[i] = v; cursor[i] = v; }
}

__global__ void scatter_k(const int* __restrict__ ei, int E,
                          int* __restrict__ cursor, int* __restrict__ csr) {
  int e = blockIdx.x * 256 + threadIdx.x;
  if (e < E) {
    int d = ei[E + e];
    int p = atomicAdd(&cursor[d], 1);
    csr[p] = ei[e];
  }
}

// ---------------- attention dots ----------------
__global__ __launch_bounds__(256) void att1_k(const uint* __restrict__ h1u,
                                              const float* __restrict__ att_s,
                                              const float* __restrict__ att_d,
                                              float* __restrict__ a_s, float* __restrict__ a_d, int n) {
  int w = threadIdx.x >> 6, l = threadIdx.x & 63;
  int node = blockIdx.x * 4 + w;
  if (node >= n) return;
  int h = l >> 4, c = l * 2;
  uint pair = h1u[(size_t)node * 64 + l];
  float vx = bf16_lo(pair), vy = bf16_hi(pair);
  float2 as = *(const float2*)&att_s[h * 32 + (c & 31)];
  float2 ad = *(const float2*)&att_d[h * 32 + (c & 31)];
  float ps = vx * as.x + vy * as.y;
  float pd = vx * ad.x + vy * ad.y;
  for (int o = 1; o < 16; o <<= 1) { ps += __shfl_xor(ps, o, 64); pd += __shfl_xor(pd, o, 64); }
  if ((l & 15) == 0) { a_s[node * 4 + h] = ps; a_d[node * 4 + h] = pd; }
}

__global__ __launch_bounds__(256) void att2_k(const ushort* __restrict__ h2b,
                                              const float* __restrict__ att_s,
                                              const float* __restrict__ att_d,
                                              float* __restrict__ a_s, float* __restrict__ a_d, int n) {
  int w = threadIdx.x >> 6, l = threadIdx.x & 63;
  int node = blockIdx.x * 4 + w;
  if (node >= n) return;
  float v = __uint_as_float((uint)h2b[(size_t)node * 64 + l] << 16);
  float ps = v * att_s[l], pd = v * att_d[l];
  for (int o = 1; o < 64; o <<= 1) { ps += __shfl_xor(ps, o, 64); pd += __shfl_xor(pd, o, 64); }
  if (l == 0) { a_s[node] = ps; a_d[node] = pd; }
}

// ---------------- aggregation: max-free softmax, unroll-4 ----------------
// logits are dots of ~unit-variance vectors (|a| << 80) -> expf safe without max shift.
__global__ __launch_bounds__(256) void aggr1_k(const uint* __restrict__ h1u,
                                               const float* __restrict__ xres,
                                               const float* __restrict__ a_s,
                                               const float* __restrict__ a_d,
                                               const int* __restrict__ off,
                                               const int* __restrict__ csr,
                                               const float* __restrict__ b1,
                                               uint* __restrict__ hpre_bf,
                                               uint* __restrict__ hlk_bf, int n) {
  int w = threadIdx.x >> 6, l = threadIdx.x & 63;
  int d = blockIdx.x * 4 + w;
  if (d >= n) return;
  int h = l >> 4, c = l * 2;
  float adh = a_d[d * 4 + h];
  // self loop folded into init
  float ws = __expf(lrelu(a_s[d * 4 + h] + adh));
  uint pd = h1u[(size_t)d * 64 + l];
  float lsum = ws, accx = ws * bf16_lo(pd), accy = ws * bf16_hi(pd);

  int s0 = off[d], s1 = off[d + 1];
  int p = s0;
  for (; p + 4 <= s1; p += 4) {
    int i0 = csr[p], i1 = csr[p + 1], i2 = csr[p + 2], i3 = csr[p + 3];
    float w0 = __expf(lrelu(a_s[i0 * 4 + h] + adh));
    float w1 = __expf(lrelu(a_s[i1 * 4 + h] + adh));
    float w2 = __expf(lrelu(a_s[i2 * 4 + h] + adh));
    float w3 = __expf(lrelu(a_s[i3 * 4 + h] + adh));
    uint q0 = h1u[(size_t)i0 * 64 + l];
    uint q1 = h1u[(size_t)i1 * 64 + l];
    uint q2 = h1u[(size_t)i2 * 64 + l];
    uint q3 = h1u[(size_t)i3 * 64 + l];
    lsum += (w0 + w1) + (w2 + w3);
    accx += w0 * bf16_lo(q0) + w1 * bf16_lo(q1) + w2 * bf16_lo(q2) + w3 * bf16_lo(q3);
    accy += w0 * bf16_hi(q0) + w1 * bf16_hi(q1) + w2 * bf16_hi(q2) + w3 * bf16_hi(q3);
  }
  for (; p < s1; ++p) {
    int s = csr[p];
    float wv = __expf(lrelu(a_s[s * 4 + h] + adh));
    uint q = h1u[(size_t)s * 64 + l];
    lsum += wv;
    accx += wv * bf16_lo(q);
    accy += wv * bf16_hi(q);
  }
  float inv = 1.f / (lsum + 1e-16f);
  float2 xr = *(const float2*)&xres[(size_t)d * 128 + c];
  float vx = accx * inv + b1[c] + xr.x;
  float vy = accy * inv + b1[c + 1] + xr.y;
  hpre_bf[(size_t)d * 64 + l] = (uint)rne_bf16(vx) | ((uint)rne_bf16(vy) << 16);
  float lx = lrelu(vx), ly = lrelu(vy);
  hlk_bf[(size_t)d * 64 + l] = (uint)rne_bf16(lx) | ((uint)rne_bf16(ly) << 16);
}

__global__ __launch_bounds__(256) void aggr2_k(const ushort* __restrict__ h2b,
                                               const float* __restrict__ hres,
                                               const float* __restrict__ a_s,
                                               const float* __restrict__ a_d,
                                               const int* __restrict__ off,
                                               const int* __restrict__ csr,
                                               const float* __restrict__ b2,
                                               float* __restrict__ out, int n) {
  int w = threadIdx.x >> 6, l = threadIdx.x & 63;
  int d = blockIdx.x * 4 + w;
  if (d >= n) return;
  float adh = a_d[d];
  float ws = __expf(lrelu(a_s[d] + adh));
  float lsum = ws;
  float acc = ws * __uint_as_float((uint)h2b[(size_t)d * 64 + l] << 16);

  int s0 = off[d], s1 = off[d + 1];
  int p = s0;
  for (; p + 4 <= s1; p += 4) {
    int i0 = csr[p], i1 = csr[p + 1], i2 = csr[p + 2], i3 = csr[p + 3];
    float w0 = __expf(lrelu(a_s[i0] + adh));
    float w1 = __expf(lrelu(a_s[i1] + adh));
    float w2 = __expf(lrelu(a_s[i2] + adh));
    float w3 = __expf(lrelu(a_s[i3] + adh));
    float f0 = __uint_as_float((uint)h2b[(size_t)i0 * 64 + l] << 16);
    float f1 = __uint_as_float((uint)h2b[(size_t)i1 * 64 + l] << 16);
    float f2 = __uint_as_float((uint)h2b[(size_t)i2 * 64 + l] << 16);
    float f3 = __uint_as_float((uint)h2b[(size_t)i3 * 64 + l] << 16);
    lsum += (w0 + w1) + (w2 + w3);
    acc += w0 * f0 + w1 * f1 + w2 * f2 + w3 * f3;
  }
  for (; p < s1; ++p) {
    int s = csr[p];
    float wv = __expf(lrelu(a_s[s] + adh));
    lsum += wv;
    acc += wv * __uint_as_float((uint)h2b[(size_t)s * 64 + l] << 16);
  }
  float inv = 1.f / (lsum + 1e-16f);
  float z = acc * inv + b2[l] + hres[(size_t)d * 64 + l];
  out[(size_t)d * 64 + l] = lrelu(z);
}

// ---------------- launch ----------------
extern "C" void kernel_launch(void* const* d_in, const int* in_sizes, int n_in,
                              void* d_out, int out_size, void* d_ws, size_t ws_size,
                              hipStream_t stream) {
  const float* x        = (const float*)d_in[0];
  const int*   ei       = (const int*)d_in[1];
  const float* W1       = (const float*)d_in[2];
  const float* att_src1 = (const float*)d_in[3];
  const float* att_dst1 = (const float*)d_in[4];
  const float* b1       = (const float*)d_in[5];
  const float* W2       = (const float*)d_in[6];
  const float* att_src2 = (const float*)d_in[7];
  const float* att_dst2 = (const float*)d_in[8];
  const float* b2       = (const float*)d_in[9];
  const float* res1_w   = (const float*)d_in[10];
  const float* res1_b   = (const float*)d_in[11];
  const float* fc_w     = (const float*)d_in[12];
  const float* fc_b     = (const float*)d_in[13];
  float* out = (float*)d_out;

  const int N = in_sizes[0] / 256;
  const int E = in_sizes[1] / 2;

  ushort* x_bf  = (ushort*)d_ws;                 // N*256 bf16
  ushort* h1bf  = x_bf + (size_t)N * 256;        // N*128 bf16
  float*  xres  = (float*)(h1bf + (size_t)N * 128);  // N*128 f32
  float*  as1   = xres + (size_t)N * 128;        // N*4
  float*  ad1   = as1 + (size_t)N * 4;           // N*4
  ushort* Wt1   = (ushort*)(ad1 + (size_t)N * 4);// 256*256
  ushort* fcT   = Wt1 + 256 * 256;               // 64*128
  ushort* W2T   = fcT + 64 * 128;                // 64*128
  int* cnt      = (int*)(W2T + 64 * 128);        // N
  int* offp     = cnt + N;                       // N+1
  int* cursor   = offp + N + 1;                  // N
  int* csr      = cursor + N;                    // E
  int* bsum     = csr + E;                       // 64
  uint*   hpre_bf = (uint*)x_bf;
  uint*   hlk_bf  = (uint*)(x_bf + (size_t)N * 128);
  ushort* h2bf    = h1bf;
  float*  hres    = xres;
  float*  as2 = as1, *ad2 = ad1;

  const int nb = (N + 1023) / 1024;
  const int mblk = (N + 127) / 128;

  cast_bf16_k<<<(N * 256 / 8 + 255) / 256, 256, 0, stream>>>(x, x_bf, (long)N * 256);
  transpose_cast_k<<<(256 * 128 + 255) / 256, 256, 0, stream>>>(W1, Wt1, 256, 128);
  transpose_cast_k<<<(256 * 128 + 255) / 256, 256, 0, stream>>>(res1_w, Wt1 + 128 * 256, 256, 128);
  transpose_cast_k<<<(128 * 64 + 255) / 256, 256, 0, stream>>>(fc_w, fcT, 128, 64);
  transpose_cast_k<<<(128 * 64 + 255) / 256, 256, 0, stream>>>(W2, W2T, 128, 64);

  hipMemsetAsync(cnt, 0, (size_t)N * 4, stream);
  count_k<<<(E + 255) / 256, 256, 0, stream>>>(ei, E, cnt);
  scan_block<<<nb, 1024, 0, stream>>>(cnt, offp, bsum, N);
  scan_partials<<<1, 1, 0, stream>>>(bsum, nb, offp, N);
  scan_add<<<nb, 1024, 0, stream>>>(offp, cursor, bsum, N);
  scatter_k<<<(E + 255) / 256, 256, 0, stream>>>(ei, E, cursor, csr);

  mfma_gemm<128, 0><<<dim3(mblk, 2), 256, 0, stream>>>(x_bf, Wt1, res1_b, h1bf, xres, N, 256);

  att1_k<<<(N + 3) / 4, 256, 0, stream>>>((const uint*)h1bf, att_src1, att_dst1, as1, ad1, N);
  aggr1_k<<<(N + 3) / 4, 256, 0, stream>>>((const uint*)h1bf, xres, as1, ad1, offp, csr, b1,
                                           hpre_bf, hlk_bf, N);

  mfma_gemm<64, 1><<<dim3(mblk, 1), 256, 0, stream>>>((const ushort*)hpre_bf, fcT, fc_b, hres, nullptr, N, 128);
  mfma_gemm<64, 2><<<dim3(mblk, 1), 256, 0, stream>>>((const ushort*)hlk_bf, W2T, nullptr, h2bf, nullptr, N, 128);

  att2_k<<<(N + 3) / 4, 256, 0, stream>>>(h2bf, att_src2, att_dst2, as2, ad2, N);
  aggr2_k<<<(N + 3) / 4, 256, 0, stream>>>(h2bf, hres, as2, ad2, offp, csr, b2, out, N);
}

// Round 4
// 300.990 us; speedup vs baseline: 2.2919x; 1.0324x over previous
//
#include <hip/hip_runtime.h>

typedef __attribute__((ext_vector_type(8))) short short8;
typedef __attribute__((ext_vector_type(4))) float f32x4;

__device__ __forceinline__ ushort rne_bf16(float f) {
  uint u = __float_as_uint(f);
  uint r = (u + 0x7FFFu + ((u >> 16) & 1u)) >> 16;
  return (ushort)r;
}
__device__ __forceinline__ float bf16_lo(uint pair) { return __uint_as_float(pair << 16); }
__device__ __forceinline__ float bf16_hi(uint pair) { return __uint_as_float(pair & 0xffff0000u); }
__device__ __forceinline__ float bf1(ushort v) { return __uint_as_float((uint)v << 16); }
__device__ __forceinline__ float lrelu(float a) { return a >= 0.f ? a : 0.2f * a; }

// ---------------- casts / weight prep ----------------
__global__ __launch_bounds__(256) void cast_bf16_k(const float* __restrict__ in,
                                                   ushort* __restrict__ out, long n) {
  long i = ((long)blockIdx.x * 256 + threadIdx.x) * 8;
  if (i >= n) return;
  float4 a = *(const float4*)&in[i];
  float4 b = *(const float4*)&in[i + 4];
  ushort o[8] = {rne_bf16(a.x), rne_bf16(a.y), rne_bf16(a.z), rne_bf16(a.w),
                 rne_bf16(b.x), rne_bf16(b.y), rne_bf16(b.z), rne_bf16(b.w)};
  *(uint4*)&out[i] = *(const uint4*)o;
}

// all four weight transposes fused: out[n*K+k] = bf16(in[k*NO+n])
__global__ __launch_bounds__(256) void prep_weights_k(
    const float* __restrict__ W1, const float* __restrict__ res1_w,
    const float* __restrict__ fc_w, const float* __restrict__ W2,
    ushort* __restrict__ Wt1, ushort* __restrict__ fcT, ushort* __restrict__ W2T) {
  int gi = blockIdx.x * 256 + threadIdx.x;
  const float* src; ushort* dst; int K, NO, local;
  if (gi < 32768)            { src = W1;     dst = Wt1;          K = 256; NO = 128; local = gi; }
  else if (gi < 65536)       { src = res1_w; dst = Wt1 + 32768;  K = 256; NO = 128; local = gi - 32768; }
  else if (gi < 65536+8192)  { src = fc_w;   dst = fcT;          K = 128; NO = 64;  local = gi - 65536; }
  else if (gi < 65536+16384) { src = W2;     dst = W2T;          K = 128; NO = 64;  local = gi - 65536 - 8192; }
  else return;
  int n = local / K, k = local % K;
  dst[local] = rne_bf16(src[(size_t)k * NO + n]);
}

// ---------------- bf16 MFMA GEMM: BM=64, BK=64, 4 waves (2x2), bf16 out ----------------
// blockIdx.y picks {A, B-half, bias, out}. Epilogue staged via LDS -> coalesced 16B stores.
template<int BN>
__global__ __launch_bounds__(256) void gemm_bf(
    const ushort* __restrict__ A0, const ushort* __restrict__ A1,
    const ushort* __restrict__ Bt, const float* __restrict__ bias0,
    const float* __restrict__ bias1, ushort* __restrict__ out0,
    ushort* __restrict__ out1, int M, int K)
{
  constexpr int LDA = 72;                 // 64 + 8 pad (bank-conflict-free b128 reads)
  constexpr int WN = BN / 2;
  constexpr int NREP = WN / 16;
  constexpr int BITERS = BN / 32;
  __shared__ ushort smem[64 * LDA + BN * LDA];
  ushort* As = smem;
  ushort* Bs = smem + 64 * LDA;

  const int tid = threadIdx.x, w = tid >> 6, l = tid & 63;
  const int wr = w >> 1, wc = w & 1;
  const int l15 = l & 15, lg = l >> 4;
  const int row0 = blockIdx.x * 64;
  const ushort* A = blockIdx.y ? A1 : A0;
  const ushort* B = Bt + (size_t)blockIdx.y * BN * K;
  const float* bias = blockIdx.y ? bias1 : bias0;
  ushort* out = blockIdx.y ? out1 : out0;

  f32x4 acc[2][NREP] = {};

  for (int k0 = 0; k0 < K; k0 += 64) {
    float4 ra[2], rb[BITERS];
#pragma unroll
    for (int i = 0; i < 2; ++i) {
      int ci = i * 256 + tid, row = ci >> 3, ch = ci & 7;
      int gr = row0 + row; if (gr >= M) gr = M - 1;
      ra[i] = *(const float4*)(A + (size_t)gr * K + k0 + ch * 8);
    }
#pragma unroll
    for (int i = 0; i < BITERS; ++i) {
      int ci = i * 256 + tid, row = ci >> 3, ch = ci & 7;
      rb[i] = *(const float4*)(B + (size_t)row * K + k0 + ch * 8);
    }
    __syncthreads();
#pragma unroll
    for (int i = 0; i < 2; ++i) {
      int ci = i * 256 + tid, row = ci >> 3, ch = ci & 7;
      *(float4*)&As[row * LDA + ch * 8] = ra[i];
    }
#pragma unroll
    for (int i = 0; i < BITERS; ++i) {
      int ci = i * 256 + tid, row = ci >> 3, ch = ci & 7;
      *(float4*)&Bs[row * LDA + ch * 8] = rb[i];
    }
    __syncthreads();

    short8 aF[2][2], bF[NREP][2];
#pragma unroll
    for (int m = 0; m < 2; ++m)
#pragma unroll
      for (int kk = 0; kk < 2; ++kk)
        aF[m][kk] = *(const short8*)&As[(wr * 32 + m * 16 + l15) * LDA + kk * 32 + lg * 8];
#pragma unroll
    for (int n = 0; n < NREP; ++n)
#pragma unroll
      for (int kk = 0; kk < 2; ++kk)
        bF[n][kk] = *(const short8*)&Bs[(wc * WN + n * 16 + l15) * LDA + kk * 32 + lg * 8];
#pragma unroll
    for (int m = 0; m < 2; ++m)
#pragma unroll
      for (int n = 0; n < NREP; ++n)
#pragma unroll
        for (int kk = 0; kk < 2; ++kk)
          acc[m][n] = __builtin_amdgcn_mfma_f32_16x16x32_bf16(aF[m][kk], bF[n][kk], acc[m][n], 0, 0, 0);
    __syncthreads();
  }

  // epilogue: fragments -> LDS (bf16) -> coalesced linear copy
  ushort* Cs = smem;
#pragma unroll
  for (int m = 0; m < 2; ++m)
#pragma unroll
    for (int n = 0; n < NREP; ++n)
#pragma unroll
      for (int j = 0; j < 4; ++j) {
        int rl = wr * 32 + m * 16 + lg * 4 + j;
        int col = wc * WN + n * 16 + l15;
        float v = acc[m][n][j] + (bias ? bias[col] : 0.f);
        Cs[rl * BN + col] = rne_bf16(v);
      }
  __syncthreads();
  constexpr int CHUNKS = 64 * BN / 8;      // 16B chunks
  uint4* dst = (uint4*)(out + (size_t)row0 * BN);
  const uint4* srcv = (const uint4*)Cs;
#pragma unroll
  for (int idx = tid; idx < CHUNKS; idx += 256) {
    int row = idx / (BN / 8);
    if (row0 + row < M) dst[idx] = srcv[idx];
  }
}

// ---------------- CSR build ----------------
__global__ void count_k(const int* __restrict__ ei, int E, int* __restrict__ cnt) {
  int e = blockIdx.x * 256 + threadIdx.x;
  if (e < E) atomicAdd(&cnt[ei[E + e]], 1);
}

__global__ __launch_bounds__(1024) void scan_block(const int* __restrict__ cnt,
                                                   int* __restrict__ off,
                                                   int* __restrict__ bsum, int n) {
  __shared__ int sh[1024];
  int i = blockIdx.x * 1024 + threadIdx.x;
  int v = (i < n) ? cnt[i] : 0;
  sh[threadIdx.x] = v;
  __syncthreads();
  for (int o = 1; o < 1024; o <<= 1) {
    int t = (threadIdx.x >= o) ? sh[threadIdx.x - o] : 0;
    __syncthreads();
    sh[threadIdx.x] += t;
    __syncthreads();
  }
  if (i < n) off[i] = sh[threadIdx.x] - v;
  if (threadIdx.x == 1023) bsum[blockIdx.x] = sh[1023];
}

__global__ void scan_partials(int* __restrict__ bsum, int nb, int* __restrict__ off, int n) {
  int run = 0;
  for (int b = 0; b < nb; ++b) { int t = bsum[b]; bsum[b] = run; run += t; }
  off[n] = run;
}

__global__ __launch_bounds__(1024) void scan_add(int* __restrict__ off, int* __restrict__ cursor,
                                                 const int* __restrict__ bsum, int n) {
  int i = blockIdx.x * 1024 + threadIdx.x;
  if (i < n) { int v = off[i] + bsum[blockIdx.x]; off[i] = v; cursor[i] = v; }
}

__global__ void scatter_k(const int* __restrict__ ei, int E,
                          int* __restrict__ cursor, int* __restrict__ csr) {
  int e = blockIdx.x * 256 + threadIdx.x;
  if (e < E) {
    int d = ei[E + e];
    int p = atomicAdd(&cursor[d], 1);
    csr[p] = ei[e];
  }
}

// ---------------- attention dots ----------------
__global__ __launch_bounds__(256) void att1_k(const uint* __restrict__ h1u,
                                              const float* __restrict__ att_s,
                                              const float* __restrict__ att_d,
                                              float* __restrict__ a_s, float* __restrict__ a_d, int n) {
  int w = threadIdx.x >> 6, l = threadIdx.x & 63;
  int node = blockIdx.x * 4 + w;
  if (node >= n) return;
  int h = l >> 4, c = l * 2;
  uint pair = h1u[(size_t)node * 64 + l];
  float vx = bf16_lo(pair), vy = bf16_hi(pair);
  float2 as = *(const float2*)&att_s[h * 32 + (c & 31)];
  float2 ad = *(const float2*)&att_d[h * 32 + (c & 31)];
  float ps = vx * as.x + vy * as.y;
  float pd = vx * ad.x + vy * ad.y;
  for (int o = 1; o < 16; o <<= 1) { ps += __shfl_xor(ps, o, 64); pd += __shfl_xor(pd, o, 64); }
  if ((l & 15) == 0) { a_s[node * 4 + h] = ps; a_d[node * 4 + h] = pd; }
}

__global__ __launch_bounds__(256) void att2_k(const ushort* __restrict__ h2b,
                                              const float* __restrict__ att_s,
                                              const float* __restrict__ att_d,
                                              float* __restrict__ a_s, float* __restrict__ a_d, int n) {
  int w = threadIdx.x >> 6, l = threadIdx.x & 63;
  int node = blockIdx.x * 4 + w;
  if (node >= n) return;
  float v = bf1(h2b[(size_t)node * 64 + l]);
  float ps = v * att_s[l], pd = v * att_d[l];
  for (int o = 1; o < 64; o <<= 1) { ps += __shfl_xor(ps, o, 64); pd += __shfl_xor(pd, o, 64); }
  if (l == 0) { a_s[node] = ps; a_d[node] = pd; }
}

// ---------------- aggregation: max-free softmax, batched-4 (masked tail) ----------------
__global__ __launch_bounds__(256) void aggr1_k(const uint* __restrict__ h1u,
                                               const uint* __restrict__ xresu,
                                               const float* __restrict__ a_s,
                                               const float* __restrict__ a_d,
                                               const int* __restrict__ off,
                                               const int* __restrict__ csr,
                                               const float* __restrict__ b1,
                                               uint* __restrict__ hpre_bf,
                                               uint* __restrict__ hlk_bf, int n) {
  int w = threadIdx.x >> 6, l = threadIdx.x & 63;
  int d = blockIdx.x * 4 + w;
  if (d >= n) return;
  int h = l >> 4, c = l * 2;
  float adh = a_d[d * 4 + h];
  float ws = __expf(lrelu(a_s[d * 4 + h] + adh));   // self loop in init
  uint pd = h1u[(size_t)d * 64 + l];
  float lsum = ws, accx = ws * bf16_lo(pd), accy = ws * bf16_hi(pd);

  int s0 = off[d], s1 = off[d + 1];
  for (int p = s0; p < s1; p += 4) {
    int j1 = p + 1 < s1 ? p + 1 : s1 - 1;
    int j2 = p + 2 < s1 ? p + 2 : s1 - 1;
    int j3 = p + 3 < s1 ? p + 3 : s1 - 1;
    int i0 = csr[p], i1 = csr[j1], i2 = csr[j2], i3 = csr[j3];
    float w0 = __expf(lrelu(a_s[i0 * 4 + h] + adh));
    float w1 = __expf(lrelu(a_s[i1 * 4 + h] + adh));
    float w2 = __expf(lrelu(a_s[i2 * 4 + h] + adh));
    float w3 = __expf(lrelu(a_s[i3 * 4 + h] + adh));
    if (p + 1 >= s1) w1 = 0.f;
    if (p + 2 >= s1) w2 = 0.f;
    if (p + 3 >= s1) w3 = 0.f;
    uint q0 = h1u[(size_t)i0 * 64 + l];
    uint q1 = h1u[(size_t)i1 * 64 + l];
    uint q2 = h1u[(size_t)i2 * 64 + l];
    uint q3 = h1u[(size_t)i3 * 64 + l];
    lsum += (w0 + w1) + (w2 + w3);
    accx += w0 * bf16_lo(q0) + w1 * bf16_lo(q1) + w2 * bf16_lo(q2) + w3 * bf16_lo(q3);
    accy += w0 * bf16_hi(q0) + w1 * bf16_hi(q1) + w2 * bf16_hi(q2) + w3 * bf16_hi(q3);
  }
  float inv = 1.f / (lsum + 1e-16f);
  uint xr = xresu[(size_t)d * 64 + l];
  float vx = accx * inv + b1[c] + bf16_lo(xr);
  float vy = accy * inv + b1[c + 1] + bf16_hi(xr);
  hpre_bf[(size_t)d * 64 + l] = (uint)rne_bf16(vx) | ((uint)rne_bf16(vy) << 16);
  hlk_bf[(size_t)d * 64 + l] = (uint)rne_bf16(lrelu(vx)) | ((uint)rne_bf16(lrelu(vy)) << 16);
}

__global__ __launch_bounds__(256) void aggr2_k(const ushort* __restrict__ h2b,
                                               const ushort* __restrict__ hresb,
                                               const float* __restrict__ a_s,
                                               const float* __restrict__ a_d,
                                               const int* __restrict__ off,
                                               const int* __restrict__ csr,
                                               const float* __restrict__ b2,
                                               float* __restrict__ out, int n) {
  int w = threadIdx.x >> 6, l = threadIdx.x & 63;
  int d = blockIdx.x * 4 + w;
  if (d >= n) return;
  float adh = a_d[d];
  float ws = __expf(lrelu(a_s[d] + adh));
  float lsum = ws;
  float acc = ws * bf1(h2b[(size_t)d * 64 + l]);

  int s0 = off[d], s1 = off[d + 1];
  for (int p = s0; p < s1; p += 4) {
    int j1 = p + 1 < s1 ? p + 1 : s1 - 1;
    int j2 = p + 2 < s1 ? p + 2 : s1 - 1;
    int j3 = p + 3 < s1 ? p + 3 : s1 - 1;
    int i0 = csr[p], i1 = csr[j1], i2 = csr[j2], i3 = csr[j3];
    float w0 = __expf(lrelu(a_s[i0] + adh));
    float w1 = __expf(lrelu(a_s[i1] + adh));
    float w2 = __expf(lrelu(a_s[i2] + adh));
    float w3 = __expf(lrelu(a_s[i3] + adh));
    if (p + 1 >= s1) w1 = 0.f;
    if (p + 2 >= s1) w2 = 0.f;
    if (p + 3 >= s1) w3 = 0.f;
    float f0 = bf1(h2b[(size_t)i0 * 64 + l]);
    float f1 = bf1(h2b[(size_t)i1 * 64 + l]);
    float f2 = bf1(h2b[(size_t)i2 * 64 + l]);
    float f3 = bf1(h2b[(size_t)i3 * 64 + l]);
    lsum += (w0 + w1) + (w2 + w3);
    acc += w0 * f0 + w1 * f1 + w2 * f2 + w3 * f3;
  }
  float inv = 1.f / (lsum + 1e-16f);
  float z = acc * inv + b2[l] + bf1(hresb[(size_t)d * 64 + l]);
  out[(size_t)d * 64 + l] = lrelu(z);
}

// ---------------- launch ----------------
extern "C" void kernel_launch(void* const* d_in, const int* in_sizes, int n_in,
                              void* d_out, int out_size, void* d_ws, size_t ws_size,
                              hipStream_t stream) {
  const float* x        = (const float*)d_in[0];
  const int*   ei       = (const int*)d_in[1];
  const float* W1       = (const float*)d_in[2];
  const float* att_src1 = (const float*)d_in[3];
  const float* att_dst1 = (const float*)d_in[4];
  const float* b1       = (const float*)d_in[5];
  const float* W2       = (const float*)d_in[6];
  const float* att_src2 = (const float*)d_in[7];
  const float* att_dst2 = (const float*)d_in[8];
  const float* b2       = (const float*)d_in[9];
  const float* res1_w   = (const float*)d_in[10];
  const float* res1_b   = (const float*)d_in[11];
  const float* fc_w     = (const float*)d_in[12];
  const float* fc_b     = (const float*)d_in[13];
  float* out = (float*)d_out;

  const int N = in_sizes[0] / 256;
  const int E = in_sizes[1] / 2;

  ushort* x_bf   = (ushort*)d_ws;                    // N*256
  ushort* h1bf   = x_bf + (size_t)N * 256;           // N*128
  ushort* xresbf = h1bf + (size_t)N * 128;           // N*128
  float*  as1    = (float*)(xresbf + (size_t)N * 128); // N*4
  float*  ad1    = as1 + (size_t)N * 4;              // N*4
  ushort* Wt1    = (ushort*)(ad1 + (size_t)N * 4);   // 256*256
  ushort* fcT    = Wt1 + 256 * 256;                  // 64*128
  ushort* W2T    = fcT + 64 * 128;                   // 64*128
  int* cnt       = (int*)(W2T + 64 * 128);           // N
  int* offp      = cnt + N;                          // N+1
  int* cursor    = offp + N + 1;                     // N
  int* csr       = cursor + N;                       // E
  int* bsum      = csr + E;                          // 64
  // aliases (source regions dead when written)
  uint*   hpre_bf = (uint*)x_bf;                     // N*64 uints
  uint*   hlk_bf  = (uint*)(x_bf + (size_t)N * 128);
  ushort* h2bf    = h1bf;                            // N*64
  ushort* hresb   = xresbf;                          // N*64
  float*  as2 = as1, *ad2 = ad1;

  const int nb = (N + 1023) / 1024;
  const int mblk = (N + 63) / 64;

  cast_bf16_k<<<(N * 256 / 8 + 255) / 256, 256, 0, stream>>>(x, x_bf, (long)N * 256);
  prep_weights_k<<<(81920 + 255) / 256, 256, 0, stream>>>(W1, res1_w, fc_w, W2, Wt1, fcT, W2T);

  hipMemsetAsync(cnt, 0, (size_t)N * 4, stream);
  count_k<<<(E + 255) / 256, 256, 0, stream>>>(ei, E, cnt);
  scan_block<<<nb, 1024, 0, stream>>>(cnt, offp, bsum, N);
  scan_partials<<<1, 1, 0, stream>>>(bsum, nb, offp, N);
  scan_add<<<nb, 1024, 0, stream>>>(offp, cursor, bsum, N);
  scatter_k<<<(E + 255) / 256, 256, 0, stream>>>(ei, E, cursor, csr);

  // layer 1: y=0 -> h1bf (x@W1), y=1 -> xresbf (x@res1_w + res1_b)
  gemm_bf<128><<<dim3(mblk, 2), 256, 0, stream>>>(x_bf, x_bf, Wt1, nullptr, res1_b,
                                                  h1bf, xresbf, N, 256);

  att1_k<<<(N + 3) / 4, 256, 0, stream>>>((const uint*)h1bf, att_src1, att_dst1, as1, ad1, N);
  aggr1_k<<<(N + 3) / 4, 256, 0, stream>>>((const uint*)h1bf, (const uint*)xresbf, as1, ad1,
                                           offp, csr, b1, hpre_bf, hlk_bf, N);

  // layer 2 (one launch): y=0 -> hres = hpre@fc_w + fc_b ; y=1 -> h2 = leaky(hpre)@W2
  gemm_bf<64><<<dim3(mblk, 2), 256, 0, stream>>>((const ushort*)hpre_bf, (const ushort*)hlk_bf,
                                                 fcT, fc_b, nullptr, hresb, h2bf, N, 128);

  att2_k<<<(N + 3) / 4, 256, 0, stream>>>(h2bf, att_src2, att_dst2, as2, ad2, N);
  aggr2_k<<<(N + 3) / 4, 256, 0, stream>>>(h2bf, hresb, as2, ad2, offp, csr, b2, out, N);
}

// Round 5
// 233.411 us; speedup vs baseline: 2.9555x; 1.2895x over previous
//
#include <hip/hip_runtime.h>

typedef __attribute__((ext_vector_type(8))) short short8;
typedef __attribute__((ext_vector_type(4))) float f32x4;

__device__ __forceinline__ ushort rne_bf16(float f) {
  uint u = __float_as_uint(f);
  uint r = (u + 0x7FFFu + ((u >> 16) & 1u)) >> 16;
  return (ushort)r;
}
__device__ __forceinline__ float bf16_lo(uint pair) { return __uint_as_float(pair << 16); }
__device__ __forceinline__ float bf16_hi(uint pair) { return __uint_as_float(pair & 0xffff0000u); }
__device__ __forceinline__ float bf1(ushort v) { return __uint_as_float((uint)v << 16); }
__device__ __forceinline__ float lrelu(float a) { return a >= 0.f ? a : 0.2f * a; }

// ---------------- fused prep: cast x, count degrees, transpose-cast weights ----------------
__global__ __launch_bounds__(256) void prep_all_k(
    const float* __restrict__ x, ushort* __restrict__ x_bf, long nitems,
    const int* __restrict__ ei, int E, int* __restrict__ cnt,
    const float* __restrict__ W1, const float* __restrict__ res1_w,
    const float* __restrict__ fc_w, const float* __restrict__ W2,
    ushort* __restrict__ Wt1, ushort* __restrict__ fcT, ushort* __restrict__ W2T)
{
  const long gstride = (long)gridDim.x * 256;
  const long g0 = (long)blockIdx.x * 256 + threadIdx.x;
  // phase 1: cast x -> bf16 (8 f32 / iter)
  for (long it = g0; it < nitems; it += gstride) {
    long i = it * 8;
    float4 a = *(const float4*)&x[i];
    float4 b = *(const float4*)&x[i + 4];
    ushort o[8] = {rne_bf16(a.x), rne_bf16(a.y), rne_bf16(a.z), rne_bf16(a.w),
                   rne_bf16(b.x), rne_bf16(b.y), rne_bf16(b.z), rne_bf16(b.w)};
    *(uint4*)&x_bf[i] = *(const uint4*)o;
  }
  // phase 2: in-degree count
  for (long e = g0; e < E; e += gstride)
    atomicAdd(&cnt[ei[E + e]], 1);
  // phase 3: weight transpose-casts (Wt1 = [W1|res1] N-major; fcT; W2T)
  for (long gi = g0; gi < 81920; gi += gstride) {
    const float* src; ushort* dst; int K, NO; long local;
    if (gi < 32768)            { src = W1;     dst = Wt1;          K = 256; NO = 128; local = gi; }
    else if (gi < 65536)       { src = res1_w; dst = Wt1 + 32768;  K = 256; NO = 128; local = gi - 32768; }
    else if (gi < 65536+8192)  { src = fc_w;   dst = fcT;          K = 128; NO = 64;  local = gi - 65536; }
    else                       { src = W2;     dst = W2T;          K = 128; NO = 64;  local = gi - 65536 - 8192; }
    int n = (int)(local / K), k = (int)(local % K);
    dst[local] = rne_bf16(src[(size_t)k * NO + n]);
  }
}

// ---------------- scans ----------------
__global__ __launch_bounds__(1024) void scan_block(const int* __restrict__ cnt,
                                                   int* __restrict__ off,
                                                   int* __restrict__ bsum, int n) {
  __shared__ int sh[1024];
  int i = blockIdx.x * 1024 + threadIdx.x;
  int v = (i < n) ? cnt[i] : 0;
  sh[threadIdx.x] = v;
  __syncthreads();
  for (int o = 1; o < 1024; o <<= 1) {
    int t = (threadIdx.x >= o) ? sh[threadIdx.x - o] : 0;
    __syncthreads();
    sh[threadIdx.x] += t;
    __syncthreads();
  }
  if (i < n) off[i] = sh[threadIdx.x] - v;
  if (threadIdx.x == 1023) bsum[blockIdx.x] = sh[1023];
}

__global__ void scan_partials(int* __restrict__ bsum, int nb, int* __restrict__ off, int n) {
  int run = 0;
  for (int b = 0; b < nb; ++b) { int t = bsum[b]; bsum[b] = run; run += t; }
  off[n] = run;
}

__global__ __launch_bounds__(1024) void scan_add(int* __restrict__ off, int* __restrict__ cursor,
                                                 const int* __restrict__ bsum, int n) {
  int i = blockIdx.x * 1024 + threadIdx.x;
  if (i < n) { int v = off[i] + bsum[blockIdx.x]; off[i] = v; cursor[i] = v; }
}

// ---------------- fused L1 GEMM (BM=64, BN=256, 512thr) + att1 + CSR scatter ----------------
// role by bid%3: 0 -> gemm tile bid/3 ; else scatter chunk (interleaved for co-residency)
__global__ __launch_bounds__(512) void gemm1_scatter_k(
    const ushort* __restrict__ x_bf, const ushort* __restrict__ Wt1,
    const float* __restrict__ res1_b,
    const float* __restrict__ att_s1, const float* __restrict__ att_d1,
    ushort* __restrict__ h1bf, ushort* __restrict__ xresbf,
    float* __restrict__ a_s, float* __restrict__ a_d,
    const int* __restrict__ ei, int E, int* __restrict__ cursor, int* __restrict__ csr,
    int M, int ngemm)
{
  constexpr int LDA = 72;
  __shared__ ushort smem[64 * LDA + 256 * LDA];
  const int bid = blockIdx.x, tid = threadIdx.x;

  if (bid % 3 != 0) {                 // ---- scatter role ----
    int sc = bid - 1 - bid / 3;
    long estride = (long)(2 * ngemm) * 512;
    for (long e = (long)sc * 512 + tid; e < E; e += estride) {
      int d = ei[E + e];
      int p = atomicAdd(&cursor[d], 1);
      csr[p] = ei[e];
    }
    return;
  }
  const int tile = bid / 3;
  if (tile >= ngemm) return;

  ushort* As = smem;
  ushort* Bs = smem + 64 * LDA;
  const int w = tid >> 6, l = tid & 63;
  const int wr = w >> 2, wc = w & 3;           // 2x4 waves: 32-row x 64-col tiles
  const int l15 = l & 15, lg = l >> 4;
  const int row0 = tile * 64;

  f32x4 acc[2][4] = {};

  for (int k0 = 0; k0 < 256; k0 += 64) {
    float4 ra, rb[4];
    {
      int row = tid >> 3, ch = tid & 7;
      int gr = row0 + row; if (gr >= M) gr = M - 1;
      ra = *(const float4*)(x_bf + (size_t)gr * 256 + k0 + ch * 8);
    }
#pragma unroll
    for (int i = 0; i < 4; ++i) {
      int ci = i * 512 + tid, row = ci >> 3, ch = ci & 7;
      rb[i] = *(const float4*)(Wt1 + (size_t)row * 256 + k0 + ch * 8);
    }
    __syncthreads();
    { int row = tid >> 3, ch = tid & 7; *(float4*)&As[row * LDA + ch * 8] = ra; }
#pragma unroll
    for (int i = 0; i < 4; ++i) {
      int ci = i * 512 + tid, row = ci >> 3, ch = ci & 7;
      *(float4*)&Bs[row * LDA + ch * 8] = rb[i];
    }
    __syncthreads();

    short8 aF[2][2], bF[4][2];
#pragma unroll
    for (int m = 0; m < 2; ++m)
#pragma unroll
      for (int kk = 0; kk < 2; ++kk)
        aF[m][kk] = *(const short8*)&As[(wr * 32 + m * 16 + l15) * LDA + kk * 32 + lg * 8];
#pragma unroll
    for (int n = 0; n < 4; ++n)
#pragma unroll
      for (int kk = 0; kk < 2; ++kk)
        bF[n][kk] = *(const short8*)&Bs[(wc * 64 + n * 16 + l15) * LDA + kk * 32 + lg * 8];
#pragma unroll
    for (int m = 0; m < 2; ++m)
#pragma unroll
      for (int n = 0; n < 4; ++n)
#pragma unroll
        for (int kk = 0; kk < 2; ++kk)
          acc[m][n] = __builtin_amdgcn_mfma_f32_16x16x32_bf16(aF[m][kk], bF[n][kk], acc[m][n], 0, 0, 0);
    __syncthreads();
  }

  // stage C tile (64 x 256 bf16) in LDS; bias only on res-half
  ushort* Cs = smem;
#pragma unroll
  for (int m = 0; m < 2; ++m)
#pragma unroll
    for (int n = 0; n < 4; ++n)
#pragma unroll
      for (int j = 0; j < 4; ++j) {
        int rl = wr * 32 + m * 16 + lg * 4 + j;
        int col = wc * 64 + n * 16 + l15;
        float v = acc[m][n][j] + (col >= 128 ? res1_b[col - 128] : 0.f);
        Cs[rl * 256 + col] = rne_bf16(v);
      }
  __syncthreads();

  // fused att1: thread t -> row t>>3, seg t&7 (16 cols of h1); head = seg>>1
  {
    int r = tid >> 3, s = tid & 7, h = s >> 1;
    int gr = row0 + r;
    float ps = 0.f, pd = 0.f;
#pragma unroll
    for (int i = 0; i < 16; ++i) {
      int col = s * 16 + i;
      float v = bf1(Cs[r * 256 + col]);
      ps += v * att_s1[h * 32 + (col & 31)];
      pd += v * att_d1[h * 32 + (col & 31)];
    }
    ps += __shfl_xor(ps, 1, 64);
    pd += __shfl_xor(pd, 1, 64);
    if (!(s & 1) && gr < M) { a_s[gr * 4 + h] = ps; a_d[gr * 4 + h] = pd; }
  }

  // coalesced split copy: cols<128 -> h1bf, cols>=128 -> xresbf
#pragma unroll
  for (int idx = tid; idx < 2048; idx += 512) {
    int row = idx >> 5, c16 = idx & 31;
    int gr = row0 + row;
    if (gr < M) {
      uint4 v = *(const uint4*)&Cs[row * 256 + c16 * 8];
      if (c16 < 16) *(uint4*)&h1bf[(size_t)gr * 128 + c16 * 8] = v;
      else          *(uint4*)&xresbf[(size_t)gr * 128 + (c16 - 16) * 8] = v;
    }
  }
}

// ---------------- L2 GEMM (BM=64, BN=64, 512thr, y: 0=hres 1=h2) + att2 ----------------
__global__ __launch_bounds__(512) void gemm2_k(
    const ushort* __restrict__ hpre, const ushort* __restrict__ hlk,
    const ushort* __restrict__ fcT,            // W2T = fcT + 64*128
    const float* __restrict__ fc_b,
    const float* __restrict__ att_s2, const float* __restrict__ att_d2,
    ushort* __restrict__ hresb, ushort* __restrict__ h2bf,
    float* __restrict__ a_s, float* __restrict__ a_d, int M)
{
  constexpr int LDA = 72;
  __shared__ ushort smem[64 * LDA + 64 * LDA];
  const int tid = threadIdx.x, y = blockIdx.y;
  const ushort* A = y ? hlk : hpre;
  const ushort* B = fcT + (size_t)y * 64 * 128;
  ushort* out = y ? h2bf : hresb;
  const int row0 = blockIdx.x * 64;
  ushort* As = smem;
  ushort* Bs = smem + 64 * LDA;
  const int w = tid >> 6, l = tid & 63;
  const int wr = w >> 1, wc = w & 1;           // 4x2 waves: 16-row x 32-col tiles
  const int l15 = l & 15, lg = l >> 4;

  f32x4 acc[2] = {};

  for (int k0 = 0; k0 < 128; k0 += 64) {
    float4 ra, rb;
    int row = tid >> 3, ch = tid & 7;
    {
      int gr = row0 + row; if (gr >= M) gr = M - 1;
      ra = *(const float4*)(A + (size_t)gr * 128 + k0 + ch * 8);
    }
    rb = *(const float4*)(B + (size_t)row * 128 + k0 + ch * 8);
    __syncthreads();
    *(float4*)&As[row * LDA + ch * 8] = ra;
    *(float4*)&Bs[row * LDA + ch * 8] = rb;
    __syncthreads();

    short8 aF[2], bF[2][2];
#pragma unroll
    for (int kk = 0; kk < 2; ++kk)
      aF[kk] = *(const short8*)&As[(wr * 16 + l15) * LDA + kk * 32 + lg * 8];
#pragma unroll
    for (int n = 0; n < 2; ++n)
#pragma unroll
      for (int kk = 0; kk < 2; ++kk)
        bF[n][kk] = *(const short8*)&Bs[(wc * 32 + n * 16 + l15) * LDA + kk * 32 + lg * 8];
#pragma unroll
    for (int n = 0; n < 2; ++n)
#pragma unroll
      for (int kk = 0; kk < 2; ++kk)
        acc[n] = __builtin_amdgcn_mfma_f32_16x16x32_bf16(aF[kk], bF[n][kk], acc[n], 0, 0, 0);
    __syncthreads();
  }

  ushort* Cs = smem;
#pragma unroll
  for (int n = 0; n < 2; ++n)
#pragma unroll
    for (int j = 0; j < 4; ++j) {
      int rl = wr * 16 + lg * 4 + j;
      int col = wc * 32 + n * 16 + l15;
      float v = acc[n][j] + (y == 0 ? fc_b[col] : 0.f);
      Cs[rl * 64 + col] = rne_bf16(v);
    }
  __syncthreads();

  if (y == 1) {   // fused att2: row = t>>3, seg = t&7 covers 8 cols
    int r = tid >> 3, s = tid & 7;
    int gr = row0 + r;
    float ps = 0.f, pd = 0.f;
#pragma unroll
    for (int i = 0; i < 8; ++i) {
      int col = s * 8 + i;
      float v = bf1(Cs[r * 64 + col]);
      ps += v * att_s2[col];
      pd += v * att_d2[col];
    }
    ps += __shfl_xor(ps, 1, 64); pd += __shfl_xor(pd, 1, 64);
    ps += __shfl_xor(ps, 2, 64); pd += __shfl_xor(pd, 2, 64);
    ps += __shfl_xor(ps, 4, 64); pd += __shfl_xor(pd, 4, 64);
    if (s == 0 && gr < M) { a_s[gr] = ps; a_d[gr] = pd; }
  }

  {
    int row = tid >> 3, c16 = tid & 7;
    int gr = row0 + row;
    if (gr < M)
      *(uint4*)&out[(size_t)gr * 64 + c16 * 8] = *(const uint4*)&Cs[row * 64 + c16 * 8];
  }
}

// ---------------- aggregation: max-free softmax, batched-8 ----------------
__global__ __launch_bounds__(256) void aggr1_k(const uint* __restrict__ h1u,
                                               const uint* __restrict__ xresu,
                                               const float* __restrict__ a_s,
                                               const float* __restrict__ a_d,
                                               const int* __restrict__ off,
                                               const int* __restrict__ csr,
                                               const float* __restrict__ b1,
                                               uint* __restrict__ hpre_bf,
                                               uint* __restrict__ hlk_bf, int n) {
  int w = threadIdx.x >> 6, l = threadIdx.x & 63;
  int d = blockIdx.x * 4 + w;
  if (d >= n) return;
  int h = l >> 4, c = l * 2;
  float adh = a_d[d * 4 + h];
  float ws = __expf(lrelu(a_s[d * 4 + h] + adh));   // self loop in init
  uint pd = h1u[(size_t)d * 64 + l];
  float lsum = ws, accx = ws * bf16_lo(pd), accy = ws * bf16_hi(pd);

  int s0 = off[d], s1 = off[d + 1];
  for (int p = s0; p < s1; p += 8) {
    int idxs[8]; float wv[8]; uint q[8];
#pragma unroll
    for (int i = 0; i < 8; ++i) {
      int jp = (p + i < s1) ? p + i : s1 - 1;
      idxs[i] = csr[jp];
    }
#pragma unroll
    for (int i = 0; i < 8; ++i) wv[i] = __expf(lrelu(a_s[idxs[i] * 4 + h] + adh));
#pragma unroll
    for (int i = 0; i < 8; ++i) q[i] = h1u[(size_t)idxs[i] * 64 + l];
#pragma unroll
    for (int i = 0; i < 8; ++i) if (p + i >= s1) wv[i] = 0.f;
#pragma unroll
    for (int i = 0; i < 8; ++i) {
      lsum += wv[i];
      accx += wv[i] * bf16_lo(q[i]);
      accy += wv[i] * bf16_hi(q[i]);
    }
  }
  float inv = 1.f / (lsum + 1e-16f);
  uint xr = xresu[(size_t)d * 64 + l];
  float vx = accx * inv + b1[c] + bf16_lo(xr);
  float vy = accy * inv + b1[c + 1] + bf16_hi(xr);
  hpre_bf[(size_t)d * 64 + l] = (uint)rne_bf16(vx) | ((uint)rne_bf16(vy) << 16);
  hlk_bf[(size_t)d * 64 + l] = (uint)rne_bf16(lrelu(vx)) | ((uint)rne_bf16(lrelu(vy)) << 16);
}

__global__ __launch_bounds__(256) void aggr2_k(const ushort* __restrict__ h2b,
                                               const ushort* __restrict__ hresb,
                                               const float* __restrict__ a_s,
                                               const float* __restrict__ a_d,
                                               const int* __restrict__ off,
                                               const int* __restrict__ csr,
                                               const float* __restrict__ b2,
                                               float* __restrict__ out, int n) {
  int w = threadIdx.x >> 6, l = threadIdx.x & 63;
  int d = blockIdx.x * 4 + w;
  if (d >= n) return;
  float adh = a_d[d];
  float ws = __expf(lrelu(a_s[d] + adh));
  float lsum = ws;
  float acc = ws * bf1(h2b[(size_t)d * 64 + l]);

  int s0 = off[d], s1 = off[d + 1];
  for (int p = s0; p < s1; p += 8) {
    int idxs[8]; float wv[8]; float f[8];
#pragma unroll
    for (int i = 0; i < 8; ++i) {
      int jp = (p + i < s1) ? p + i : s1 - 1;
      idxs[i] = csr[jp];
    }
#pragma unroll
    for (int i = 0; i < 8; ++i) wv[i] = __expf(lrelu(a_s[idxs[i]] + adh));
#pragma unroll
    for (int i = 0; i < 8; ++i) f[i] = bf1(h2b[(size_t)idxs[i] * 64 + l]);
#pragma unroll
    for (int i = 0; i < 8; ++i) if (p + i >= s1) wv[i] = 0.f;
#pragma unroll
    for (int i = 0; i < 8; ++i) { lsum += wv[i]; acc += wv[i] * f[i]; }
  }
  float inv = 1.f / (lsum + 1e-16f);
  float z = acc * inv + b2[l] + bf1(hresb[(size_t)d * 64 + l]);
  out[(size_t)d * 64 + l] = lrelu(z);
}

// ---------------- launch ----------------
extern "C" void kernel_launch(void* const* d_in, const int* in_sizes, int n_in,
                              void* d_out, int out_size, void* d_ws, size_t ws_size,
                              hipStream_t stream) {
  const float* x        = (const float*)d_in[0];
  const int*   ei       = (const int*)d_in[1];
  const float* W1       = (const float*)d_in[2];
  const float* att_src1 = (const float*)d_in[3];
  const float* att_dst1 = (const float*)d_in[4];
  const float* b1       = (const float*)d_in[5];
  const float* W2       = (const float*)d_in[6];
  const float* att_src2 = (const float*)d_in[7];
  const float* att_dst2 = (const float*)d_in[8];
  const float* b2       = (const float*)d_in[9];
  const float* res1_w   = (const float*)d_in[10];
  const float* res1_b   = (const float*)d_in[11];
  const float* fc_w     = (const float*)d_in[12];
  const float* fc_b     = (const float*)d_in[13];
  float* out = (float*)d_out;

  const int N = in_sizes[0] / 256;
  const int E = in_sizes[1] / 2;

  ushort* x_bf   = (ushort*)d_ws;                      // N*256
  ushort* h1bf   = x_bf + (size_t)N * 256;             // N*128
  ushort* xresbf = h1bf + (size_t)N * 128;             // N*128
  float*  as1    = (float*)(xresbf + (size_t)N * 128); // N*4
  float*  ad1    = as1 + (size_t)N * 4;                // N*4
  ushort* Wt1    = (ushort*)(ad1 + (size_t)N * 4);     // 256*256
  ushort* fcT    = Wt1 + 256 * 256;                    // 64*128
  ushort* W2T    = fcT + 64 * 128;                     // 64*128
  int* cnt       = (int*)(W2T + 64 * 128);             // N
  int* offp      = cnt + N;                            // N+1
  int* cursor    = offp + N + 1;                       // N
  int* csr       = cursor + N;                         // E
  int* bsum      = csr + E;                            // 64
  // aliases (source regions dead when written)
  uint*   hpre_bf = (uint*)x_bf;
  uint*   hlk_bf  = (uint*)(x_bf + (size_t)N * 128);
  ushort* h2bf    = h1bf;
  ushort* hresb   = xresbf;
  float*  as2 = as1, *ad2 = ad1;

  const int nb = (N + 1023) / 1024;
  const int ngemm = (N + 63) / 64;

  hipMemsetAsync(cnt, 0, (size_t)N * 4, stream);
  prep_all_k<<<2048, 256, 0, stream>>>(x, x_bf, (long)N * 256 / 8, ei, E, cnt,
                                       W1, res1_w, fc_w, W2, Wt1, fcT, W2T);
  scan_block<<<nb, 1024, 0, stream>>>(cnt, offp, bsum, N);
  scan_partials<<<1, 1, 0, stream>>>(bsum, nb, offp, N);
  scan_add<<<nb, 1024, 0, stream>>>(offp, cursor, bsum, N);

  // fused: L1 GEMM (x@[W1|res1]) + att1 + CSR scatter, role-interleaved
  gemm1_scatter_k<<<3 * ngemm, 512, 0, stream>>>(
      x_bf, Wt1, res1_b, att_src1, att_dst1, h1bf, xresbf, as1, ad1,
      ei, E, cursor, csr, N, ngemm);

  aggr1_k<<<(N + 3) / 4, 256, 0, stream>>>((const uint*)h1bf, (const uint*)xresbf, as1, ad1,
                                           offp, csr, b1, hpre_bf, hlk_bf, N);

  // L2 GEMMs + fused att2 (y=0: hres = hpre@fc+b ; y=1: h2 = hlk@W2)
  gemm2_k<<<dim3(ngemm, 2), 512, 0, stream>>>(
      (const ushort*)hpre_bf, (const ushort*)hlk_bf, fcT, fc_b,
      att_src2, att_dst2, hresb, h2bf, as2, ad2, N);

  aggr2_k<<<(N + 3) / 4, 256, 0, stream>>>(h2bf, hresb, as2, ad2, offp, csr, b2, out, N);
}

// Round 6
// 220.340 us; speedup vs baseline: 3.1309x; 1.0593x over previous
//
#include <hip/hip_runtime.h>

typedef __attribute__((ext_vector_type(8))) short short8;
typedef __attribute__((ext_vector_type(4))) float f32x4;

__device__ __forceinline__ ushort rne_bf16(float f) {
  uint u = __float_as_uint(f);
  uint r = (u + 0x7FFFu + ((u >> 16) & 1u)) >> 16;
  return (ushort)r;
}
__device__ __forceinline__ float bf16_lo(uint pair) { return __uint_as_float(pair << 16); }
__device__ __forceinline__ float bf16_hi(uint pair) { return __uint_as_float(pair & 0xffff0000u); }
__device__ __forceinline__ float bf1(ushort v) { return __uint_as_float((uint)v << 16); }
__device__ __forceinline__ float lrelu(float a) { return a >= 0.f ? a : 0.2f * a; }

// ---------------- fused prep: cast x, count degrees, transpose-cast weights ----------------
__global__ __launch_bounds__(256) void prep_all_k(
    const float* __restrict__ x, ushort* __restrict__ x_bf, long nitems,
    const int* __restrict__ ei, int E, int* __restrict__ cnt,
    const float* __restrict__ W1, const float* __restrict__ res1_w,
    const float* __restrict__ fc_w, const float* __restrict__ W2,
    ushort* __restrict__ Wt1, ushort* __restrict__ fcT, ushort* __restrict__ W2T)
{
  const long gstride = (long)gridDim.x * 256;
  const long g0 = (long)blockIdx.x * 256 + threadIdx.x;
  for (long it = g0; it < nitems; it += gstride) {
    long i = it * 8;
    float4 a = *(const float4*)&x[i];
    float4 b = *(const float4*)&x[i + 4];
    ushort o[8] = {rne_bf16(a.x), rne_bf16(a.y), rne_bf16(a.z), rne_bf16(a.w),
                   rne_bf16(b.x), rne_bf16(b.y), rne_bf16(b.z), rne_bf16(b.w)};
    *(uint4*)&x_bf[i] = *(const uint4*)o;
  }
  for (long e = g0; e < E; e += gstride)
    atomicAdd(&cnt[ei[E + e]], 1);
  for (long gi = g0; gi < 81920; gi += gstride) {
    const float* src; ushort* dst; int K, NO; long local;
    if (gi < 32768)            { src = W1;     dst = Wt1;          K = 256; NO = 128; local = gi; }
    else if (gi < 65536)       { src = res1_w; dst = Wt1 + 32768;  K = 256; NO = 128; local = gi - 32768; }
    else if (gi < 65536+8192)  { src = fc_w;   dst = fcT;          K = 128; NO = 64;  local = gi - 65536; }
    else                       { src = W2;     dst = W2T;          K = 128; NO = 64;  local = gi - 65536 - 8192; }
    int n = (int)(local / K), k = (int)(local % K);
    dst[local] = rne_bf16(src[(size_t)k * NO + n]);
  }
}

// ---------------- scans ----------------
__global__ __launch_bounds__(1024) void scan_block(const int* __restrict__ cnt,
                                                   int* __restrict__ off,
                                                   int* __restrict__ bsum, int n) {
  __shared__ int sh[1024];
  int i = blockIdx.x * 1024 + threadIdx.x;
  int v = (i < n) ? cnt[i] : 0;
  sh[threadIdx.x] = v;
  __syncthreads();
  for (int o = 1; o < 1024; o <<= 1) {
    int t = (threadIdx.x >= o) ? sh[threadIdx.x - o] : 0;
    __syncthreads();
    sh[threadIdx.x] += t;
    __syncthreads();
  }
  if (i < n) off[i] = sh[threadIdx.x] - v;
  if (threadIdx.x == 1023) bsum[blockIdx.x] = sh[1023];
}

__global__ void scan_partials(int* __restrict__ bsum, int nb, int* __restrict__ off, int n) {
  int run = 0;
  for (int b = 0; b < nb; ++b) { int t = bsum[b]; bsum[b] = run; run += t; }
  off[n] = run;
}

__global__ __launch_bounds__(1024) void scan_add(int* __restrict__ off, int* __restrict__ cursor,
                                                 const int* __restrict__ bsum, int n) {
  int i = blockIdx.x * 1024 + threadIdx.x;
  if (i < n) { int v = off[i] + bsum[blockIdx.x]; off[i] = v; cursor[i] = v; }
}

__global__ void binit_k(const int* __restrict__ off, int* __restrict__ bcursor, int nbuck) {
  int b = blockIdx.x * 256 + threadIdx.x;
  if (b < nbuck) bcursor[b] = off[b * 128];
}

// ---------------- pass 1: LDS-radix partition of edges into dst-buckets ----------------
// bucket = dst >> 7. Each block: 8192 edges, rank via LDS counters, one global
// atomic per (block,bucket) to reserve a contiguous run, contiguous writes.
__global__ __launch_bounds__(512) void part1_k(const int* __restrict__ ei, int E,
                                               int* __restrict__ bcursor,
                                               uint2* __restrict__ tmp, int nbuck) {
  __shared__ int lcnt[400];
  __shared__ int gbase[400];
  const int tid = threadIdx.x;
  const long base = (long)blockIdx.x * 8192;
  for (int i = tid; i < nbuck; i += 512) lcnt[i] = 0;
  __syncthreads();
  int srcs[16], dsts[16], rk[16];
#pragma unroll
  for (int i = 0; i < 16; ++i) {
    long e = base + i * 512 + tid;
    if (e < E) {
      srcs[i] = ei[e];
      dsts[i] = ei[E + e];
      rk[i] = atomicAdd(&lcnt[dsts[i] >> 7], 1);
    } else dsts[i] = -1;
  }
  __syncthreads();
  for (int b = tid; b < nbuck; b += 512)
    gbase[b] = lcnt[b] ? atomicAdd(&bcursor[b], lcnt[b]) : 0;
  __syncthreads();
#pragma unroll
  for (int i = 0; i < 16; ++i) {
    if (dsts[i] >= 0) {
      int b = dsts[i] >> 7;
      tmp[gbase[b] + rk[i]] = make_uint2((uint)srcs[i], (uint)dsts[i]);
    }
  }
}

// ---------------- L1 GEMM (BM=64, BN=256, 512thr, reg-prefetch pipeline)
//                  + fused att1 + CSR pass-2 tail ----------------
__global__ __launch_bounds__(512) void gemm1_k(
    const ushort* __restrict__ x_bf, const ushort* __restrict__ Wt1,
    const float* __restrict__ res1_b,
    const float* __restrict__ att_s1, const float* __restrict__ att_d1,
    ushort* __restrict__ h1bf, ushort* __restrict__ xresbf,
    float* __restrict__ a_s, float* __restrict__ a_d,
    const uint2* __restrict__ tmp, int E, int* __restrict__ cursor, int* __restrict__ csr,
    int M)
{
  constexpr int LDA = 72;
  __shared__ ushort smem[64 * LDA + 256 * LDA];
  const int bid = blockIdx.x, tid = threadIdx.x;
  ushort* As = smem;
  ushort* Bs = smem + 64 * LDA;
  const int w = tid >> 6, l = tid & 63;
  const int wr = w >> 2, wc = w & 3;           // 2x4 waves
  const int l15 = l & 15, lg = l >> 4;
  const int row0 = bid * 64;
  const int srow = tid >> 3, sch = tid & 7;    // staging: 64(or 256) rows x 8 chunks

  int gra = row0 + srow; if (gra >= M) gra = M - 1;
  const ushort* Ap = x_bf + (size_t)gra * 256 + sch * 8;
  const ushort* Bp = Wt1 + (size_t)srow * 256 + sch * 8;   // +i*64 rows per chunk

  f32x4 acc[2][4] = {};
  float4 raC, rbC0, rbC1, rbC2, rbC3, raN, rbN0, rbN1, rbN2, rbN3;
  raC  = *(const float4*)(Ap);
  rbC0 = *(const float4*)(Bp);
  rbC1 = *(const float4*)(Bp + 64 * 256);
  rbC2 = *(const float4*)(Bp + 128 * 256);
  rbC3 = *(const float4*)(Bp + 192 * 256);

#pragma unroll
  for (int kt = 0; kt < 4; ++kt) {
    __syncthreads();
    *(float4*)&As[srow * LDA + sch * 8] = raC;
    *(float4*)&Bs[(0 * 64 + srow) * LDA + sch * 8] = rbC0;
    *(float4*)&Bs[(1 * 64 + srow) * LDA + sch * 8] = rbC1;
    *(float4*)&Bs[(2 * 64 + srow) * LDA + sch * 8] = rbC2;
    *(float4*)&Bs[(3 * 64 + srow) * LDA + sch * 8] = rbC3;
    __syncthreads();
    if (kt < 3) {
      int k1 = (kt + 1) * 64;
      raN  = *(const float4*)(Ap + k1);
      rbN0 = *(const float4*)(Bp + k1);
      rbN1 = *(const float4*)(Bp + 64 * 256 + k1);
      rbN2 = *(const float4*)(Bp + 128 * 256 + k1);
      rbN3 = *(const float4*)(Bp + 192 * 256 + k1);
    }
    short8 aF[2][2], bF[4][2];
#pragma unroll
    for (int m = 0; m < 2; ++m)
#pragma unroll
      for (int kk = 0; kk < 2; ++kk)
        aF[m][kk] = *(const short8*)&As[(wr * 32 + m * 16 + l15) * LDA + kk * 32 + lg * 8];
#pragma unroll
    for (int n = 0; n < 4; ++n)
#pragma unroll
      for (int kk = 0; kk < 2; ++kk)
        bF[n][kk] = *(const short8*)&Bs[(wc * 64 + n * 16 + l15) * LDA + kk * 32 + lg * 8];
#pragma unroll
    for (int m = 0; m < 2; ++m)
#pragma unroll
      for (int n = 0; n < 4; ++n)
#pragma unroll
        for (int kk = 0; kk < 2; ++kk)
          acc[m][n] = __builtin_amdgcn_mfma_f32_16x16x32_bf16(aF[m][kk], bF[n][kk], acc[m][n], 0, 0, 0);
    raC = raN; rbC0 = rbN0; rbC1 = rbN1; rbC2 = rbN2; rbC3 = rbN3;
  }
  __syncthreads();

  // stage C tile (64 x 256 bf16) in LDS; bias only on res-half
  ushort* Cs = smem;
#pragma unroll
  for (int m = 0; m < 2; ++m)
#pragma unroll
    for (int n = 0; n < 4; ++n)
#pragma unroll
      for (int j = 0; j < 4; ++j) {
        int rl = wr * 32 + m * 16 + lg * 4 + j;
        int col = wc * 64 + n * 16 + l15;
        float v = acc[m][n][j] + (col >= 128 ? res1_b[col - 128] : 0.f);
        Cs[rl * 256 + col] = rne_bf16(v);
      }
  __syncthreads();

  // fused att1: thread t -> row t>>3, seg t&7 (16 cols of h1); head = seg>>1
  {
    int r = tid >> 3, s = tid & 7, h = s >> 1;
    int gr = row0 + r;
    float ps = 0.f, pd = 0.f;
#pragma unroll
    for (int i = 0; i < 16; ++i) {
      int col = s * 16 + i;
      float v = bf1(Cs[r * 256 + col]);
      ps += v * att_s1[h * 32 + (col & 31)];
      pd += v * att_d1[h * 32 + (col & 31)];
    }
    ps += __shfl_xor(ps, 1, 64);
    pd += __shfl_xor(pd, 1, 64);
    if (!(s & 1) && gr < M) { a_s[gr * 4 + h] = ps; a_d[gr * 4 + h] = pd; }
  }

  // coalesced split copy
#pragma unroll
  for (int idx = tid; idx < 2048; idx += 512) {
    int row = idx >> 5, c16 = idx & 31;
    int gr = row0 + row;
    if (gr < M) {
      uint4 v = *(const uint4*)&Cs[row * 256 + c16 * 8];
      if (c16 < 16) *(uint4*)&h1bf[(size_t)gr * 128 + c16 * 8] = v;
      else          *(uint4*)&xresbf[(size_t)gr * 128 + (c16 - 16) * 8] = v;
    }
  }

  // CSR pass-2 tail: bucket-grouped tmp -> final csr (localized writes)
  {
    long stride = (long)gridDim.x * 512;
    for (long e = (long)bid * 512 + tid; e < E; e += stride) {
      uint2 t = tmp[e];
      int p = atomicAdd(&cursor[t.y], 1);
      csr[p] = (int)t.x;
    }
  }
}

// ---------------- L2 GEMM (BM=64, BN=64, 512thr, y: 0=hres 1=h2) + att2 ----------------
__global__ __launch_bounds__(512) void gemm2_k(
    const ushort* __restrict__ hpre, const ushort* __restrict__ hlk,
    const ushort* __restrict__ fcT,            // W2T = fcT + 64*128
    const float* __restrict__ fc_b,
    const float* __restrict__ att_s2, const float* __restrict__ att_d2,
    ushort* __restrict__ hresb, ushort* __restrict__ h2bf,
    float* __restrict__ a_s, float* __restrict__ a_d, int M)
{
  constexpr int LDA = 72;
  __shared__ ushort smem[64 * LDA + 64 * LDA];
  const int tid = threadIdx.x, y = blockIdx.y;
  const ushort* A = y ? hlk : hpre;
  const ushort* B = fcT + (size_t)y * 64 * 128;
  ushort* out = y ? h2bf : hresb;
  const int row0 = blockIdx.x * 64;
  ushort* As = smem;
  ushort* Bs = smem + 64 * LDA;
  const int w = tid >> 6, l = tid & 63;
  const int wr = w >> 1, wc = w & 1;           // 4x2 waves
  const int l15 = l & 15, lg = l >> 4;
  const int srow = tid >> 3, sch = tid & 7;

  int gra = row0 + srow; if (gra >= M) gra = M - 1;
  const ushort* Ap = A + (size_t)gra * 128 + sch * 8;
  const ushort* Bp = B + (size_t)srow * 128 + sch * 8;

  f32x4 acc[2] = {};
  float4 raC = *(const float4*)(Ap);
  float4 rbC = *(const float4*)(Bp);
  float4 raN, rbN;

#pragma unroll
  for (int kt = 0; kt < 2; ++kt) {
    __syncthreads();
    *(float4*)&As[srow * LDA + sch * 8] = raC;
    *(float4*)&Bs[srow * LDA + sch * 8] = rbC;
    __syncthreads();
    if (kt < 1) { raN = *(const float4*)(Ap + 64); rbN = *(const float4*)(Bp + 64); }

    short8 aF[2], bF[2][2];
#pragma unroll
    for (int kk = 0; kk < 2; ++kk)
      aF[kk] = *(const short8*)&As[(wr * 16 + l15) * LDA + kk * 32 + lg * 8];
#pragma unroll
    for (int n = 0; n < 2; ++n)
#pragma unroll
      for (int kk = 0; kk < 2; ++kk)
        bF[n][kk] = *(const short8*)&Bs[(wc * 32 + n * 16 + l15) * LDA + kk * 32 + lg * 8];
#pragma unroll
    for (int n = 0; n < 2; ++n)
#pragma unroll
      for (int kk = 0; kk < 2; ++kk)
        acc[n] = __builtin_amdgcn_mfma_f32_16x16x32_bf16(aF[kk], bF[n][kk], acc[n], 0, 0, 0);
    raC = raN; rbC = rbN;
  }
  __syncthreads();

  ushort* Cs = smem;
#pragma unroll
  for (int n = 0; n < 2; ++n)
#pragma unroll
    for (int j = 0; j < 4; ++j) {
      int rl = wr * 16 + lg * 4 + j;
      int col = wc * 32 + n * 16 + l15;
      float v = acc[n][j] + (y == 0 ? fc_b[col] : 0.f);
      Cs[rl * 64 + col] = rne_bf16(v);
    }
  __syncthreads();

  if (y == 1) {
    int r = tid >> 3, s = tid & 7;
    int gr = row0 + r;
    float ps = 0.f, pd = 0.f;
#pragma unroll
    for (int i = 0; i < 8; ++i) {
      int col = s * 8 + i;
      float v = bf1(Cs[r * 64 + col]);
      ps += v * att_s2[col];
      pd += v * att_d2[col];
    }
    ps += __shfl_xor(ps, 1, 64); pd += __shfl_xor(pd, 1, 64);
    ps += __shfl_xor(ps, 2, 64); pd += __shfl_xor(pd, 2, 64);
    ps += __shfl_xor(ps, 4, 64); pd += __shfl_xor(pd, 4, 64);
    if (s == 0 && gr < M) { a_s[gr] = ps; a_d[gr] = pd; }
  }

  {
    int row = tid >> 3, c16 = tid & 7;
    int gr = row0 + row;
    if (gr < M)
      *(uint4*)&out[(size_t)gr * 64 + c16 * 8] = *(const uint4*)&Cs[row * 64 + c16 * 8];
  }
}

// ---------------- aggregation: max-free softmax, batched-8 ----------------
__global__ __launch_bounds__(256) void aggr1_k(const uint* __restrict__ h1u,
                                               const uint* __restrict__ xresu,
                                               const float* __restrict__ a_s,
                                               const float* __restrict__ a_d,
                                               const int* __restrict__ off,
                                               const int* __restrict__ csr,
                                               const float* __restrict__ b1,
                                               uint* __restrict__ hpre_bf,
                                               uint* __restrict__ hlk_bf, int n) {
  int w = threadIdx.x >> 6, l = threadIdx.x & 63;
  int d = blockIdx.x * 4 + w;
  if (d >= n) return;
  int h = l >> 4, c = l * 2;
  float adh = a_d[d * 4 + h];
  float ws = __expf(lrelu(a_s[d * 4 + h] + adh));   // self loop
  uint pd = h1u[(size_t)d * 64 + l];
  float lsum = ws, accx = ws * bf16_lo(pd), accy = ws * bf16_hi(pd);

  int s0 = off[d], s1 = off[d + 1];
  for (int p = s0; p < s1; p += 8) {
    int idxs[8]; float wv[8]; uint q[8];
#pragma unroll
    for (int i = 0; i < 8; ++i) {
      int jp = (p + i < s1) ? p + i : s1 - 1;
      idxs[i] = csr[jp];
    }
#pragma unroll
    for (int i = 0; i < 8; ++i) wv[i] = __expf(lrelu(a_s[idxs[i] * 4 + h] + adh));
#pragma unroll
    for (int i = 0; i < 8; ++i) q[i] = h1u[(size_t)idxs[i] * 64 + l];
#pragma unroll
    for (int i = 0; i < 8; ++i) if (p + i >= s1) wv[i] = 0.f;
#pragma unroll
    for (int i = 0; i < 8; ++i) {
      lsum += wv[i];
      accx += wv[i] * bf16_lo(q[i]);
      accy += wv[i] * bf16_hi(q[i]);
    }
  }
  float inv = 1.f / (lsum + 1e-16f);
  uint xr = xresu[(size_t)d * 64 + l];
  float vx = accx * inv + b1[c] + bf16_lo(xr);
  float vy = accy * inv + b1[c + 1] + bf16_hi(xr);
  hpre_bf[(size_t)d * 64 + l] = (uint)rne_bf16(vx) | ((uint)rne_bf16(vy) << 16);
  hlk_bf[(size_t)d * 64 + l] = (uint)rne_bf16(lrelu(vx)) | ((uint)rne_bf16(lrelu(vy)) << 16);
}

__global__ __launch_bounds__(256) void aggr2_k(const ushort* __restrict__ h2b,
                                               const ushort* __restrict__ hresb,
                                               const float* __restrict__ a_s,
                                               const float* __restrict__ a_d,
                                               const int* __restrict__ off,
                                               const int* __restrict__ csr,
                                               const float* __restrict__ b2,
                                               float* __restrict__ out, int n) {
  int w = threadIdx.x >> 6, l = threadIdx.x & 63;
  int d = blockIdx.x * 4 + w;
  if (d >= n) return;
  float adh = a_d[d];
  float ws = __expf(lrelu(a_s[d] + adh));
  float lsum = ws;
  float acc = ws * bf1(h2b[(size_t)d * 64 + l]);

  int s0 = off[d], s1 = off[d + 1];
  for (int p = s0; p < s1; p += 8) {
    int idxs[8]; float wv[8]; float f[8];
#pragma unroll
    for (int i = 0; i < 8; ++i) {
      int jp = (p + i < s1) ? p + i : s1 - 1;
      idxs[i] = csr[jp];
    }
#pragma unroll
    for (int i = 0; i < 8; ++i) wv[i] = __expf(lrelu(a_s[idxs[i]] + adh));
#pragma unroll
    for (int i = 0; i < 8; ++i) f[i] = bf1(h2b[(size_t)idxs[i] * 64 + l]);
#pragma unroll
    for (int i = 0; i < 8; ++i) if (p + i >= s1) wv[i] = 0.f;
#pragma unroll
    for (int i = 0; i < 8; ++i) { lsum += wv[i]; acc += wv[i] * f[i]; }
  }
  float inv = 1.f / (lsum + 1e-16f);
  float z = acc * inv + b2[l] + bf1(hresb[(size_t)d * 64 + l]);
  out[(size_t)d * 64 + l] = lrelu(z);
}

// ---------------- launch ----------------
extern "C" void kernel_launch(void* const* d_in, const int* in_sizes, int n_in,
                              void* d_out, int out_size, void* d_ws, size_t ws_size,
                              hipStream_t stream) {
  const float* x        = (const float*)d_in[0];
  const int*   ei       = (const int*)d_in[1];
  const float* W1       = (const float*)d_in[2];
  const float* att_src1 = (const float*)d_in[3];
  const float* att_dst1 = (const float*)d_in[4];
  const float* b1       = (const float*)d_in[5];
  const float* W2       = (const float*)d_in[6];
  const float* att_src2 = (const float*)d_in[7];
  const float* att_dst2 = (const float*)d_in[8];
  const float* b2       = (const float*)d_in[9];
  const float* res1_w   = (const float*)d_in[10];
  const float* res1_b   = (const float*)d_in[11];
  const float* fc_w     = (const float*)d_in[12];
  const float* fc_b     = (const float*)d_in[13];
  float* out = (float*)d_out;

  const int N = in_sizes[0] / 256;
  const int E = in_sizes[1] / 2;
  const int nbuck = (N + 127) / 128;

  ushort* x_bf   = (ushort*)d_ws;                      // N*256
  ushort* h1bf   = x_bf + (size_t)N * 256;             // N*128
  ushort* xresbf = h1bf + (size_t)N * 128;             // N*128
  float*  as1    = (float*)(xresbf + (size_t)N * 128); // N*4
  float*  ad1    = as1 + (size_t)N * 4;                // N*4
  ushort* Wt1    = (ushort*)(ad1 + (size_t)N * 4);     // 256*256
  ushort* fcT    = Wt1 + 256 * 256;                    // 64*128
  ushort* W2T    = fcT + 64 * 128;                     // 64*128
  int* cnt       = (int*)(W2T + 64 * 128);             // N
  int* offp      = cnt + N;                            // N+1
  int* cursor    = offp + N + 1;                       // N
  int* csr       = cursor + N;                         // E
  int* bsum      = csr + E;                            // 64
  int* bcursor   = bsum + 64;                          // nbuck (<=512)
  uint2* tmp     = (uint2*)(((uintptr_t)(bcursor + 512) + 7) & ~(uintptr_t)7);  // E uint2
  // aliases
  uint*   hpre_bf = (uint*)x_bf;
  uint*   hlk_bf  = (uint*)(x_bf + (size_t)N * 128);
  ushort* h2bf    = h1bf;
  ushort* hresb   = xresbf;
  float*  as2 = as1, *ad2 = ad1;

  const int nb = (N + 1023) / 1024;
  const int ngemm = (N + 63) / 64;

  hipMemsetAsync(cnt, 0, (size_t)N * 4, stream);
  prep_all_k<<<2048, 256, 0, stream>>>(x, x_bf, (long)N * 256 / 8, ei, E, cnt,
                                       W1, res1_w, fc_w, W2, Wt1, fcT, W2T);
  scan_block<<<nb, 1024, 0, stream>>>(cnt, offp, bsum, N);
  scan_partials<<<1, 1, 0, stream>>>(bsum, nb, offp, N);
  scan_add<<<nb, 1024, 0, stream>>>(offp, cursor, bsum, N);
  binit_k<<<(nbuck + 255) / 256, 256, 0, stream>>>(offp, bcursor, nbuck);
  part1_k<<<(E + 8191) / 8192, 512, 0, stream>>>(ei, E, bcursor, tmp, nbuck);

  // L1 GEMM + fused att1 + CSR finalize tail
  gemm1_k<<<ngemm, 512, 0, stream>>>(x_bf, Wt1, res1_b, att_src1, att_dst1,
                                     h1bf, xresbf, as1, ad1, tmp, E, cursor, csr, N);

  aggr1_k<<<(N + 3) / 4, 256, 0, stream>>>((const uint*)h1bf, (const uint*)xresbf, as1, ad1,
                                           offp, csr, b1, hpre_bf, hlk_bf, N);

  gemm2_k<<<dim3(ngemm, 2), 512, 0, stream>>>(
      (const ushort*)hpre_bf, (const ushort*)hlk_bf, fcT, fc_b,
      att_src2, att_dst2, hresb, h2bf, as2, ad2, N);

  aggr2_k<<<(N + 3) / 4, 256, 0, stream>>>(h2bf, hresb, as2, ad2, offp, csr, b2, out, N);
}

// Round 7
// 206.291 us; speedup vs baseline: 3.3441x; 1.0681x over previous
//
#include <hip/hip_runtime.h>

typedef __attribute__((ext_vector_type(8))) short short8;
typedef __attribute__((ext_vector_type(4))) float f32x4;

__device__ __forceinline__ ushort rne_bf16(float f) {
  uint u = __float_as_uint(f);
  uint r = (u + 0x7FFFu + ((u >> 16) & 1u)) >> 16;
  return (ushort)r;
}
__device__ __forceinline__ float bf16_lo(uint pair) { return __uint_as_float(pair << 16); }
__device__ __forceinline__ float bf16_hi(uint pair) { return __uint_as_float(pair & 0xffff0000u); }
__device__ __forceinline__ float bf1(ushort v) { return __uint_as_float((uint)v << 16); }
__device__ __forceinline__ float lrelu(float a) { return a >= 0.f ? a : 0.2f * a; }

// ---------------- fused prep: cast x, count degrees, transpose-cast weights ----------------
__global__ __launch_bounds__(256) void prep_all_k(
    const float* __restrict__ x, ushort* __restrict__ x_bf, long nitems,
    const int* __restrict__ ei, int E, int* __restrict__ cnt,
    const float* __restrict__ W1, const float* __restrict__ res1_w,
    const float* __restrict__ fc_w, const float* __restrict__ W2,
    ushort* __restrict__ Wt1, ushort* __restrict__ fcT, ushort* __restrict__ W2T)
{
  const long gstride = (long)gridDim.x * 256;
  const long g0 = (long)blockIdx.x * 256 + threadIdx.x;
  for (long it = g0; it < nitems; it += gstride) {
    long i = it * 8;
    float4 a = *(const float4*)&x[i];
    float4 b = *(const float4*)&x[i + 4];
    ushort o[8] = {rne_bf16(a.x), rne_bf16(a.y), rne_bf16(a.z), rne_bf16(a.w),
                   rne_bf16(b.x), rne_bf16(b.y), rne_bf16(b.z), rne_bf16(b.w)};
    *(uint4*)&x_bf[i] = *(const uint4*)o;
  }
  for (long e = g0; e < E; e += gstride)
    atomicAdd(&cnt[ei[E + e]], 1);
  for (long gi = g0; gi < 81920; gi += gstride) {
    const float* src; ushort* dst; int K, NO; long local;
    if (gi < 32768)            { src = W1;     dst = Wt1;          K = 256; NO = 128; local = gi; }
    else if (gi < 65536)       { src = res1_w; dst = Wt1 + 32768;  K = 256; NO = 128; local = gi - 32768; }
    else if (gi < 65536+8192)  { src = fc_w;   dst = fcT;          K = 128; NO = 64;  local = gi - 65536; }
    else                       { src = W2;     dst = W2T;          K = 128; NO = 64;  local = gi - 65536 - 8192; }
    int n = (int)(local / K), k = (int)(local % K);
    dst[local] = rne_bf16(src[(size_t)k * NO + n]);
  }
}

// ---------------- scans ----------------
__global__ __launch_bounds__(1024) void scan_block(const int* __restrict__ cnt,
                                                   int* __restrict__ off,
                                                   int* __restrict__ bsum, int n) {
  __shared__ int sh[1024];
  int i = blockIdx.x * 1024 + threadIdx.x;
  int v = (i < n) ? cnt[i] : 0;
  sh[threadIdx.x] = v;
  __syncthreads();
  for (int o = 1; o < 1024; o <<= 1) {
    int t = (threadIdx.x >= o) ? sh[threadIdx.x - o] : 0;
    __syncthreads();
    sh[threadIdx.x] += t;
    __syncthreads();
  }
  if (i < n) off[i] = sh[threadIdx.x] - v;
  if (threadIdx.x == 1023) bsum[blockIdx.x] = sh[1023];
}

__global__ void scan_partials(int* __restrict__ bsum, int nb, int* __restrict__ off, int n) {
  int run = 0;
  for (int b = 0; b < nb; ++b) { int t = bsum[b]; bsum[b] = run; run += t; }
  off[n] = run;
}

__global__ __launch_bounds__(1024) void scan_add(int* __restrict__ off,
                                                 const int* __restrict__ bsum, int n) {
  int i = blockIdx.x * 1024 + threadIdx.x;
  if (i < n) off[i] += bsum[blockIdx.x];
}

__global__ void binit_k(const int* __restrict__ off, int* __restrict__ bcursor, int nbuck) {
  int b = blockIdx.x * 256 + threadIdx.x;
  if (b < nbuck) bcursor[b] = off[b * 128];
}

// ---------------- pass 1: LDS-radix partition of edges into dst-buckets ----------------
__global__ __launch_bounds__(512) void part1_k(const int* __restrict__ ei, int E,
                                               int* __restrict__ bcursor,
                                               uint2* __restrict__ tmp, int nbuck) {
  __shared__ int lcnt[400];
  __shared__ int gbase[400];
  const int tid = threadIdx.x;
  const long base = (long)blockIdx.x * 8192;
  for (int i = tid; i < nbuck; i += 512) lcnt[i] = 0;
  __syncthreads();
  int srcs[16], dsts[16], rk[16];
#pragma unroll
  for (int i = 0; i < 16; ++i) {
    long e = base + i * 512 + tid;
    if (e < E) {
      srcs[i] = ei[e];
      dsts[i] = ei[E + e];
      rk[i] = atomicAdd(&lcnt[dsts[i] >> 7], 1);
    } else dsts[i] = -1;
  }
  __syncthreads();
  for (int b = tid; b < nbuck; b += 512)
    gbase[b] = lcnt[b] ? atomicAdd(&bcursor[b], lcnt[b]) : 0;
  __syncthreads();
#pragma unroll
  for (int i = 0; i < 16; ++i) {
    if (dsts[i] >= 0) {
      int b = dsts[i] >> 7;
      tmp[gbase[b] + rk[i]] = make_uint2((uint)srcs[i], (uint)dsts[i]);
    }
  }
}

// ---------------- L1 GEMM (BM=64, BN=256, 512thr, reg-prefetch pipeline)
//   + fused att1 + CSR pass-2 (bucket-owned counting sort, no global atomics) ----------------
__global__ __launch_bounds__(512) void gemm1_k(
    const ushort* __restrict__ x_bf, const ushort* __restrict__ Wt1,
    const float* __restrict__ res1_b,
    const float* __restrict__ att_s1, const float* __restrict__ att_d1,
    ushort* __restrict__ h1bf, ushort* __restrict__ xresbf,
    float* __restrict__ a_s, float* __restrict__ a_d,
    const uint2* __restrict__ tmp, const int* __restrict__ offp,
    int* __restrict__ csr, int nbuck, int M)
{
  constexpr int LDA = 72;
  __shared__ ushort smem[64 * LDA + 256 * LDA];
  const int bid = blockIdx.x, tid = threadIdx.x;
  ushort* As = smem;
  ushort* Bs = smem + 64 * LDA;
  const int w = tid >> 6, l = tid & 63;
  const int wr = w >> 2, wc = w & 3;           // 2x4 waves
  const int l15 = l & 15, lg = l >> 4;
  const int row0 = bid * 64;
  const int srow = tid >> 3, sch = tid & 7;

  int gra = row0 + srow; if (gra >= M) gra = M - 1;
  const ushort* Ap = x_bf + (size_t)gra * 256 + sch * 8;
  const ushort* Bp = Wt1 + (size_t)srow * 256 + sch * 8;

  f32x4 acc[2][4] = {};
  float4 raC, rbC0, rbC1, rbC2, rbC3, raN, rbN0, rbN1, rbN2, rbN3;
  raC  = *(const float4*)(Ap);
  rbC0 = *(const float4*)(Bp);
  rbC1 = *(const float4*)(Bp + 64 * 256);
  rbC2 = *(const float4*)(Bp + 128 * 256);
  rbC3 = *(const float4*)(Bp + 192 * 256);

#pragma unroll
  for (int kt = 0; kt < 4; ++kt) {
    __syncthreads();
    *(float4*)&As[srow * LDA + sch * 8] = raC;
    *(float4*)&Bs[(0 * 64 + srow) * LDA + sch * 8] = rbC0;
    *(float4*)&Bs[(1 * 64 + srow) * LDA + sch * 8] = rbC1;
    *(float4*)&Bs[(2 * 64 + srow) * LDA + sch * 8] = rbC2;
    *(float4*)&Bs[(3 * 64 + srow) * LDA + sch * 8] = rbC3;
    __syncthreads();
    if (kt < 3) {
      int k1 = (kt + 1) * 64;
      raN  = *(const float4*)(Ap + k1);
      rbN0 = *(const float4*)(Bp + k1);
      rbN1 = *(const float4*)(Bp + 64 * 256 + k1);
      rbN2 = *(const float4*)(Bp + 128 * 256 + k1);
      rbN3 = *(const float4*)(Bp + 192 * 256 + k1);
    }
    short8 aF[2][2], bF[4][2];
#pragma unroll
    for (int m = 0; m < 2; ++m)
#pragma unroll
      for (int kk = 0; kk < 2; ++kk)
        aF[m][kk] = *(const short8*)&As[(wr * 32 + m * 16 + l15) * LDA + kk * 32 + lg * 8];
#pragma unroll
    for (int n = 0; n < 4; ++n)
#pragma unroll
      for (int kk = 0; kk < 2; ++kk)
        bF[n][kk] = *(const short8*)&Bs[(wc * 64 + n * 16 + l15) * LDA + kk * 32 + lg * 8];
#pragma unroll
    for (int m = 0; m < 2; ++m)
#pragma unroll
      for (int n = 0; n < 4; ++n)
#pragma unroll
        for (int kk = 0; kk < 2; ++kk)
          acc[m][n] = __builtin_amdgcn_mfma_f32_16x16x32_bf16(aF[m][kk], bF[n][kk], acc[m][n], 0, 0, 0);
    raC = raN; rbC0 = rbN0; rbC1 = rbN1; rbC2 = rbN2; rbC3 = rbN3;
  }
  __syncthreads();

  // stage C tile (64 x 256 bf16) in LDS; bias only on res-half
  ushort* Cs = smem;
#pragma unroll
  for (int m = 0; m < 2; ++m)
#pragma unroll
    for (int n = 0; n < 4; ++n)
#pragma unroll
      for (int j = 0; j < 4; ++j) {
        int rl = wr * 32 + m * 16 + lg * 4 + j;
        int col = wc * 64 + n * 16 + l15;
        float v = acc[m][n][j] + (col >= 128 ? res1_b[col - 128] : 0.f);
        Cs[rl * 256 + col] = rne_bf16(v);
      }
  __syncthreads();

  // fused att1
  {
    int r = tid >> 3, s = tid & 7, h = s >> 1;
    int gr = row0 + r;
    float ps = 0.f, pd = 0.f;
#pragma unroll
    for (int i = 0; i < 16; ++i) {
      int col = s * 16 + i;
      float v = bf1(Cs[r * 256 + col]);
      ps += v * att_s1[h * 32 + (col & 31)];
      pd += v * att_d1[h * 32 + (col & 31)];
    }
    ps += __shfl_xor(ps, 1, 64);
    pd += __shfl_xor(pd, 1, 64);
    if (!(s & 1) && gr < M) { a_s[gr * 4 + h] = ps; a_d[gr * 4 + h] = pd; }
  }

  // coalesced split copy
#pragma unroll
  for (int idx = tid; idx < 2048; idx += 512) {
    int row = idx >> 5, c16 = idx & 31;
    int gr = row0 + row;
    if (gr < M) {
      uint4 v = *(const uint4*)&Cs[row * 256 + c16 * 8];
      if (c16 < 16) *(uint4*)&h1bf[(size_t)gr * 128 + c16 * 8] = v;
      else          *(uint4*)&xresbf[(size_t)gr * 128 + (c16 - 16) * 8] = v;
    }
  }

  // CSR pass-2: block bid owns bucket bid entirely -> exclusive, full-line csr writes
  if (bid < nbuck) {
    __syncthreads();                       // done reading Cs; reuse smem
    int* lcnt  = (int*)smem;               // 128 counters
    int* dbase = lcnt + 128;               // per-dst base (relative to bucket base)
    const int vbase = bid * 128;
    const int endi = (vbase + 128 < M) ? vbase + 128 : M;
    const int base0 = offp[vbase];
    const int bend  = offp[endi];
    if (tid < 128) {
      int gi = vbase + tid;
      dbase[tid] = ((gi < M) ? offp[gi] : bend) - base0;
      lcnt[tid] = 0;
    }
    __syncthreads();
    for (int e = base0 + tid; e < bend; e += 512) {
      uint2 t = tmp[e];
      int li = (int)t.y - vbase;
      int r = atomicAdd(&lcnt[li], 1);
      csr[base0 + dbase[li] + r] = (int)t.x;
    }
  }
}

// ---------------- L2 GEMM (BM=64, BN=64, 512thr, y: 0=hres 1=h2) + att2 ----------------
__global__ __launch_bounds__(512) void gemm2_k(
    const ushort* __restrict__ hpre, const ushort* __restrict__ hlk,
    const ushort* __restrict__ fcT,            // W2T = fcT + 64*128
    const float* __restrict__ fc_b,
    const float* __restrict__ att_s2, const float* __restrict__ att_d2,
    ushort* __restrict__ hresb, ushort* __restrict__ h2bf,
    float* __restrict__ a_s, float* __restrict__ a_d, int M)
{
  constexpr int LDA = 72;
  __shared__ ushort smem[64 * LDA + 64 * LDA];
  const int tid = threadIdx.x, y = blockIdx.y;
  const ushort* A = y ? hlk : hpre;
  const ushort* B = fcT + (size_t)y * 64 * 128;
  ushort* out = y ? h2bf : hresb;
  const int row0 = blockIdx.x * 64;
  ushort* As = smem;
  ushort* Bs = smem + 64 * LDA;
  const int w = tid >> 6, l = tid & 63;
  const int wr = w >> 1, wc = w & 1;
  const int l15 = l & 15, lg = l >> 4;
  const int srow = tid >> 3, sch = tid & 7;

  int gra = row0 + srow; if (gra >= M) gra = M - 1;
  const ushort* Ap = A + (size_t)gra * 128 + sch * 8;
  const ushort* Bp = B + (size_t)srow * 128 + sch * 8;

  f32x4 acc[2] = {};
  float4 raC = *(const float4*)(Ap);
  float4 rbC = *(const float4*)(Bp);
  float4 raN, rbN;

#pragma unroll
  for (int kt = 0; kt < 2; ++kt) {
    __syncthreads();
    *(float4*)&As[srow * LDA + sch * 8] = raC;
    *(float4*)&Bs[srow * LDA + sch * 8] = rbC;
    __syncthreads();
    if (kt < 1) { raN = *(const float4*)(Ap + 64); rbN = *(const float4*)(Bp + 64); }

    short8 aF[2], bF[2][2];
#pragma unroll
    for (int kk = 0; kk < 2; ++kk)
      aF[kk] = *(const short8*)&As[(wr * 16 + l15) * LDA + kk * 32 + lg * 8];
#pragma unroll
    for (int n = 0; n < 2; ++n)
#pragma unroll
      for (int kk = 0; kk < 2; ++kk)
        bF[n][kk] = *(const short8*)&Bs[(wc * 32 + n * 16 + l15) * LDA + kk * 32 + lg * 8];
#pragma unroll
    for (int n = 0; n < 2; ++n)
#pragma unroll
      for (int kk = 0; kk < 2; ++kk)
        acc[n] = __builtin_amdgcn_mfma_f32_16x16x32_bf16(aF[kk], bF[n][kk], acc[n], 0, 0, 0);
    raC = raN; rbC = rbN;
  }
  __syncthreads();

  ushort* Cs = smem;
#pragma unroll
  for (int n = 0; n < 2; ++n)
#pragma unroll
    for (int j = 0; j < 4; ++j) {
      int rl = wr * 16 + lg * 4 + j;
      int col = wc * 32 + n * 16 + l15;
      float v = acc[n][j] + (y == 0 ? fc_b[col] : 0.f);
      Cs[rl * 64 + col] = rne_bf16(v);
    }
  __syncthreads();

  if (y == 1) {
    int r = tid >> 3, s = tid & 7;
    int gr = row0 + r;
    float ps = 0.f, pd = 0.f;
#pragma unroll
    for (int i = 0; i < 8; ++i) {
      int col = s * 8 + i;
      float v = bf1(Cs[r * 64 + col]);
      ps += v * att_s2[col];
      pd += v * att_d2[col];
    }
    ps += __shfl_xor(ps, 1, 64); pd += __shfl_xor(pd, 1, 64);
    ps += __shfl_xor(ps, 2, 64); pd += __shfl_xor(pd, 2, 64);
    ps += __shfl_xor(ps, 4, 64); pd += __shfl_xor(pd, 4, 64);
    if (s == 0 && gr < M) { a_s[gr] = ps; a_d[gr] = pd; }
  }

  {
    int row = tid >> 3, c16 = tid & 7;
    int gr = row0 + row;
    if (gr < M)
      *(uint4*)&out[(size_t)gr * 64 + c16 * 8] = *(const uint4*)&Cs[row * 64 + c16 * 8];
  }
}

// ---------------- aggregation: max-free softmax, batched-8 ----------------
__global__ __launch_bounds__(256) void aggr1_k(const uint* __restrict__ h1u,
                                               const uint* __restrict__ xresu,
                                               const float* __restrict__ a_s,
                                               const float* __restrict__ a_d,
                                               const int* __restrict__ off,
                                               const int* __restrict__ csr,
                                               const float* __restrict__ b1,
                                               uint* __restrict__ hpre_bf,
                                               uint* __restrict__ hlk_bf, int n) {
  int w = threadIdx.x >> 6, l = threadIdx.x & 63;
  int d = blockIdx.x * 4 + w;
  if (d >= n) return;
  int h = l >> 4, c = l * 2;
  float adh = a_d[d * 4 + h];
  float ws = __expf(lrelu(a_s[d * 4 + h] + adh));   // self loop
  uint pd = h1u[(size_t)d * 64 + l];
  float lsum = ws, accx = ws * bf16_lo(pd), accy = ws * bf16_hi(pd);

  int s0 = off[d], s1 = off[d + 1];
  for (int p = s0; p < s1; p += 8) {
    int idxs[8]; float wv[8]; uint q[8];
#pragma unroll
    for (int i = 0; i < 8; ++i) {
      int jp = (p + i < s1) ? p + i : s1 - 1;
      idxs[i] = csr[jp];
    }
#pragma unroll
    for (int i = 0; i < 8; ++i) wv[i] = __expf(lrelu(a_s[idxs[i] * 4 + h] + adh));
#pragma unroll
    for (int i = 0; i < 8; ++i) q[i] = h1u[(size_t)idxs[i] * 64 + l];
#pragma unroll
    for (int i = 0; i < 8; ++i) if (p + i >= s1) wv[i] = 0.f;
#pragma unroll
    for (int i = 0; i < 8; ++i) {
      lsum += wv[i];
      accx += wv[i] * bf16_lo(q[i]);
      accy += wv[i] * bf16_hi(q[i]);
    }
  }
  float inv = 1.f / (lsum + 1e-16f);
  uint xr = xresu[(size_t)d * 64 + l];
  float vx = accx * inv + b1[c] + bf16_lo(xr);
  float vy = accy * inv + b1[c + 1] + bf16_hi(xr);
  hpre_bf[(size_t)d * 64 + l] = (uint)rne_bf16(vx) | ((uint)rne_bf16(vy) << 16);
  hlk_bf[(size_t)d * 64 + l] = (uint)rne_bf16(lrelu(vx)) | ((uint)rne_bf16(lrelu(vy)) << 16);
}

__global__ __launch_bounds__(256) void aggr2_k(const ushort* __restrict__ h2b,
                                               const ushort* __restrict__ hresb,
                                               const float* __restrict__ a_s,
                                               const float* __restrict__ a_d,
                                               const int* __restrict__ off,
                                               const int* __restrict__ csr,
                                               const float* __restrict__ b2,
                                               float* __restrict__ out, int n) {
  int w = threadIdx.x >> 6, l = threadIdx.x & 63;
  int d = blockIdx.x * 4 + w;
  if (d >= n) return;
  float adh = a_d[d];
  float ws = __expf(lrelu(a_s[d] + adh));
  float lsum = ws;
  float acc = ws * bf1(h2b[(size_t)d * 64 + l]);

  int s0 = off[d], s1 = off[d + 1];
  for (int p = s0; p < s1; p += 8) {
    int idxs[8]; float wv[8]; float f[8];
#pragma unroll
    for (int i = 0; i < 8; ++i) {
      int jp = (p + i < s1) ? p + i : s1 - 1;
      idxs[i] = csr[jp];
    }
#pragma unroll
    for (int i = 0; i < 8; ++i) wv[i] = __expf(lrelu(a_s[idxs[i]] + adh));
#pragma unroll
    for (int i = 0; i < 8; ++i) f[i] = bf1(h2b[(size_t)idxs[i] * 64 + l]);
#pragma unroll
    for (int i = 0; i < 8; ++i) if (p + i >= s1) wv[i] = 0.f;
#pragma unroll
    for (int i = 0; i < 8; ++i) { lsum += wv[i]; acc += wv[i] * f[i]; }
  }
  float inv = 1.f / (lsum + 1e-16f);
  float z = acc * inv + b2[l] + bf1(hresb[(size_t)d * 64 + l]);
  out[(size_t)d * 64 + l] = lrelu(z);
}

// ---------------- launch ----------------
extern "C" void kernel_launch(void* const* d_in, const int* in_sizes, int n_in,
                              void* d_out, int out_size, void* d_ws, size_t ws_size,
                              hipStream_t stream) {
  const float* x        = (const float*)d_in[0];
  const int*   ei       = (const int*)d_in[1];
  const float* W1       = (const float*)d_in[2];
  const float* att_src1 = (const float*)d_in[3];
  const float* att_dst1 = (const float*)d_in[4];
  const float* b1       = (const float*)d_in[5];
  const float* W2       = (const float*)d_in[6];
  const float* att_src2 = (const float*)d_in[7];
  const float* att_dst2 = (const float*)d_in[8];
  const float* b2       = (const float*)d_in[9];
  const float* res1_w   = (const float*)d_in[10];
  const float* res1_b   = (const float*)d_in[11];
  const float* fc_w     = (const float*)d_in[12];
  const float* fc_b     = (const float*)d_in[13];
  float* out = (float*)d_out;

  const int N = in_sizes[0] / 256;
  const int E = in_sizes[1] / 2;
  const int nbuck = (N + 127) / 128;

  ushort* x_bf   = (ushort*)d_ws;                      // N*256
  ushort* h1bf   = x_bf + (size_t)N * 256;             // N*128
  ushort* xresbf = h1bf + (size_t)N * 128;             // N*128
  float*  as1    = (float*)(xresbf + (size_t)N * 128); // N*4
  float*  ad1    = as1 + (size_t)N * 4;                // N*4
  ushort* Wt1    = (ushort*)(ad1 + (size_t)N * 4);     // 256*256
  ushort* fcT    = Wt1 + 256 * 256;                    // 64*128
  ushort* W2T    = fcT + 64 * 128;                     // 64*128
  int* cnt       = (int*)(W2T + 64 * 128);             // N
  int* offp      = cnt + N;                            // N+1
  int* cursor    = offp + N + 1;                       // N (unused, layout keep)
  int* csr       = cursor + N;                         // E
  int* bsum      = csr + E;                            // 64
  int* bcursor   = bsum + 64;                          // nbuck (<=512)
  uint2* tmp     = (uint2*)(((uintptr_t)(bcursor + 512) + 7) & ~(uintptr_t)7);  // E uint2
  // aliases
  uint*   hpre_bf = (uint*)x_bf;
  uint*   hlk_bf  = (uint*)(x_bf + (size_t)N * 128);
  ushort* h2bf    = h1bf;
  ushort* hresb   = xresbf;
  float*  as2 = as1, *ad2 = ad1;

  const int nb = (N + 1023) / 1024;
  const int ngemm = (N + 63) / 64;

  hipMemsetAsync(cnt, 0, (size_t)N * 4, stream);
  prep_all_k<<<2048, 256, 0, stream>>>(x, x_bf, (long)N * 256 / 8, ei, E, cnt,
                                       W1, res1_w, fc_w, W2, Wt1, fcT, W2T);
  scan_block<<<nb, 1024, 0, stream>>>(cnt, offp, bsum, N);
  scan_partials<<<1, 1, 0, stream>>>(bsum, nb, offp, N);
  scan_add<<<nb, 1024, 0, stream>>>(offp, bsum, N);
  binit_k<<<(nbuck + 255) / 256, 256, 0, stream>>>(offp, bcursor, nbuck);
  part1_k<<<(E + 8191) / 8192, 512, 0, stream>>>(ei, E, bcursor, tmp, nbuck);

  // L1 GEMM + fused att1 + bucket-owned CSR finalize
  gemm1_k<<<ngemm, 512, 0, stream>>>(x_bf, Wt1, res1_b, att_src1, att_dst1,
                                     h1bf, xresbf, as1, ad1, tmp, offp, csr, nbuck, N);

  aggr1_k<<<(N + 3) / 4, 256, 0, stream>>>((const uint*)h1bf, (const uint*)xresbf, as1, ad1,
                                           offp, csr, b1, hpre_bf, hlk_bf, N);

  gemm2_k<<<dim3(ngemm, 2), 512, 0, stream>>>(
      (const ushort*)hpre_bf, (const ushort*)hlk_bf, fcT, fc_b,
      att_src2, att_dst2, hresb, h2bf, as2, ad2, N);

  aggr2_k<<<(N + 3) / 4, 256, 0, stream>>>(h2bf, hresb, as2, ad2, offp, csr, b2, out, N);
}

// Round 8
// 196.710 us; speedup vs baseline: 3.5070x; 1.0487x over previous
//
#include <hip/hip_runtime.h>

typedef __attribute__((ext_vector_type(8))) short short8;
typedef __attribute__((ext_vector_type(4))) float f32x4;

__device__ __forceinline__ ushort rne_bf16(float f) {
  uint u = __float_as_uint(f);
  uint r = (u + 0x7FFFu + ((u >> 16) & 1u)) >> 16;
  return (ushort)r;
}
__device__ __forceinline__ float bf16_lo(uint pair) { return __uint_as_float(pair << 16); }
__device__ __forceinline__ float bf16_hi(uint pair) { return __uint_as_float(pair & 0xffff0000u); }
__device__ __forceinline__ float bf1(ushort v) { return __uint_as_float((uint)v << 16); }
__device__ __forceinline__ float lrelu(float a) { return a >= 0.f ? a : 0.2f * a; }

__device__ __forceinline__ uint lrelu_pair(uint pair) {
  float lo = lrelu(bf16_lo(pair));
  float hi = lrelu(bf16_hi(pair));
  return (uint)rne_bf16(lo) | ((uint)rne_bf16(hi) << 16);
}
__device__ __forceinline__ float4 lrelu_bf8(float4 v) {
  uint4 u = *(uint4*)&v;
  u.x = lrelu_pair(u.x); u.y = lrelu_pair(u.y);
  u.z = lrelu_pair(u.z); u.w = lrelu_pair(u.w);
  return *(float4*)&u;
}

// ---------------- fused prep: cast x, count degrees, transpose-cast weights ----------------
__global__ __launch_bounds__(256) void prep_all_k(
    const float* __restrict__ x, ushort* __restrict__ x_bf, long nitems,
    const int* __restrict__ ei, int E, int* __restrict__ cnt,
    const float* __restrict__ W1, const float* __restrict__ res1_w,
    const float* __restrict__ fc_w, const float* __restrict__ W2,
    ushort* __restrict__ Wt1, ushort* __restrict__ fcT, ushort* __restrict__ W2T)
{
  const long gstride = (long)gridDim.x * 256;
  const long g0 = (long)blockIdx.x * 256 + threadIdx.x;
  for (long it = g0; it < nitems; it += gstride) {
    long i = it * 8;
    float4 a = *(const float4*)&x[i];
    float4 b = *(const float4*)&x[i + 4];
    ushort o[8] = {rne_bf16(a.x), rne_bf16(a.y), rne_bf16(a.z), rne_bf16(a.w),
                   rne_bf16(b.x), rne_bf16(b.y), rne_bf16(b.z), rne_bf16(b.w)};
    *(uint4*)&x_bf[i] = *(const uint4*)o;
  }
  for (long e = g0; e < E; e += gstride)
    atomicAdd(&cnt[ei[E + e]], 1);
  for (long gi = g0; gi < 81920; gi += gstride) {
    const float* src; ushort* dst; int K, NO; long local;
    if (gi < 32768)            { src = W1;     dst = Wt1;          K = 256; NO = 128; local = gi; }
    else if (gi < 65536)       { src = res1_w; dst = Wt1 + 32768;  K = 256; NO = 128; local = gi - 32768; }
    else if (gi < 65536+8192)  { src = fc_w;   dst = fcT;          K = 128; NO = 64;  local = gi - 65536; }
    else                       { src = W2;     dst = W2T;          K = 128; NO = 64;  local = gi - 65536 - 8192; }
    int n = (int)(local / K), k = (int)(local % K);
    dst[local] = rne_bf16(src[(size_t)k * NO + n]);
  }
}

// ---------------- scans ----------------
__global__ __launch_bounds__(1024) void scan_block(const int* __restrict__ cnt,
                                                   int* __restrict__ off,
                                                   int* __restrict__ bsum, int n) {
  __shared__ int sh[1024];
  int i = blockIdx.x * 1024 + threadIdx.x;
  int v = (i < n) ? cnt[i] : 0;
  sh[threadIdx.x] = v;
  __syncthreads();
  for (int o = 1; o < 1024; o <<= 1) {
    int t = (threadIdx.x >= o) ? sh[threadIdx.x - o] : 0;
    __syncthreads();
    sh[threadIdx.x] += t;
    __syncthreads();
  }
  if (i < n) off[i] = sh[threadIdx.x] - v;
  if (threadIdx.x == 1023) bsum[blockIdx.x] = sh[1023];
}

__global__ void scan_partials(int* __restrict__ bsum, int nb, int* __restrict__ off, int n) {
  int run = 0;
  for (int b = 0; b < nb; ++b) { int t = bsum[b]; bsum[b] = run; run += t; }
  off[n] = run;
}

__global__ __launch_bounds__(1024) void scan_add(int* __restrict__ off,
                                                 const int* __restrict__ bsum, int n) {
  int i = blockIdx.x * 1024 + threadIdx.x;
  if (i < n) off[i] += bsum[blockIdx.x];
}

__global__ void binit_k(const int* __restrict__ off, int* __restrict__ bcursor, int nbuck) {
  int b = blockIdx.x * 256 + threadIdx.x;
  if (b < nbuck) bcursor[b] = off[b * 128];
}

// ---------------- pass 1: LDS-radix partition of edges into dst-buckets ----------------
__global__ __launch_bounds__(512) void part1_k(const int* __restrict__ ei, int E,
                                               int* __restrict__ bcursor,
                                               uint2* __restrict__ tmp, int nbuck) {
  __shared__ int lcnt[400];
  __shared__ int gbase[400];
  const int tid = threadIdx.x;
  const long base = (long)blockIdx.x * 8192;
  for (int i = tid; i < nbuck; i += 512) lcnt[i] = 0;
  __syncthreads();
  int srcs[16], dsts[16], rk[16];
#pragma unroll
  for (int i = 0; i < 16; ++i) {
    long e = base + i * 512 + tid;
    if (e < E) {
      srcs[i] = ei[e];
      dsts[i] = ei[E + e];
      rk[i] = atomicAdd(&lcnt[dsts[i] >> 7], 1);
    } else dsts[i] = -1;
  }
  __syncthreads();
  for (int b = tid; b < nbuck; b += 512)
    gbase[b] = lcnt[b] ? atomicAdd(&bcursor[b], lcnt[b]) : 0;
  __syncthreads();
#pragma unroll
  for (int i = 0; i < 16; ++i) {
    if (dsts[i] >= 0) {
      int b = dsts[i] >> 7;
      tmp[gbase[b] + rk[i]] = make_uint2((uint)srcs[i], (uint)dsts[i]);
    }
  }
}

// ---------------- L1 GEMM + fused att1 + CSR pass-2 (bucket-owned) ----------------
__global__ __launch_bounds__(512) void gemm1_k(
    const ushort* __restrict__ x_bf, const ushort* __restrict__ Wt1,
    const float* __restrict__ res1_b,
    const float* __restrict__ att_s1, const float* __restrict__ att_d1,
    ushort* __restrict__ h1bf, ushort* __restrict__ xresbf,
    float* __restrict__ a_s, float* __restrict__ a_d,
    const uint2* __restrict__ tmp, const int* __restrict__ offp,
    int* __restrict__ csr, int nbuck, int M)
{
  constexpr int LDA = 72;
  __shared__ ushort smem[64 * LDA + 256 * LDA];
  const int bid = blockIdx.x, tid = threadIdx.x;
  ushort* As = smem;
  ushort* Bs = smem + 64 * LDA;
  const int w = tid >> 6, l = tid & 63;
  const int wr = w >> 2, wc = w & 3;
  const int l15 = l & 15, lg = l >> 4;
  const int row0 = bid * 64;
  const int srow = tid >> 3, sch = tid & 7;

  int gra = row0 + srow; if (gra >= M) gra = M - 1;
  const ushort* Ap = x_bf + (size_t)gra * 256 + sch * 8;
  const ushort* Bp = Wt1 + (size_t)srow * 256 + sch * 8;

  f32x4 acc[2][4] = {};
  float4 raC, rbC0, rbC1, rbC2, rbC3, raN, rbN0, rbN1, rbN2, rbN3;
  raC  = *(const float4*)(Ap);
  rbC0 = *(const float4*)(Bp);
  rbC1 = *(const float4*)(Bp + 64 * 256);
  rbC2 = *(const float4*)(Bp + 128 * 256);
  rbC3 = *(const float4*)(Bp + 192 * 256);

#pragma unroll
  for (int kt = 0; kt < 4; ++kt) {
    __syncthreads();
    *(float4*)&As[srow * LDA + sch * 8] = raC;
    *(float4*)&Bs[(0 * 64 + srow) * LDA + sch * 8] = rbC0;
    *(float4*)&Bs[(1 * 64 + srow) * LDA + sch * 8] = rbC1;
    *(float4*)&Bs[(2 * 64 + srow) * LDA + sch * 8] = rbC2;
    *(float4*)&Bs[(3 * 64 + srow) * LDA + sch * 8] = rbC3;
    __syncthreads();
    if (kt < 3) {
      int k1 = (kt + 1) * 64;
      raN  = *(const float4*)(Ap + k1);
      rbN0 = *(const float4*)(Bp + k1);
      rbN1 = *(const float4*)(Bp + 64 * 256 + k1);
      rbN2 = *(const float4*)(Bp + 128 * 256 + k1);
      rbN3 = *(const float4*)(Bp + 192 * 256 + k1);
    }
    short8 aF[2][2], bF[4][2];
#pragma unroll
    for (int m = 0; m < 2; ++m)
#pragma unroll
      for (int kk = 0; kk < 2; ++kk)
        aF[m][kk] = *(const short8*)&As[(wr * 32 + m * 16 + l15) * LDA + kk * 32 + lg * 8];
#pragma unroll
    for (int n = 0; n < 4; ++n)
#pragma unroll
      for (int kk = 0; kk < 2; ++kk)
        bF[n][kk] = *(const short8*)&Bs[(wc * 64 + n * 16 + l15) * LDA + kk * 32 + lg * 8];
#pragma unroll
    for (int m = 0; m < 2; ++m)
#pragma unroll
      for (int n = 0; n < 4; ++n)
#pragma unroll
        for (int kk = 0; kk < 2; ++kk)
          acc[m][n] = __builtin_amdgcn_mfma_f32_16x16x32_bf16(aF[m][kk], bF[n][kk], acc[m][n], 0, 0, 0);
    raC = raN; rbC0 = rbN0; rbC1 = rbN1; rbC2 = rbN2; rbC3 = rbN3;
  }
  __syncthreads();

  ushort* Cs = smem;
#pragma unroll
  for (int m = 0; m < 2; ++m)
#pragma unroll
    for (int n = 0; n < 4; ++n)
#pragma unroll
      for (int j = 0; j < 4; ++j) {
        int rl = wr * 32 + m * 16 + lg * 4 + j;
        int col = wc * 64 + n * 16 + l15;
        float v = acc[m][n][j] + (col >= 128 ? res1_b[col - 128] : 0.f);
        Cs[rl * 256 + col] = rne_bf16(v);
      }
  __syncthreads();

  // fused att1
  {
    int r = tid >> 3, s = tid & 7, h = s >> 1;
    int gr = row0 + r;
    float ps = 0.f, pd = 0.f;
#pragma unroll
    for (int i = 0; i < 16; ++i) {
      int col = s * 16 + i;
      float v = bf1(Cs[r * 256 + col]);
      ps += v * att_s1[h * 32 + (col & 31)];
      pd += v * att_d1[h * 32 + (col & 31)];
    }
    ps += __shfl_xor(ps, 1, 64);
    pd += __shfl_xor(pd, 1, 64);
    if (!(s & 1) && gr < M) { a_s[gr * 4 + h] = ps; a_d[gr * 4 + h] = pd; }
  }

  // coalesced split copy
#pragma unroll
  for (int idx = tid; idx < 2048; idx += 512) {
    int row = idx >> 5, c16 = idx & 31;
    int gr = row0 + row;
    if (gr < M) {
      uint4 v = *(const uint4*)&Cs[row * 256 + c16 * 8];
      if (c16 < 16) *(uint4*)&h1bf[(size_t)gr * 128 + c16 * 8] = v;
      else          *(uint4*)&xresbf[(size_t)gr * 128 + (c16 - 16) * 8] = v;
    }
  }

  // CSR pass-2: block bid owns bucket bid
  if (bid < nbuck) {
    __syncthreads();
    int* lcnt  = (int*)smem;
    int* dbase = lcnt + 128;
    const int vbase = bid * 128;
    const int endi = (vbase + 128 < M) ? vbase + 128 : M;
    const int base0 = offp[vbase];
    const int bend  = offp[endi];
    if (tid < 128) {
      int gi = vbase + tid;
      dbase[tid] = ((gi < M) ? offp[gi] : bend) - base0;
      lcnt[tid] = 0;
    }
    __syncthreads();
    for (int e = base0 + tid; e < bend; e += 512) {
      uint2 t = tmp[e];
      int li = (int)t.y - vbase;
      int r = atomicAdd(&lcnt[li], 1);
      csr[base0 + dbase[li] + r] = (int)t.x;
    }
  }
}

// ---------------- L2 GEMM (y: 0=hres=hpre@fc+b ; 1=h2=lrelu(hpre)@W2) + att2 ----------------
__global__ __launch_bounds__(512) void gemm2_k(
    const ushort* __restrict__ hpre,
    const ushort* __restrict__ fcT,            // W2T = fcT + 64*128
    const float* __restrict__ fc_b,
    const float* __restrict__ att_s2, const float* __restrict__ att_d2,
    ushort* __restrict__ hresb, ushort* __restrict__ h2bf,
    float* __restrict__ a_s, float* __restrict__ a_d, int M)
{
  constexpr int LDA = 72;
  __shared__ ushort smem[64 * LDA + 64 * LDA];
  const int tid = threadIdx.x, y = blockIdx.y;
  const ushort* B = fcT + (size_t)y * 64 * 128;
  ushort* out = y ? h2bf : hresb;
  const int row0 = blockIdx.x * 64;
  ushort* As = smem;
  ushort* Bs = smem + 64 * LDA;
  const int w = tid >> 6, l = tid & 63;
  const int wr = w >> 1, wc = w & 1;
  const int l15 = l & 15, lg = l >> 4;
  const int srow = tid >> 3, sch = tid & 7;

  int gra = row0 + srow; if (gra >= M) gra = M - 1;
  const ushort* Ap = hpre + (size_t)gra * 128 + sch * 8;
  const ushort* Bp = B + (size_t)srow * 128 + sch * 8;

  f32x4 acc[2] = {};
  float4 raC = *(const float4*)(Ap);
  float4 rbC = *(const float4*)(Bp);
  if (y) raC = lrelu_bf8(raC);
  float4 raN, rbN;

#pragma unroll
  for (int kt = 0; kt < 2; ++kt) {
    __syncthreads();
    *(float4*)&As[srow * LDA + sch * 8] = raC;
    *(float4*)&Bs[srow * LDA + sch * 8] = rbC;
    __syncthreads();
    if (kt < 1) {
      raN = *(const float4*)(Ap + 64);
      rbN = *(const float4*)(Bp + 64);
      if (y) raN = lrelu_bf8(raN);
    }

    short8 aF[2], bF[2][2];
#pragma unroll
    for (int kk = 0; kk < 2; ++kk)
      aF[kk] = *(const short8*)&As[(wr * 16 + l15) * LDA + kk * 32 + lg * 8];
#pragma unroll
    for (int n = 0; n < 2; ++n)
#pragma unroll
      for (int kk = 0; kk < 2; ++kk)
        bF[n][kk] = *(const short8*)&Bs[(wc * 32 + n * 16 + l15) * LDA + kk * 32 + lg * 8];
#pragma unroll
    for (int n = 0; n < 2; ++n)
#pragma unroll
      for (int kk = 0; kk < 2; ++kk)
        acc[n] = __builtin_amdgcn_mfma_f32_16x16x32_bf16(aF[kk], bF[n][kk], acc[n], 0, 0, 0);
    raC = raN; rbC = rbN;
  }
  __syncthreads();

  ushort* Cs = smem;
#pragma unroll
  for (int n = 0; n < 2; ++n)
#pragma unroll
    for (int j = 0; j < 4; ++j) {
      int rl = wr * 16 + lg * 4 + j;
      int col = wc * 32 + n * 16 + l15;
      float v = acc[n][j] + (y == 0 ? fc_b[col] : 0.f);
      Cs[rl * 64 + col] = rne_bf16(v);
    }
  __syncthreads();

  if (y == 1) {
    int r = tid >> 3, s = tid & 7;
    int gr = row0 + r;
    float ps = 0.f, pd = 0.f;
#pragma unroll
    for (int i = 0; i < 8; ++i) {
      int col = s * 8 + i;
      float v = bf1(Cs[r * 64 + col]);
      ps += v * att_s2[col];
      pd += v * att_d2[col];
    }
    ps += __shfl_xor(ps, 1, 64); pd += __shfl_xor(pd, 1, 64);
    ps += __shfl_xor(ps, 2, 64); pd += __shfl_xor(pd, 2, 64);
    ps += __shfl_xor(ps, 4, 64); pd += __shfl_xor(pd, 4, 64);
    if (s == 0 && gr < M) { a_s[gr] = ps; a_d[gr] = pd; }
  }

  {
    int row = tid >> 3, c16 = tid & 7;
    int gr = row0 + row;
    if (gr < M)
      *(uint4*)&out[(size_t)gr * 64 + c16 * 8] = *(const uint4*)&Cs[row * 64 + c16 * 8];
  }
}

// ---------------- aggregation: 16-edge batches, cooperative weights + shfl ----------------
__global__ __launch_bounds__(256) void aggr1_k(const uint* __restrict__ h1u,
                                               const uint* __restrict__ xresu,
                                               const float* __restrict__ a_s,
                                               const float* __restrict__ a_d,
                                               const int* __restrict__ off,
                                               const int* __restrict__ csr,
                                               const float* __restrict__ b1,
                                               uint* __restrict__ hpre_bf, int n) {
  int w = threadIdx.x >> 6, l = threadIdx.x & 63;
  int d = blockIdx.x * 4 + w;
  if (d >= n) return;
  int h = l >> 4, c = l * 2;
  int le = l & 15, hb = l & 48;
  float adh = a_d[d * 4 + h];
  float ws = __expf(lrelu(a_s[d * 4 + h] + adh));   // self loop
  uint pd = h1u[(size_t)d * 64 + l];
  float lsum = ws, accx = ws * bf16_lo(pd), accy = ws * bf16_hi(pd);

  int s0 = off[d], s1 = off[d + 1];
  for (int p = s0; p < s1; p += 16) {
    int jp = p + le;
    bool valid = jp < s1;
    int jc = valid ? jp : s1 - 1;
    int idxv = csr[jc];
    float wv = valid ? __expf(lrelu(a_s[idxv * 4 + h] + adh)) : 0.f;
    float wi[16]; int sv[16];
#pragma unroll
    for (int i = 0; i < 16; ++i) {
      wi[i] = __shfl(wv, hb + i, 64);
      sv[i] = __shfl(idxv, i, 64);
    }
#pragma unroll
    for (int i = 0; i < 16; ++i) {
      uint q = h1u[(size_t)sv[i] * 64 + l];
      lsum += wi[i];
      accx += wi[i] * bf16_lo(q);
      accy += wi[i] * bf16_hi(q);
    }
  }
  float inv = 1.f / (lsum + 1e-16f);
  uint xr = xresu[(size_t)d * 64 + l];
  float vx = accx * inv + b1[c] + bf16_lo(xr);
  float vy = accy * inv + b1[c + 1] + bf16_hi(xr);
  hpre_bf[(size_t)d * 64 + l] = (uint)rne_bf16(vx) | ((uint)rne_bf16(vy) << 16);
}

__global__ __launch_bounds__(256) void aggr2_k(const ushort* __restrict__ h2b,
                                               const ushort* __restrict__ hresb,
                                               const float* __restrict__ a_s,
                                               const float* __restrict__ a_d,
                                               const int* __restrict__ off,
                                               const int* __restrict__ csr,
                                               const float* __restrict__ b2,
                                               float* __restrict__ out, int n) {
  int w = threadIdx.x >> 6, l = threadIdx.x & 63;
  int d = blockIdx.x * 4 + w;
  if (d >= n) return;
  int le = l & 15;
  float adh = a_d[d];
  float ws = __expf(lrelu(a_s[d] + adh));
  float lsum = ws;
  float acc = ws * bf1(h2b[(size_t)d * 64 + l]);

  int s0 = off[d], s1 = off[d + 1];
  for (int p = s0; p < s1; p += 16) {
    int jp = p + le;
    bool valid = jp < s1;
    int jc = valid ? jp : s1 - 1;
    int idxv = csr[jc];
    float wv = valid ? __expf(lrelu(a_s[idxv] + adh)) : 0.f;
    float wi[16]; int sv[16];
#pragma unroll
    for (int i = 0; i < 16; ++i) {
      wi[i] = __shfl(wv, i, 64);
      sv[i] = __shfl(idxv, i, 64);
    }
#pragma unroll
    for (int i = 0; i < 16; ++i) {
      float fv = bf1(h2b[(size_t)sv[i] * 64 + l]);
      lsum += wi[i];
      acc += wi[i] * fv;
    }
  }
  float inv = 1.f / (lsum + 1e-16f);
  float z = acc * inv + b2[l] + bf1(hresb[(size_t)d * 64 + l]);
  out[(size_t)d * 64 + l] = lrelu(z);
}

// ---------------- launch ----------------
extern "C" void kernel_launch(void* const* d_in, const int* in_sizes, int n_in,
                              void* d_out, int out_size, void* d_ws, size_t ws_size,
                              hipStream_t stream) {
  const float* x        = (const float*)d_in[0];
  const int*   ei       = (const int*)d_in[1];
  const float* W1       = (const float*)d_in[2];
  const float* att_src1 = (const float*)d_in[3];
  const float* att_dst1 = (const float*)d_in[4];
  const float* b1       = (const float*)d_in[5];
  const float* W2       = (const float*)d_in[6];
  const float* att_src2 = (const float*)d_in[7];
  const float* att_dst2 = (const float*)d_in[8];
  const float* b2       = (const float*)d_in[9];
  const float* res1_w   = (const float*)d_in[10];
  const float* res1_b   = (const float*)d_in[11];
  const float* fc_w     = (const float*)d_in[12];
  const float* fc_b     = (const float*)d_in[13];
  float* out = (float*)d_out;

  const int N = in_sizes[0] / 256;
  const int E = in_sizes[1] / 2;
  const int nbuck = (N + 127) / 128;

  ushort* x_bf   = (ushort*)d_ws;                      // N*256
  ushort* h1bf   = x_bf + (size_t)N * 256;             // N*128
  ushort* xresbf = h1bf + (size_t)N * 128;             // N*128
  float*  as1    = (float*)(xresbf + (size_t)N * 128); // N*4
  float*  ad1    = as1 + (size_t)N * 4;                // N*4
  ushort* Wt1    = (ushort*)(ad1 + (size_t)N * 4);     // 256*256
  ushort* fcT    = Wt1 + 256 * 256;                    // 64*128
  ushort* W2T    = fcT + 64 * 128;                     // 64*128
  int* cnt       = (int*)(W2T + 64 * 128);             // N
  int* offp      = cnt + N;                            // N+1
  int* cursor    = offp + N + 1;                       // N (unused, layout keep)
  int* csr       = cursor + N;                         // E
  int* bsum      = csr + E;                            // 64
  int* bcursor   = bsum + 64;                          // nbuck (<=512)
  uint2* tmp     = (uint2*)(((uintptr_t)(bcursor + 512) + 7) & ~(uintptr_t)7);  // E uint2
  // aliases
  uint*   hpre_bf = (uint*)x_bf;
  ushort* h2bf    = h1bf;
  ushort* hresb   = xresbf;
  float*  as2 = as1, *ad2 = ad1;

  const int nb = (N + 1023) / 1024;
  const int ngemm = (N + 63) / 64;

  hipMemsetAsync(cnt, 0, (size_t)N * 4, stream);
  prep_all_k<<<2048, 256, 0, stream>>>(x, x_bf, (long)N * 256 / 8, ei, E, cnt,
                                       W1, res1_w, fc_w, W2, Wt1, fcT, W2T);
  scan_block<<<nb, 1024, 0, stream>>>(cnt, offp, bsum, N);
  scan_partials<<<1, 1, 0, stream>>>(bsum, nb, offp, N);
  scan_add<<<nb, 1024, 0, stream>>>(offp, bsum, N);
  binit_k<<<(nbuck + 255) / 256, 256, 0, stream>>>(offp, bcursor, nbuck);
  part1_k<<<(E + 8191) / 8192, 512, 0, stream>>>(ei, E, bcursor, tmp, nbuck);

  gemm1_k<<<ngemm, 512, 0, stream>>>(x_bf, Wt1, res1_b, att_src1, att_dst1,
                                     h1bf, xresbf, as1, ad1, tmp, offp, csr, nbuck, N);

  aggr1_k<<<(N + 3) / 4, 256, 0, stream>>>((const uint*)h1bf, (const uint*)xresbf, as1, ad1,
                                           offp, csr, b1, hpre_bf, N);

  gemm2_k<<<dim3(ngemm, 2), 512, 0, stream>>>(
      (const ushort*)hpre_bf, fcT, fc_b,
      att_src2, att_dst2, hresb, h2bf, as2, ad2, N);

  aggr2_k<<<(N + 3) / 4, 256, 0, stream>>>(h2bf, hresb, as2, ad2, offp, csr, b2, out, N);
}

// Round 9
// 156.793 us; speedup vs baseline: 4.3998x; 1.2546x over previous
//
#include <hip/hip_runtime.h>

typedef __attribute__((ext_vector_type(8))) short short8;
typedef __attribute__((ext_vector_type(4))) float f32x4;

constexpr int BCAP = 4096;   // padded per-bucket capacity in tmp (mean 2048, max ~2300)

__device__ __forceinline__ ushort rne_bf16(float f) {
  uint u = __float_as_uint(f);
  uint r = (u + 0x7FFFu + ((u >> 16) & 1u)) >> 16;
  return (ushort)r;
}
__device__ __forceinline__ float bf16_lo(uint pair) { return __uint_as_float(pair << 16); }
__device__ __forceinline__ float bf16_hi(uint pair) { return __uint_as_float(pair & 0xffff0000u); }
__device__ __forceinline__ float bf1(ushort v) { return __uint_as_float((uint)v << 16); }
__device__ __forceinline__ float lrelu(float a) { return a >= 0.f ? a : 0.2f * a; }

__device__ __forceinline__ uint lrelu_pair(uint pair) {
  float lo = lrelu(bf16_lo(pair));
  float hi = lrelu(bf16_hi(pair));
  return (uint)rne_bf16(lo) | ((uint)rne_bf16(hi) << 16);
}
__device__ __forceinline__ float4 lrelu_bf8(float4 v) {
  uint4 u = *(uint4*)&v;
  u.x = lrelu_pair(u.x); u.y = lrelu_pair(u.y);
  u.z = lrelu_pair(u.z); u.w = lrelu_pair(u.w);
  return *(float4*)&u;
}

// ---- fused prep: cast x | bucket-partition edges (LDS rank) | transpose-cast weights ----
__global__ __launch_bounds__(256) void prep_all_k(
    const float* __restrict__ x, ushort* __restrict__ x_bf, long nitems,
    const int* __restrict__ ei, int E, int nEB,
    int* __restrict__ bcnt, uint2* __restrict__ tmp, int nbuck,
    const float* __restrict__ W1, const float* __restrict__ res1_w,
    const float* __restrict__ fc_w, const float* __restrict__ W2,
    ushort* __restrict__ Wt1, ushort* __restrict__ fcT, ushort* __restrict__ W2T)
{
  __shared__ int lcnt[400];
  __shared__ int gbase[400];
  const int tid = threadIdx.x, bid = blockIdx.x;
  const long gstride = (long)gridDim.x * 256;
  const long g0 = (long)bid * 256 + tid;

  // phase A: cast x -> bf16 (32B per thread-iter, coalesced)
  for (long it = g0; it < nitems; it += gstride) {
    long i = it * 8;
    float4 a = *(const float4*)&x[i];
    float4 b = *(const float4*)&x[i + 4];
    ushort o[8] = {rne_bf16(a.x), rne_bf16(a.y), rne_bf16(a.z), rne_bf16(a.w),
                   rne_bf16(b.x), rne_bf16(b.y), rne_bf16(b.z), rne_bf16(b.w)};
    *(uint4*)&x_bf[i] = *(const uint4*)o;
  }

  // phase B: blocks [0, nEB) partition 4096 edges each into dst-buckets
  if (bid < nEB) {
    for (int i = tid; i < nbuck; i += 256) lcnt[i] = 0;
    __syncthreads();
    const int ebase = bid * 4096;
    int srcs[16], dsts[16], rk[16];
#pragma unroll
    for (int i = 0; i < 16; ++i) {
      int e = ebase + i * 256 + tid;
      if (e < E) {
        srcs[i] = ei[e];
        dsts[i] = ei[E + e];
        rk[i] = atomicAdd(&lcnt[dsts[i] >> 7], 1);   // LDS atomic
      } else dsts[i] = -1;
    }
    __syncthreads();
    for (int b = tid; b < nbuck; b += 256)
      gbase[b] = lcnt[b] ? atomicAdd(&bcnt[b], lcnt[b]) : 0;   // 1 global atomic/(blk,bucket)
    __syncthreads();
#pragma unroll
    for (int i = 0; i < 16; ++i) {
      if (dsts[i] >= 0) {
        int b = dsts[i] >> 7;
        tmp[(size_t)b * BCAP + gbase[b] + rk[i]] = make_uint2((uint)srcs[i], (uint)dsts[i]);
      }
    }
  }

  // phase C: weight transpose-casts
  for (long gi = g0; gi < 81920; gi += gstride) {
    const float* src; ushort* dst; int K, NO; long local;
    if (gi < 32768)            { src = W1;     dst = Wt1;          K = 256; NO = 128; local = gi; }
    else if (gi < 65536)       { src = res1_w; dst = Wt1 + 32768;  K = 256; NO = 128; local = gi - 32768; }
    else if (gi < 65536+8192)  { src = fc_w;   dst = fcT;          K = 128; NO = 64;  local = gi - 65536; }
    else                       { src = W2;     dst = W2T;          K = 128; NO = 64;  local = gi - 65536 - 8192; }
    int n = (int)(local / K), k = (int)(local % K);
    dst[local] = rne_bf16(src[(size_t)k * NO + n]);
  }
}

// ---- exclusive scan of bucket totals (1 block; nbuck <= 512) ----
__global__ __launch_bounds__(512) void scan_buckets_k(const int* __restrict__ bcnt,
                                                      int* __restrict__ bbase,
                                                      int* __restrict__ offp,
                                                      int nbuck, int N) {
  __shared__ int sh[512];
  int tid = threadIdx.x;
  int v = (tid < nbuck) ? bcnt[tid] : 0;
  sh[tid] = v;
  __syncthreads();
  for (int o = 1; o < 512; o <<= 1) {
    int t = (tid >= o) ? sh[tid - o] : 0;
    __syncthreads();
    sh[tid] += t;
    __syncthreads();
  }
  if (tid < nbuck) bbase[tid] = sh[tid] - v;
  if (tid == nbuck - 1) { bbase[nbuck] = sh[tid]; offp[N] = sh[tid]; }
}

// ---- L1 GEMM + fused att1 + bucket-owned CSR finalize (offp + sorted csr) ----
__global__ __launch_bounds__(512) void gemm1_k(
    const ushort* __restrict__ x_bf, const ushort* __restrict__ Wt1,
    const float* __restrict__ res1_b,
    const float* __restrict__ att_s1, const float* __restrict__ att_d1,
    ushort* __restrict__ h1bf, ushort* __restrict__ xresbf,
    float* __restrict__ a_s, float* __restrict__ a_d,
    const uint2* __restrict__ tmp, const int* __restrict__ bcnt,
    const int* __restrict__ bbase, int* __restrict__ offp,
    int* __restrict__ csr, int nbuck, int M)
{
  constexpr int LDA = 72;
  __shared__ ushort smem[64 * LDA + 256 * LDA];
  const int bid = blockIdx.x, tid = threadIdx.x;
  ushort* As = smem;
  ushort* Bs = smem + 64 * LDA;
  const int w = tid >> 6, l = tid & 63;
  const int wr = w >> 2, wc = w & 3;
  const int l15 = l & 15, lg = l >> 4;
  const int row0 = bid * 64;
  const int srow = tid >> 3, sch = tid & 7;

  int gra = row0 + srow; if (gra >= M) gra = M - 1;
  const ushort* Ap = x_bf + (size_t)gra * 256 + sch * 8;
  const ushort* Bp = Wt1 + (size_t)srow * 256 + sch * 8;

  f32x4 acc[2][4] = {};
  float4 raC, rbC0, rbC1, rbC2, rbC3, raN, rbN0, rbN1, rbN2, rbN3;
  raC  = *(const float4*)(Ap);
  rbC0 = *(const float4*)(Bp);
  rbC1 = *(const float4*)(Bp + 64 * 256);
  rbC2 = *(const float4*)(Bp + 128 * 256);
  rbC3 = *(const float4*)(Bp + 192 * 256);

#pragma unroll
  for (int kt = 0; kt < 4; ++kt) {
    __syncthreads();
    *(float4*)&As[srow * LDA + sch * 8] = raC;
    *(float4*)&Bs[(0 * 64 + srow) * LDA + sch * 8] = rbC0;
    *(float4*)&Bs[(1 * 64 + srow) * LDA + sch * 8] = rbC1;
    *(float4*)&Bs[(2 * 64 + srow) * LDA + sch * 8] = rbC2;
    *(float4*)&Bs[(3 * 64 + srow) * LDA + sch * 8] = rbC3;
    __syncthreads();
    if (kt < 3) {
      int k1 = (kt + 1) * 64;
      raN  = *(const float4*)(Ap + k1);
      rbN0 = *(const float4*)(Bp + k1);
      rbN1 = *(const float4*)(Bp + 64 * 256 + k1);
      rbN2 = *(const float4*)(Bp + 128 * 256 + k1);
      rbN3 = *(const float4*)(Bp + 192 * 256 + k1);
    }
    short8 aF[2][2], bF[4][2];
#pragma unroll
    for (int m = 0; m < 2; ++m)
#pragma unroll
      for (int kk = 0; kk < 2; ++kk)
        aF[m][kk] = *(const short8*)&As[(wr * 32 + m * 16 + l15) * LDA + kk * 32 + lg * 8];
#pragma unroll
    for (int n = 0; n < 4; ++n)
#pragma unroll
      for (int kk = 0; kk < 2; ++kk)
        bF[n][kk] = *(const short8*)&Bs[(wc * 64 + n * 16 + l15) * LDA + kk * 32 + lg * 8];
#pragma unroll
    for (int m = 0; m < 2; ++m)
#pragma unroll
      for (int n = 0; n < 4; ++n)
#pragma unroll
        for (int kk = 0; kk < 2; ++kk)
          acc[m][n] = __builtin_amdgcn_mfma_f32_16x16x32_bf16(aF[m][kk], bF[n][kk], acc[m][n], 0, 0, 0);
    raC = raN; rbC0 = rbN0; rbC1 = rbN1; rbC2 = rbN2; rbC3 = rbN3;
  }
  __syncthreads();

  ushort* Cs = smem;
#pragma unroll
  for (int m = 0; m < 2; ++m)
#pragma unroll
    for (int n = 0; n < 4; ++n)
#pragma unroll
      for (int j = 0; j < 4; ++j) {
        int rl = wr * 32 + m * 16 + lg * 4 + j;
        int col = wc * 64 + n * 16 + l15;
        float v = acc[m][n][j] + (col >= 128 ? res1_b[col - 128] : 0.f);
        Cs[rl * 256 + col] = rne_bf16(v);
      }
  __syncthreads();

  // fused att1
  {
    int r = tid >> 3, s = tid & 7, h = s >> 1;
    int gr = row0 + r;
    float ps = 0.f, pd = 0.f;
#pragma unroll
    for (int i = 0; i < 16; ++i) {
      int col = s * 16 + i;
      float v = bf1(Cs[r * 256 + col]);
      ps += v * att_s1[h * 32 + (col & 31)];
      pd += v * att_d1[h * 32 + (col & 31)];
    }
    ps += __shfl_xor(ps, 1, 64);
    pd += __shfl_xor(pd, 1, 64);
    if (!(s & 1) && gr < M) { a_s[gr * 4 + h] = ps; a_d[gr * 4 + h] = pd; }
  }

  // coalesced split copy
#pragma unroll
  for (int idx = tid; idx < 2048; idx += 512) {
    int row = idx >> 5, c16 = idx & 31;
    int gr = row0 + row;
    if (gr < M) {
      uint4 v = *(const uint4*)&Cs[row * 256 + c16 * 8];
      if (c16 < 16) *(uint4*)&h1bf[(size_t)gr * 128 + c16 * 8] = v;
      else          *(uint4*)&xresbf[(size_t)gr * 128 + (c16 - 16) * 8] = v;
    }
  }

  // CSR finalize: block bid owns bucket bid — count, scan, write offp + sorted csr
  if (bid < nbuck) {
    __syncthreads();
    int* lcnt = (int*)smem;        // 128 counters
    int* excl = lcnt + 128;        // 128 exclusive offsets
    const int vbase = bid * 128;
    const int nloc = ((vbase + 128 < M) ? 128 : M - vbase);
    const int cntb = bcnt[bid];
    const int bbase0 = bbase[bid];
    const uint2* bt = tmp + (size_t)bid * BCAP;
    if (tid < 128) lcnt[tid] = 0;
    __syncthreads();
    for (int e = tid; e < cntb; e += 512)
      atomicAdd(&lcnt[(int)bt[e].y - vbase], 1);
    __syncthreads();
    if (tid < 128) {
      int v = lcnt[tid];
      int sc = v;
#pragma unroll
      for (int o = 1; o < 64; o <<= 1) {
        int t = __shfl_up(sc, o, 64);
        if ((tid & 63) >= o) sc += t;
      }
      excl[tid] = sc - v;          // exclusive within wave
    }
    __syncthreads();
    if (tid >= 64 && tid < 128) excl[tid] += excl[63] + lcnt[63];
    __syncthreads();
    if (tid < nloc) offp[vbase + tid] = bbase0 + excl[tid];
    if (tid < 128) lcnt[tid] = 0;
    __syncthreads();
    for (int e = tid; e < cntb; e += 512) {
      uint2 t = bt[e];
      int li = (int)t.y - vbase;
      int r = atomicAdd(&lcnt[li], 1);
      csr[bbase0 + excl[li] + r] = (int)t.x;
    }
  }
}

// ---- L2 GEMM (y: 0=hres=hpre@fc+b ; 1=h2=lrelu(hpre)@W2) + att2 ----
__global__ __launch_bounds__(512) void gemm2_k(
    const ushort* __restrict__ hpre,
    const ushort* __restrict__ fcT,            // W2T = fcT + 64*128
    const float* __restrict__ fc_b,
    const float* __restrict__ att_s2, const float* __restrict__ att_d2,
    ushort* __restrict__ hresb, ushort* __restrict__ h2bf,
    float* __restrict__ a_s, float* __restrict__ a_d, int M)
{
  constexpr int LDA = 72;
  __shared__ ushort smem[64 * LDA + 64 * LDA];
  const int tid = threadIdx.x, y = blockIdx.y;
  const ushort* B = fcT + (size_t)y * 64 * 128;
  ushort* out = y ? h2bf : hresb;
  const int row0 = blockIdx.x * 64;
  ushort* As = smem;
  ushort* Bs = smem + 64 * LDA;
  const int w = tid >> 6, l = tid & 63;
  const int wr = w >> 1, wc = w & 1;
  const int l15 = l & 15, lg = l >> 4;
  const int srow = tid >> 3, sch = tid & 7;

  int gra = row0 + srow; if (gra >= M) gra = M - 1;
  const ushort* Ap = hpre + (size_t)gra * 128 + sch * 8;
  const ushort* Bp = B + (size_t)srow * 128 + sch * 8;

  f32x4 acc[2] = {};
  float4 raC = *(const float4*)(Ap);
  float4 rbC = *(const float4*)(Bp);
  if (y) raC = lrelu_bf8(raC);
  float4 raN, rbN;

#pragma unroll
  for (int kt = 0; kt < 2; ++kt) {
    __syncthreads();
    *(float4*)&As[srow * LDA + sch * 8] = raC;
    *(float4*)&Bs[srow * LDA + sch * 8] = rbC;
    __syncthreads();
    if (kt < 1) {
      raN = *(const float4*)(Ap + 64);
      rbN = *(const float4*)(Bp + 64);
      if (y) raN = lrelu_bf8(raN);
    }

    short8 aF[2], bF[2][2];
#pragma unroll
    for (int kk = 0; kk < 2; ++kk)
      aF[kk] = *(const short8*)&As[(wr * 16 + l15) * LDA + kk * 32 + lg * 8];
#pragma unroll
    for (int n = 0; n < 2; ++n)
#pragma unroll
      for (int kk = 0; kk < 2; ++kk)
        bF[n][kk] = *(const short8*)&Bs[(wc * 32 + n * 16 + l15) * LDA + kk * 32 + lg * 8];
#pragma unroll
    for (int n = 0; n < 2; ++n)
#pragma unroll
      for (int kk = 0; kk < 2; ++kk)
        acc[n] = __builtin_amdgcn_mfma_f32_16x16x32_bf16(aF[kk], bF[n][kk], acc[n], 0, 0, 0);
    raC = raN; rbC = rbN;
  }
  __syncthreads();

  ushort* Cs = smem;
#pragma unroll
  for (int n = 0; n < 2; ++n)
#pragma unroll
    for (int j = 0; j < 4; ++j) {
      int rl = wr * 16 + lg * 4 + j;
      int col = wc * 32 + n * 16 + l15;
      float v = acc[n][j] + (y == 0 ? fc_b[col] : 0.f);
      Cs[rl * 64 + col] = rne_bf16(v);
    }
  __syncthreads();

  if (y == 1) {
    int r = tid >> 3, s = tid & 7;
    int gr = row0 + r;
    float ps = 0.f, pd = 0.f;
#pragma unroll
    for (int i = 0; i < 8; ++i) {
      int col = s * 8 + i;
      float v = bf1(Cs[r * 64 + col]);
      ps += v * att_s2[col];
      pd += v * att_d2[col];
    }
    ps += __shfl_xor(ps, 1, 64); pd += __shfl_xor(pd, 1, 64);
    ps += __shfl_xor(ps, 2, 64); pd += __shfl_xor(pd, 2, 64);
    ps += __shfl_xor(ps, 4, 64); pd += __shfl_xor(pd, 4, 64);
    if (s == 0 && gr < M) { a_s[gr] = ps; a_d[gr] = pd; }
  }

  {
    int row = tid >> 3, c16 = tid & 7;
    int gr = row0 + row;
    if (gr < M)
      *(uint4*)&out[(size_t)gr * 64 + c16 * 8] = *(const uint4*)&Cs[row * 64 + c16 * 8];
  }
}

// ---- aggregation: 16-edge batches, cooperative weights + shfl broadcast ----
__global__ __launch_bounds__(256) void aggr1_k(const uint* __restrict__ h1u,
                                               const uint* __restrict__ xresu,
                                               const float* __restrict__ a_s,
                                               const float* __restrict__ a_d,
                                               const int* __restrict__ off,
                                               const int* __restrict__ csr,
                                               const float* __restrict__ b1,
                                               uint* __restrict__ hpre_bf, int n) {
  int w = threadIdx.x >> 6, l = threadIdx.x & 63;
  int d = blockIdx.x * 4 + w;
  if (d >= n) return;
  int h = l >> 4, c = l * 2;
  int le = l & 15, hb = l & 48;
  float adh = a_d[d * 4 + h];
  float ws = __expf(lrelu(a_s[d * 4 + h] + adh));   // self loop
  uint pd = h1u[(size_t)d * 64 + l];
  float lsum = ws, accx = ws * bf16_lo(pd), accy = ws * bf16_hi(pd);

  int s0 = off[d], s1 = off[d + 1];
  for (int p = s0; p < s1; p += 16) {
    int jp = p + le;
    bool valid = jp < s1;
    int jc = valid ? jp : s1 - 1;
    int idxv = csr[jc];
    float wv = valid ? __expf(lrelu(a_s[idxv * 4 + h] + adh)) : 0.f;
    float wi[16]; int sv[16];
#pragma unroll
    for (int i = 0; i < 16; ++i) {
      wi[i] = __shfl(wv, hb + i, 64);
      sv[i] = __shfl(idxv, i, 64);
    }
#pragma unroll
    for (int i = 0; i < 16; ++i) {
      uint q = h1u[(size_t)sv[i] * 64 + l];
      lsum += wi[i];
      accx += wi[i] * bf16_lo(q);
      accy += wi[i] * bf16_hi(q);
    }
  }
  float inv = 1.f / (lsum + 1e-16f);
  uint xr = xresu[(size_t)d * 64 + l];
  float vx = accx * inv + b1[c] + bf16_lo(xr);
  float vy = accy * inv + b1[c + 1] + bf16_hi(xr);
  hpre_bf[(size_t)d * 64 + l] = (uint)rne_bf16(vx) | ((uint)rne_bf16(vy) << 16);
}

__global__ __launch_bounds__(256) void aggr2_k(const ushort* __restrict__ h2b,
                                               const ushort* __restrict__ hresb,
                                               const float* __restrict__ a_s,
                                               const float* __restrict__ a_d,
                                               const int* __restrict__ off,
                                               const int* __restrict__ csr,
                                               const float* __restrict__ b2,
                                               float* __restrict__ out, int n) {
  int w = threadIdx.x >> 6, l = threadIdx.x & 63;
  int d = blockIdx.x * 4 + w;
  if (d >= n) return;
  int le = l & 15;
  float adh = a_d[d];
  float ws = __expf(lrelu(a_s[d] + adh));
  float lsum = ws;
  float acc = ws * bf1(h2b[(size_t)d * 64 + l]);

  int s0 = off[d], s1 = off[d + 1];
  for (int p = s0; p < s1; p += 16) {
    int jp = p + le;
    bool valid = jp < s1;
    int jc = valid ? jp : s1 - 1;
    int idxv = csr[jc];
    float wv = valid ? __expf(lrelu(a_s[idxv] + adh)) : 0.f;
    float wi[16]; int sv[16];
#pragma unroll
    for (int i = 0; i < 16; ++i) {
      wi[i] = __shfl(wv, i, 64);
      sv[i] = __shfl(idxv, i, 64);
    }
#pragma unroll
    for (int i = 0; i < 16; ++i) {
      float fv = bf1(h2b[(size_t)sv[i] * 64 + l]);
      lsum += wi[i];
      acc += wi[i] * fv;
    }
  }
  float inv = 1.f / (lsum + 1e-16f);
  float z = acc * inv + b2[l] + bf1(hresb[(size_t)d * 64 + l]);
  out[(size_t)d * 64 + l] = lrelu(z);
}

// ---------------- launch ----------------
extern "C" void kernel_launch(void* const* d_in, const int* in_sizes, int n_in,
                              void* d_out, int out_size, void* d_ws, size_t ws_size,
                              hipStream_t stream) {
  const float* x        = (const float*)d_in[0];
  const int*   ei       = (const int*)d_in[1];
  const float* W1       = (const float*)d_in[2];
  const float* att_src1 = (const float*)d_in[3];
  const float* att_dst1 = (const float*)d_in[4];
  const float* b1       = (const float*)d_in[5];
  const float* W2       = (const float*)d_in[6];
  const float* att_src2 = (const float*)d_in[7];
  const float* att_dst2 = (const float*)d_in[8];
  const float* b2       = (const float*)d_in[9];
  const float* res1_w   = (const float*)d_in[10];
  const float* res1_b   = (const float*)d_in[11];
  const float* fc_w     = (const float*)d_in[12];
  const float* fc_b     = (const float*)d_in[13];
  float* out = (float*)d_out;

  const int N = in_sizes[0] / 256;
  const int E = in_sizes[1] / 2;
  const int nbuck = (N + 127) / 128;
  const int nEB = (E + 4095) / 4096;

  ushort* x_bf   = (ushort*)d_ws;                      // N*256
  ushort* h1bf   = x_bf + (size_t)N * 256;             // N*128
  ushort* xresbf = h1bf + (size_t)N * 128;             // N*128
  float*  as1    = (float*)(xresbf + (size_t)N * 128); // N*4
  float*  ad1    = as1 + (size_t)N * 4;                // N*4
  ushort* Wt1    = (ushort*)(ad1 + (size_t)N * 4);     // 256*256
  ushort* fcT    = Wt1 + 256 * 256;                    // 64*128
  ushort* W2T    = fcT + 64 * 128;                     // 64*128
  int* offp      = (int*)(W2T + 64 * 128);             // N+1
  int* csr       = offp + N + 1;                       // E
  int* bcnt      = csr + E;                            // 512
  int* bbase     = bcnt + 512;                         // 520
  uint2* tmp     = (uint2*)(((uintptr_t)(bbase + 520) + 7) & ~(uintptr_t)7);  // nbuck*BCAP
  // aliases
  uint*   hpre_bf = (uint*)x_bf;
  ushort* h2bf    = h1bf;
  ushort* hresb   = xresbf;
  float*  as2 = as1, *ad2 = ad1;

  const int ngemm = (N + 63) / 64;

  hipMemsetAsync(bcnt, 0, 512 * 4, stream);
  prep_all_k<<<2048, 256, 0, stream>>>(x, x_bf, (long)N * 256 / 8, ei, E, nEB,
                                       bcnt, tmp, nbuck,
                                       W1, res1_w, fc_w, W2, Wt1, fcT, W2T);
  scan_buckets_k<<<1, 512, 0, stream>>>(bcnt, bbase, offp, nbuck, N);

  gemm1_k<<<ngemm, 512, 0, stream>>>(x_bf, Wt1, res1_b, att_src1, att_dst1,
                                     h1bf, xresbf, as1, ad1,
                                     tmp, bcnt, bbase, offp, csr, nbuck, N);

  aggr1_k<<<(N + 3) / 4, 256, 0, stream>>>((const uint*)h1bf, (const uint*)xresbf, as1, ad1,
                                           offp, csr, b1, hpre_bf, N);

  gemm2_k<<<dim3(ngemm, 2), 512, 0, stream>>>(
      (const ushort*)hpre_bf, fcT, fc_b,
      att_src2, att_dst2, hresb, h2bf, as2, ad2, N);

  aggr2_k<<<(N + 3) / 4, 256, 0, stream>>>(h2bf, hresb, as2, ad2, offp, csr, b2, out, N);
}

// Round 10
// 153.674 us; speedup vs baseline: 4.4891x; 1.0203x over previous
//
#include <hip/hip_runtime.h>

typedef __attribute__((ext_vector_type(8))) short short8;
typedef __attribute__((ext_vector_type(4))) float f32x4;

constexpr int BCAP = 4096;   // padded per-bucket capacity in tmp (mean 2048, max ~2300)

__device__ __forceinline__ ushort rne_bf16(float f) {
  uint u = __float_as_uint(f);
  uint r = (u + 0x7FFFu + ((u >> 16) & 1u)) >> 16;
  return (ushort)r;
}
__device__ __forceinline__ float bf16_lo(uint pair) { return __uint_as_float(pair << 16); }
__device__ __forceinline__ float bf16_hi(uint pair) { return __uint_as_float(pair & 0xffff0000u); }
__device__ __forceinline__ float bf1(ushort v) { return __uint_as_float((uint)v << 16); }
__device__ __forceinline__ float lrelu(float a) { return a >= 0.f ? a : 0.2f * a; }

__device__ __forceinline__ uint lrelu_pair(uint pair) {
  float lo = lrelu(bf16_lo(pair));
  float hi = lrelu(bf16_hi(pair));
  return (uint)rne_bf16(lo) | ((uint)rne_bf16(hi) << 16);
}
__device__ __forceinline__ float4 lrelu_bf8(float4 v) {
  uint4 u = *(uint4*)&v;
  u.x = lrelu_pair(u.x); u.y = lrelu_pair(u.y);
  u.z = lrelu_pair(u.z); u.w = lrelu_pair(u.w);
  return *(float4*)&u;
}
__device__ __forceinline__ float4 pack_bf8(float4 a, float4 b) {
  uint u0 = (uint)rne_bf16(a.x) | ((uint)rne_bf16(a.y) << 16);
  uint u1 = (uint)rne_bf16(a.z) | ((uint)rne_bf16(a.w) << 16);
  uint u2 = (uint)rne_bf16(b.x) | ((uint)rne_bf16(b.y) << 16);
  uint u3 = (uint)rne_bf16(b.z) | ((uint)rne_bf16(b.w) << 16);
  uint4 r; r.x = u0; r.y = u1; r.z = u2; r.w = u3;
  return *(float4*)&r;
}

// ---- fused prep: bucket-partition edges (LDS rank) | transpose-cast weights ----
__global__ __launch_bounds__(256) void prep_all_k(
    const int* __restrict__ ei, int E, int nEB,
    int* __restrict__ bcnt, uint2* __restrict__ tmp, int nbuck,
    const float* __restrict__ W1, const float* __restrict__ res1_w,
    const float* __restrict__ fc_w, const float* __restrict__ W2,
    ushort* __restrict__ Wt1, ushort* __restrict__ fcT, ushort* __restrict__ W2T)
{
  __shared__ int lcnt[400];
  __shared__ int gbase[400];
  const int tid = threadIdx.x, bid = blockIdx.x;
  const long gstride = (long)gridDim.x * 256;
  const long g0 = (long)bid * 256 + tid;

  // phase B: blocks [0, nEB) partition 4096 edges each into dst-buckets
  if (bid < nEB) {
    for (int i = tid; i < nbuck; i += 256) lcnt[i] = 0;
    __syncthreads();
    const int ebase = bid * 4096;
    int srcs[16], dsts[16], rk[16];
#pragma unroll
    for (int i = 0; i < 16; ++i) {
      int e = ebase + i * 256 + tid;
      if (e < E) {
        srcs[i] = ei[e];
        dsts[i] = ei[E + e];
        rk[i] = atomicAdd(&lcnt[dsts[i] >> 7], 1);   // LDS atomic
      } else dsts[i] = -1;
    }
    __syncthreads();
    for (int b = tid; b < nbuck; b += 256)
      gbase[b] = lcnt[b] ? atomicAdd(&bcnt[b], lcnt[b]) : 0;
    __syncthreads();
#pragma unroll
    for (int i = 0; i < 16; ++i) {
      if (dsts[i] >= 0) {
        int b = dsts[i] >> 7;
        tmp[(size_t)b * BCAP + gbase[b] + rk[i]] = make_uint2((uint)srcs[i], (uint)dsts[i]);
      }
    }
  }

  // phase C: weight transpose-casts
  for (long gi = g0; gi < 81920; gi += gstride) {
    const float* src; ushort* dst; int K, NO; long local;
    if (gi < 32768)            { src = W1;     dst = Wt1;          K = 256; NO = 128; local = gi; }
    else if (gi < 65536)       { src = res1_w; dst = Wt1 + 32768;  K = 256; NO = 128; local = gi - 32768; }
    else if (gi < 65536+8192)  { src = fc_w;   dst = fcT;          K = 128; NO = 64;  local = gi - 65536; }
    else                       { src = W2;     dst = W2T;          K = 128; NO = 64;  local = gi - 65536 - 8192; }
    int n = (int)(local / K), k = (int)(local % K);
    dst[local] = rne_bf16(src[(size_t)k * NO + n]);
  }
}

// ---- exclusive scan of bucket totals (1 block; nbuck <= 512) ----
__global__ __launch_bounds__(512) void scan_buckets_k(const int* __restrict__ bcnt,
                                                      int* __restrict__ bbase,
                                                      int* __restrict__ offp,
                                                      int nbuck, int N) {
  __shared__ int sh[512];
  int tid = threadIdx.x;
  int v = (tid < nbuck) ? bcnt[tid] : 0;
  sh[tid] = v;
  __syncthreads();
  for (int o = 1; o < 512; o <<= 1) {
    int t = (tid >= o) ? sh[tid - o] : 0;
    __syncthreads();
    sh[tid] += t;
    __syncthreads();
  }
  if (tid < nbuck) bbase[tid] = sh[tid] - v;
  if (tid == nbuck - 1) { bbase[nbuck] = sh[tid]; offp[N] = sh[tid]; }
}

// ---- L1 GEMM (A staged directly from f32 x, inline bf16 pack)
//      + fused att1 + bucket-owned CSR finalize ----
__global__ __launch_bounds__(512) void gemm1_k(
    const float* __restrict__ x, const ushort* __restrict__ Wt1,
    const float* __restrict__ res1_b,
    const float* __restrict__ att_s1, const float* __restrict__ att_d1,
    ushort* __restrict__ h1bf, ushort* __restrict__ xresbf,
    float* __restrict__ a_s, float* __restrict__ a_d,
    const uint2* __restrict__ tmp, const int* __restrict__ bcnt,
    const int* __restrict__ bbase, int* __restrict__ offp,
    int* __restrict__ csr, int nbuck, int M)
{
  constexpr int LDA = 72;
  __shared__ ushort smem[64 * LDA + 256 * LDA];
  const int bid = blockIdx.x, tid = threadIdx.x;
  ushort* As = smem;
  ushort* Bs = smem + 64 * LDA;
  const int w = tid >> 6, l = tid & 63;
  const int wr = w >> 2, wc = w & 3;
  const int l15 = l & 15, lg = l >> 4;
  const int row0 = bid * 64;
  const int srow = tid >> 3, sch = tid & 7;

  int gra = row0 + srow; if (gra >= M) gra = M - 1;
  const float*  Apf = x + (size_t)gra * 256 + sch * 8;
  const ushort* Bp  = Wt1 + (size_t)srow * 256 + sch * 8;

  f32x4 acc[2][4] = {};
  float4 raCa, raCb, rbC0, rbC1, rbC2, rbC3;
  float4 raNa, raNb, rbN0, rbN1, rbN2, rbN3;
  raCa = *(const float4*)(Apf);
  raCb = *(const float4*)(Apf + 4);
  rbC0 = *(const float4*)(Bp);
  rbC1 = *(const float4*)(Bp + 64 * 256);
  rbC2 = *(const float4*)(Bp + 128 * 256);
  rbC3 = *(const float4*)(Bp + 192 * 256);

#pragma unroll
  for (int kt = 0; kt < 4; ++kt) {
    __syncthreads();
    *(float4*)&As[srow * LDA + sch * 8] = pack_bf8(raCa, raCb);
    *(float4*)&Bs[(0 * 64 + srow) * LDA + sch * 8] = rbC0;
    *(float4*)&Bs[(1 * 64 + srow) * LDA + sch * 8] = rbC1;
    *(float4*)&Bs[(2 * 64 + srow) * LDA + sch * 8] = rbC2;
    *(float4*)&Bs[(3 * 64 + srow) * LDA + sch * 8] = rbC3;
    __syncthreads();
    if (kt < 3) {
      int k1 = (kt + 1) * 64;
      raNa = *(const float4*)(Apf + k1);
      raNb = *(const float4*)(Apf + k1 + 4);
      rbN0 = *(const float4*)(Bp + k1);
      rbN1 = *(const float4*)(Bp + 64 * 256 + k1);
      rbN2 = *(const float4*)(Bp + 128 * 256 + k1);
      rbN3 = *(const float4*)(Bp + 192 * 256 + k1);
    }
    short8 aF[2][2], bF[4][2];
#pragma unroll
    for (int m = 0; m < 2; ++m)
#pragma unroll
      for (int kk = 0; kk < 2; ++kk)
        aF[m][kk] = *(const short8*)&As[(wr * 32 + m * 16 + l15) * LDA + kk * 32 + lg * 8];
#pragma unroll
    for (int n = 0; n < 4; ++n)
#pragma unroll
      for (int kk = 0; kk < 2; ++kk)
        bF[n][kk] = *(const short8*)&Bs[(wc * 64 + n * 16 + l15) * LDA + kk * 32 + lg * 8];
#pragma unroll
    for (int m = 0; m < 2; ++m)
#pragma unroll
      for (int n = 0; n < 4; ++n)
#pragma unroll
        for (int kk = 0; kk < 2; ++kk)
          acc[m][n] = __builtin_amdgcn_mfma_f32_16x16x32_bf16(aF[m][kk], bF[n][kk], acc[m][n], 0, 0, 0);
    raCa = raNa; raCb = raNb;
    rbC0 = rbN0; rbC1 = rbN1; rbC2 = rbN2; rbC3 = rbN3;
  }
  __syncthreads();

  ushort* Cs = smem;
#pragma unroll
  for (int m = 0; m < 2; ++m)
#pragma unroll
    for (int n = 0; n < 4; ++n)
#pragma unroll
      for (int j = 0; j < 4; ++j) {
        int rl = wr * 32 + m * 16 + lg * 4 + j;
        int col = wc * 64 + n * 16 + l15;
        float v = acc[m][n][j] + (col >= 128 ? res1_b[col - 128] : 0.f);
        Cs[rl * 256 + col] = rne_bf16(v);
      }
  __syncthreads();

  // fused att1
  {
    int r = tid >> 3, s = tid & 7, h = s >> 1;
    int gr = row0 + r;
    float ps = 0.f, pd = 0.f;
#pragma unroll
    for (int i = 0; i < 16; ++i) {
      int col = s * 16 + i;
      float v = bf1(Cs[r * 256 + col]);
      ps += v * att_s1[h * 32 + (col & 31)];
      pd += v * att_d1[h * 32 + (col & 31)];
    }
    ps += __shfl_xor(ps, 1, 64);
    pd += __shfl_xor(pd, 1, 64);
    if (!(s & 1) && gr < M) { a_s[gr * 4 + h] = ps; a_d[gr * 4 + h] = pd; }
  }

  // coalesced split copy
#pragma unroll
  for (int idx = tid; idx < 2048; idx += 512) {
    int row = idx >> 5, c16 = idx & 31;
    int gr = row0 + row;
    if (gr < M) {
      uint4 v = *(const uint4*)&Cs[row * 256 + c16 * 8];
      if (c16 < 16) *(uint4*)&h1bf[(size_t)gr * 128 + c16 * 8] = v;
      else          *(uint4*)&xresbf[(size_t)gr * 128 + (c16 - 16) * 8] = v;
    }
  }

  // CSR finalize: block bid owns bucket bid — count, scan, write offp + sorted csr
  if (bid < nbuck) {
    __syncthreads();
    int* lcnt = (int*)smem;
    int* excl = lcnt + 128;
    const int vbase = bid * 128;
    const int nloc = ((vbase + 128 < M) ? 128 : M - vbase);
    const int cntb = bcnt[bid];
    const int bbase0 = bbase[bid];
    const uint2* bt = tmp + (size_t)bid * BCAP;
    if (tid < 128) lcnt[tid] = 0;
    __syncthreads();
    for (int e = tid; e < cntb; e += 512)
      atomicAdd(&lcnt[(int)bt[e].y - vbase], 1);
    __syncthreads();
    if (tid < 128) {
      int v = lcnt[tid];
      int sc = v;
#pragma unroll
      for (int o = 1; o < 64; o <<= 1) {
        int t = __shfl_up(sc, o, 64);
        if ((tid & 63) >= o) sc += t;
      }
      excl[tid] = sc - v;
    }
    __syncthreads();
    if (tid >= 64 && tid < 128) excl[tid] += excl[63] + lcnt[63];
    __syncthreads();
    if (tid < nloc) offp[vbase + tid] = bbase0 + excl[tid];
    if (tid < 128) lcnt[tid] = 0;
    __syncthreads();
    for (int e = tid; e < cntb; e += 512) {
      uint2 t = bt[e];
      int li = (int)t.y - vbase;
      int r = atomicAdd(&lcnt[li], 1);
      csr[bbase0 + excl[li] + r] = (int)t.x;
    }
  }
}

// ---- L2 GEMM (y: 0=hres=hpre@fc+b ; 1=h2=lrelu(hpre)@W2) + att2 ----
__global__ __launch_bounds__(512) void gemm2_k(
    const ushort* __restrict__ hpre,
    const ushort* __restrict__ fcT,            // W2T = fcT + 64*128
    const float* __restrict__ fc_b,
    const float* __restrict__ att_s2, const float* __restrict__ att_d2,
    ushort* __restrict__ hresb, ushort* __restrict__ h2bf,
    float* __restrict__ a_s, float* __restrict__ a_d, int M)
{
  constexpr int LDA = 72;
  __shared__ ushort smem[64 * LDA + 64 * LDA];
  const int tid = threadIdx.x, y = blockIdx.y;
  const ushort* B = fcT + (size_t)y * 64 * 128;
  ushort* out = y ? h2bf : hresb;
  const int row0 = blockIdx.x * 64;
  ushort* As = smem;
  ushort* Bs = smem + 64 * LDA;
  const int w = tid >> 6, l = tid & 63;
  const int wr = w >> 1, wc = w & 1;
  const int l15 = l & 15, lg = l >> 4;
  const int srow = tid >> 3, sch = tid & 7;

  int gra = row0 + srow; if (gra >= M) gra = M - 1;
  const ushort* Ap = hpre + (size_t)gra * 128 + sch * 8;
  const ushort* Bp = B + (size_t)srow * 128 + sch * 8;

  f32x4 acc[2] = {};
  float4 raC = *(const float4*)(Ap);
  float4 rbC = *(const float4*)(Bp);
  if (y) raC = lrelu_bf8(raC);
  float4 raN, rbN;

#pragma unroll
  for (int kt = 0; kt < 2; ++kt) {
    __syncthreads();
    *(float4*)&As[srow * LDA + sch * 8] = raC;
    *(float4*)&Bs[srow * LDA + sch * 8] = rbC;
    __syncthreads();
    if (kt < 1) {
      raN = *(const float4*)(Ap + 64);
      rbN = *(const float4*)(Bp + 64);
      if (y) raN = lrelu_bf8(raN);
    }

    short8 aF[2], bF[2][2];
#pragma unroll
    for (int kk = 0; kk < 2; ++kk)
      aF[kk] = *(const short8*)&As[(wr * 16 + l15) * LDA + kk * 32 + lg * 8];
#pragma unroll
    for (int n = 0; n < 2; ++n)
#pragma unroll
      for (int kk = 0; kk < 2; ++kk)
        bF[n][kk] = *(const short8*)&Bs[(wc * 32 + n * 16 + l15) * LDA + kk * 32 + lg * 8];
#pragma unroll
    for (int n = 0; n < 2; ++n)
#pragma unroll
      for (int kk = 0; kk < 2; ++kk)
        acc[n] = __builtin_amdgcn_mfma_f32_16x16x32_bf16(aF[kk], bF[n][kk], acc[n], 0, 0, 0);
    raC = raN; rbC = rbN;
  }
  __syncthreads();

  ushort* Cs = smem;
#pragma unroll
  for (int n = 0; n < 2; ++n)
#pragma unroll
    for (int j = 0; j < 4; ++j) {
      int rl = wr * 16 + lg * 4 + j;
      int col = wc * 32 + n * 16 + l15;
      float v = acc[n][j] + (y == 0 ? fc_b[col] : 0.f);
      Cs[rl * 64 + col] = rne_bf16(v);
    }
  __syncthreads();

  if (y == 1) {
    int r = tid >> 3, s = tid & 7;
    int gr = row0 + r;
    float ps = 0.f, pd = 0.f;
#pragma unroll
    for (int i = 0; i < 8; ++i) {
      int col = s * 8 + i;
      float v = bf1(Cs[r * 64 + col]);
      ps += v * att_s2[col];
      pd += v * att_d2[col];
    }
    ps += __shfl_xor(ps, 1, 64); pd += __shfl_xor(pd, 1, 64);
    ps += __shfl_xor(ps, 2, 64); pd += __shfl_xor(pd, 2, 64);
    ps += __shfl_xor(ps, 4, 64); pd += __shfl_xor(pd, 4, 64);
    if (s == 0 && gr < M) { a_s[gr] = ps; a_d[gr] = pd; }
  }

  {
    int row = tid >> 3, c16 = tid & 7;
    int gr = row0 + row;
    if (gr < M)
      *(uint4*)&out[(size_t)gr * 64 + c16 * 8] = *(const uint4*)&Cs[row * 64 + c16 * 8];
  }
}

// ---- aggregation: full-16 batches + 4-wide masked tail (wave-uniform bounds) ----
__global__ __launch_bounds__(256) void aggr1_k(const uint* __restrict__ h1u,
                                               const uint* __restrict__ xresu,
                                               const float* __restrict__ a_s,
                                               const float* __restrict__ a_d,
                                               const int* __restrict__ off,
                                               const int* __restrict__ csr,
                                               const float* __restrict__ b1,
                                               uint* __restrict__ hpreu, int n) {
  int w = threadIdx.x >> 6, l = threadIdx.x & 63;
  int d = blockIdx.x * 4 + w;
  if (d >= n) return;
  int h = l >> 4, c = l * 2;
  int le = l & 15, hb = l & 48;
  float adh = a_d[d * 4 + h];
  float ws = __expf(lrelu(a_s[d * 4 + h] + adh));   // self loop
  uint pd = h1u[(size_t)d * 64 + l];
  float lsum = ws, accx = ws * bf16_lo(pd), accy = ws * bf16_hi(pd);

  int s0 = off[d], s1 = off[d + 1];
  int p = s0;
  for (; p + 16 <= s1; p += 16) {
    int idxv = csr[p + le];
    float wv = __expf(lrelu(a_s[idxv * 4 + h] + adh));
    float wi[16]; int sv[16];
#pragma unroll
    for (int i = 0; i < 16; ++i) {
      wi[i] = __shfl(wv, hb + i, 64);
      sv[i] = __shfl(idxv, i, 64);
    }
#pragma unroll
    for (int i = 0; i < 16; ++i) {
      uint q = h1u[(size_t)sv[i] * 64 + l];
      lsum += wi[i];
      accx += wi[i] * bf16_lo(q);
      accy += wi[i] * bf16_hi(q);
    }
  }
  if (p < s1) {                       // tail: 1..15 edges
    int rem = s1 - p;                 // wave-uniform
    int jp = p + le;
    bool valid = jp < s1;
    int jc = valid ? jp : s1 - 1;
    int idxv = csr[jc];
    float wv = valid ? __expf(lrelu(a_s[idxv * 4 + h] + adh)) : 0.f;
    for (int i = 0; i < rem; i += 4) {
#pragma unroll
      for (int j = 0; j < 4; ++j) {
        float wib = __shfl(wv, hb + i + j, 64);
        int svb = __shfl(idxv, i + j, 64);
        uint q = h1u[(size_t)svb * 64 + l];
        lsum += wib;
        accx += wib * bf16_lo(q);
        accy += wib * bf16_hi(q);
      }
    }
  }
  float inv = 1.f / (lsum + 1e-16f);
  uint xr = xresu[(size_t)d * 64 + l];
  float vx = accx * inv + b1[c] + bf16_lo(xr);
  float vy = accy * inv + b1[c + 1] + bf16_hi(xr);
  hpreu[(size_t)d * 64 + l] = (uint)rne_bf16(vx) | ((uint)rne_bf16(vy) << 16);
}

__global__ __launch_bounds__(256) void aggr2_k(const ushort* __restrict__ h2b,
                                               const ushort* __restrict__ hresb,
                                               const float* __restrict__ a_s,
                                               const float* __restrict__ a_d,
                                               const int* __restrict__ off,
                                               const int* __restrict__ csr,
                                               const float* __restrict__ b2,
                                               float* __restrict__ out, int n) {
  int w = threadIdx.x >> 6, l = threadIdx.x & 63;
  int d = blockIdx.x * 4 + w;
  if (d >= n) return;
  int le = l & 15;
  float adh = a_d[d];
  float ws = __expf(lrelu(a_s[d] + adh));
  float lsum = ws;
  float acc = ws * bf1(h2b[(size_t)d * 64 + l]);

  int s0 = off[d], s1 = off[d + 1];
  int p = s0;
  for (; p + 16 <= s1; p += 16) {
    int idxv = csr[p + le];
    float wv = __expf(lrelu(a_s[idxv] + adh));
    float wi[16]; int sv[16];
#pragma unroll
    for (int i = 0; i < 16; ++i) {
      wi[i] = __shfl(wv, i, 64);
      sv[i] = __shfl(idxv, i, 64);
    }
#pragma unroll
    for (int i = 0; i < 16; ++i) {
      float fv = bf1(h2b[(size_t)sv[i] * 64 + l]);
      lsum += wi[i];
      acc += wi[i] * fv;
    }
  }
  if (p < s1) {
    int rem = s1 - p;
    int jp = p + le;
    bool valid = jp < s1;
    int jc = valid ? jp : s1 - 1;
    int idxv = csr[jc];
    float wv = valid ? __expf(lrelu(a_s[idxv] + adh)) : 0.f;
    for (int i = 0; i < rem; i += 4) {
#pragma unroll
      for (int j = 0; j < 4; ++j) {
        float wib = __shfl(wv, i + j, 64);
        int svb = __shfl(idxv, i + j, 64);
        float fv = bf1(h2b[(size_t)svb * 64 + l]);
        lsum += wib;
        acc += wib * fv;
      }
    }
  }
  float inv = 1.f / (lsum + 1e-16f);
  float z = acc * inv + b2[l] + bf1(hresb[(size_t)d * 64 + l]);
  out[(size_t)d * 64 + l] = lrelu(z);
}

// ---------------- launch ----------------
extern "C" void kernel_launch(void* const* d_in, const int* in_sizes, int n_in,
                              void* d_out, int out_size, void* d_ws, size_t ws_size,
                              hipStream_t stream) {
  const float* x        = (const float*)d_in[0];
  const int*   ei       = (const int*)d_in[1];
  const float* W1       = (const float*)d_in[2];
  const float* att_src1 = (const float*)d_in[3];
  const float* att_dst1 = (const float*)d_in[4];
  const float* b1       = (const float*)d_in[5];
  const float* W2       = (const float*)d_in[6];
  const float* att_src2 = (const float*)d_in[7];
  const float* att_dst2 = (const float*)d_in[8];
  const float* b2       = (const float*)d_in[9];
  const float* res1_w   = (const float*)d_in[10];
  const float* res1_b   = (const float*)d_in[11];
  const float* fc_w     = (const float*)d_in[12];
  const float* fc_b     = (const float*)d_in[13];
  float* out = (float*)d_out;

  const int N = in_sizes[0] / 256;
  const int E = in_sizes[1] / 2;
  const int nbuck = (N + 127) / 128;
  const int nEB = (E + 4095) / 4096;

  ushort* h1bf   = (ushort*)d_ws;                      // N*128
  ushort* xresbf = h1bf + (size_t)N * 128;             // N*128
  uint*   hpreu  = (uint*)(xresbf + (size_t)N * 128);  // N*64 uints
  float*  as1    = (float*)(hpreu + (size_t)N * 64);   // N*4
  float*  ad1    = as1 + (size_t)N * 4;                // N*4
  ushort* Wt1    = (ushort*)(ad1 + (size_t)N * 4);     // 256*256
  ushort* fcT    = Wt1 + 256 * 256;                    // 64*128
  ushort* W2T    = fcT + 64 * 128;                     // 64*128
  int* offp      = (int*)(W2T + 64 * 128);             // N+1
  int* csr       = offp + N + 1;                       // E
  int* bcnt      = csr + E;                            // 512
  int* bbase     = bcnt + 512;                         // 520
  uint2* tmp     = (uint2*)(((uintptr_t)(bbase + 520) + 7) & ~(uintptr_t)7);  // nbuck*BCAP
  // aliases (safe: producers launch after consumers of the original finish)
  ushort* h2bf   = h1bf;
  ushort* hresb  = xresbf;
  float*  as2 = as1, *ad2 = ad1;

  const int ngemm = (N + 63) / 64;

  hipMemsetAsync(bcnt, 0, 512 * 4, stream);
  prep_all_k<<<nEB, 256, 0, stream>>>(ei, E, nEB, bcnt, tmp, nbuck,
                                      W1, res1_w, fc_w, W2, Wt1, fcT, W2T);
  scan_buckets_k<<<1, 512, 0, stream>>>(bcnt, bbase, offp, nbuck, N);

  gemm1_k<<<ngemm, 512, 0, stream>>>(x, Wt1, res1_b, att_src1, att_dst1,
                                     h1bf, xresbf, as1, ad1,
                                     tmp, bcnt, bbase, offp, csr, nbuck, N);

  aggr1_k<<<(N + 3) / 4, 256, 0, stream>>>((const uint*)h1bf, (const uint*)xresbf, as1, ad1,
                                           offp, csr, b1, hpreu, N);

  gemm2_k<<<dim3(ngemm, 2), 512, 0, stream>>>(
      (const ushort*)hpreu, fcT, fc_b,
      att_src2, att_dst2, hresb, h2bf, as2, ad2, N);

  aggr2_k<<<(N + 3) / 4, 256, 0, stream>>>(h2bf, hresb, as2, ad2, offp, csr, b2, out, N);
}

// Round 11
// 149.330 us; speedup vs baseline: 4.6196x; 1.0291x over previous
//
#include <hip/hip_runtime.h>

typedef __attribute__((ext_vector_type(8))) short short8;
typedef __attribute__((ext_vector_type(4))) float f32x4;

constexpr int BCAP = 4096;   // padded per-bucket capacity in tmp (mean 2048, max ~2300)

__device__ __forceinline__ ushort rne_bf16(float f) {
  uint u = __float_as_uint(f);
  uint r = (u + 0x7FFFu + ((u >> 16) & 1u)) >> 16;
  return (ushort)r;
}
__device__ __forceinline__ float bf16_lo(uint pair) { return __uint_as_float(pair << 16); }
__device__ __forceinline__ float bf16_hi(uint pair) { return __uint_as_float(pair & 0xffff0000u); }
__device__ __forceinline__ float bf1(ushort v) { return __uint_as_float((uint)v << 16); }
__device__ __forceinline__ float lrelu(float a) { return a >= 0.f ? a : 0.2f * a; }

__device__ __forceinline__ uint lrelu_pair(uint pair) {
  float lo = lrelu(bf16_lo(pair));
  float hi = lrelu(bf16_hi(pair));
  return (uint)rne_bf16(lo) | ((uint)rne_bf16(hi) << 16);
}
__device__ __forceinline__ float4 lrelu_bf8(float4 v) {
  uint4 u = *(uint4*)&v;
  u.x = lrelu_pair(u.x); u.y = lrelu_pair(u.y);
  u.z = lrelu_pair(u.z); u.w = lrelu_pair(u.w);
  return *(float4*)&u;
}
__device__ __forceinline__ float4 pack_bf8(float4 a, float4 b) {
  uint u0 = (uint)rne_bf16(a.x) | ((uint)rne_bf16(a.y) << 16);
  uint u1 = (uint)rne_bf16(a.z) | ((uint)rne_bf16(a.w) << 16);
  uint u2 = (uint)rne_bf16(b.x) | ((uint)rne_bf16(b.y) << 16);
  uint u3 = (uint)rne_bf16(b.z) | ((uint)rne_bf16(b.w) << 16);
  uint4 r; r.x = u0; r.y = u1; r.z = u2; r.w = u3;
  return *(float4*)&r;
}

// ---- fused prep: bucket-partition edges (LDS rank) | transpose-cast weights ----
__global__ __launch_bounds__(256) void prep_all_k(
    const int* __restrict__ ei, int E, int nEB,
    int* __restrict__ bcnt, uint2* __restrict__ tmp, int nbuck,
    const float* __restrict__ W1, const float* __restrict__ res1_w,
    const float* __restrict__ fc_w, const float* __restrict__ W2,
    ushort* __restrict__ Wt1, ushort* __restrict__ fcT, ushort* __restrict__ W2T)
{
  __shared__ int lcnt[400];
  __shared__ int gbase[400];
  const int tid = threadIdx.x, bid = blockIdx.x;
  const long gstride = (long)gridDim.x * 256;
  const long g0 = (long)bid * 256 + tid;

  if (bid < nEB) {
    for (int i = tid; i < nbuck; i += 256) lcnt[i] = 0;
    __syncthreads();
    const int ebase = bid * 4096;
    int srcs[16], dsts[16], rk[16];
#pragma unroll
    for (int i = 0; i < 16; ++i) {
      int e = ebase + i * 256 + tid;
      if (e < E) {
        srcs[i] = ei[e];
        dsts[i] = ei[E + e];
        rk[i] = atomicAdd(&lcnt[dsts[i] >> 7], 1);   // LDS atomic
      } else dsts[i] = -1;
    }
    __syncthreads();
    for (int b = tid; b < nbuck; b += 256)
      gbase[b] = lcnt[b] ? atomicAdd(&bcnt[b], lcnt[b]) : 0;
    __syncthreads();
#pragma unroll
    for (int i = 0; i < 16; ++i) {
      if (dsts[i] >= 0) {
        int b = dsts[i] >> 7;
        tmp[(size_t)b * BCAP + gbase[b] + rk[i]] = make_uint2((uint)srcs[i], (uint)dsts[i]);
      }
    }
  }

  for (long gi = g0; gi < 81920; gi += gstride) {
    const float* src; ushort* dst; int K, NO; long local;
    if (gi < 32768)            { src = W1;     dst = Wt1;          K = 256; NO = 128; local = gi; }
    else if (gi < 65536)       { src = res1_w; dst = Wt1 + 32768;  K = 256; NO = 128; local = gi - 32768; }
    else if (gi < 65536+8192)  { src = fc_w;   dst = fcT;          K = 128; NO = 64;  local = gi - 65536; }
    else                       { src = W2;     dst = W2T;          K = 128; NO = 64;  local = gi - 65536 - 8192; }
    int n = (int)(local / K), k = (int)(local % K);
    dst[local] = rne_bf16(src[(size_t)k * NO + n]);
  }
}

// ---- exclusive scan of bucket totals (1 block; nbuck <= 512) ----
__global__ __launch_bounds__(512) void scan_buckets_k(const int* __restrict__ bcnt,
                                                      int* __restrict__ bbase,
                                                      int* __restrict__ offp,
                                                      int nbuck, int N) {
  __shared__ int sh[512];
  int tid = threadIdx.x;
  int v = (tid < nbuck) ? bcnt[tid] : 0;
  sh[tid] = v;
  __syncthreads();
  for (int o = 1; o < 512; o <<= 1) {
    int t = (tid >= o) ? sh[tid - o] : 0;
    __syncthreads();
    sh[tid] += t;
    __syncthreads();
  }
  if (tid < nbuck) bbase[tid] = sh[tid] - v;
  if (tid == nbuck - 1) { bbase[nbuck] = sh[tid]; offp[N] = sh[tid]; }
}

// ---- L1 GEMM: BM=64, BN=128 (y picks W1|res1 half), 512thr, 27.6 KB LDS
//      y=0: h1 + fused att1 ; y=1: xres + bias + CSR finalize ----
__global__ __launch_bounds__(512) void gemm1_k(
    const float* __restrict__ x, const ushort* __restrict__ Wt1,
    const float* __restrict__ res1_b,
    const float* __restrict__ att_s1, const float* __restrict__ att_d1,
    ushort* __restrict__ h1bf, ushort* __restrict__ xresbf,
    float* __restrict__ a_s, float* __restrict__ a_d,
    const uint2* __restrict__ tmp, const int* __restrict__ bcnt,
    const int* __restrict__ bbase, int* __restrict__ offp,
    int* __restrict__ csr, int nbuck, int M)
{
  constexpr int LDA = 72;
  __shared__ ushort smem[64 * LDA + 128 * LDA];   // 27648 B
  const int bid = blockIdx.x, y = blockIdx.y, tid = threadIdx.x;
  ushort* As = smem;
  ushort* Bs = smem + 64 * LDA;
  const int w = tid >> 6, l = tid & 63;
  const int wr = w >> 2, wc = w & 3;              // 2x4 waves: 32-row x 32-col tiles
  const int l15 = l & 15, lg = l >> 4;
  const int row0 = bid * 64;
  const int srow = tid >> 3, sch = tid & 7;

  int gra = row0 + srow; if (gra >= M) gra = M - 1;
  const float*  Apf = x + (size_t)gra * 256 + sch * 8;
  const ushort* Bp  = Wt1 + ((size_t)y * 128 + srow) * 256 + sch * 8;

  f32x4 acc[2][2] = {};
  float4 raCa, raCb, rbC0, rbC1, raNa, raNb, rbN0, rbN1;
  raCa = *(const float4*)(Apf);
  raCb = *(const float4*)(Apf + 4);
  rbC0 = *(const float4*)(Bp);
  rbC1 = *(const float4*)(Bp + 64 * 256);

#pragma unroll
  for (int kt = 0; kt < 4; ++kt) {
    __syncthreads();
    *(float4*)&As[srow * LDA + sch * 8] = pack_bf8(raCa, raCb);
    *(float4*)&Bs[srow * LDA + sch * 8] = rbC0;
    *(float4*)&Bs[(64 + srow) * LDA + sch * 8] = rbC1;
    __syncthreads();
    if (kt < 3) {
      int k1 = (kt + 1) * 64;
      raNa = *(const float4*)(Apf + k1);
      raNb = *(const float4*)(Apf + k1 + 4);
      rbN0 = *(const float4*)(Bp + k1);
      rbN1 = *(const float4*)(Bp + 64 * 256 + k1);
    }
    short8 aF[2][2], bF[2][2];
#pragma unroll
    for (int m = 0; m < 2; ++m)
#pragma unroll
      for (int kk = 0; kk < 2; ++kk)
        aF[m][kk] = *(const short8*)&As[(wr * 32 + m * 16 + l15) * LDA + kk * 32 + lg * 8];
#pragma unroll
    for (int n = 0; n < 2; ++n)
#pragma unroll
      for (int kk = 0; kk < 2; ++kk)
        bF[n][kk] = *(const short8*)&Bs[(wc * 32 + n * 16 + l15) * LDA + kk * 32 + lg * 8];
#pragma unroll
    for (int m = 0; m < 2; ++m)
#pragma unroll
      for (int n = 0; n < 2; ++n)
#pragma unroll
        for (int kk = 0; kk < 2; ++kk)
          acc[m][n] = __builtin_amdgcn_mfma_f32_16x16x32_bf16(aF[m][kk], bF[n][kk], acc[m][n], 0, 0, 0);
    raCa = raNa; raCb = raNb; rbC0 = rbN0; rbC1 = rbN1;
  }
  __syncthreads();

  // stage C tile (64 x 128 bf16) in LDS
  ushort* Cs = smem;
#pragma unroll
  for (int m = 0; m < 2; ++m)
#pragma unroll
    for (int n = 0; n < 2; ++n)
#pragma unroll
      for (int j = 0; j < 4; ++j) {
        int rl = wr * 32 + m * 16 + lg * 4 + j;
        int col = wc * 32 + n * 16 + l15;
        float v = acc[m][n][j] + (y ? res1_b[col] : 0.f);
        Cs[rl * 128 + col] = rne_bf16(v);
      }
  __syncthreads();

  if (y == 0) {
    // fused att1: thread t -> row t>>3, seg t&7 (16 cols); head = seg>>1
    int r = tid >> 3, s = tid & 7, h = s >> 1;
    int gr = row0 + r;
    float ps = 0.f, pd = 0.f;
#pragma unroll
    for (int i = 0; i < 16; ++i) {
      int col = s * 16 + i;
      float v = bf1(Cs[r * 128 + col]);
      ps += v * att_s1[h * 32 + (col & 31)];
      pd += v * att_d1[h * 32 + (col & 31)];
    }
    ps += __shfl_xor(ps, 1, 64);
    pd += __shfl_xor(pd, 1, 64);
    if (!(s & 1) && gr < M) { a_s[gr * 4 + h] = ps; a_d[gr * 4 + h] = pd; }
  }

  // coalesced copy: 64 x 128 bf16 = 1024 uint4
  {
    ushort* out = y ? xresbf : h1bf;
#pragma unroll
    for (int idx = tid; idx < 1024; idx += 512) {
      int row = idx >> 4, c16 = idx & 15;
      int gr = row0 + row;
      if (gr < M)
        *(uint4*)&out[(size_t)gr * 128 + c16 * 8] = *(const uint4*)&Cs[row * 128 + c16 * 8];
    }
  }

  // CSR finalize on y=1 blocks (y=0 did att1): block bid owns bucket bid
  if (y == 1 && bid < nbuck) {
    __syncthreads();
    int* lcnt = (int*)smem;
    int* excl = lcnt + 128;
    const int vbase = bid * 128;
    const int nloc = ((vbase + 128 < M) ? 128 : M - vbase);
    const int cntb = bcnt[bid];
    const int bbase0 = bbase[bid];
    const uint2* bt = tmp + (size_t)bid * BCAP;
    if (tid < 128) lcnt[tid] = 0;
    __syncthreads();
    for (int e = tid; e < cntb; e += 512)
      atomicAdd(&lcnt[(int)bt[e].y - vbase], 1);
    __syncthreads();
    if (tid < 128) {
      int v = lcnt[tid];
      int sc = v;
#pragma unroll
      for (int o = 1; o < 64; o <<= 1) {
        int t = __shfl_up(sc, o, 64);
        if ((tid & 63) >= o) sc += t;
      }
      excl[tid] = sc - v;
    }
    __syncthreads();
    if (tid >= 64 && tid < 128) excl[tid] += excl[63] + lcnt[63];
    __syncthreads();
    if (tid < nloc) offp[vbase + tid] = bbase0 + excl[tid];
    if (tid < 128) lcnt[tid] = 0;
    __syncthreads();
    for (int e = tid; e < cntb; e += 512) {
      uint2 t = bt[e];
      int li = (int)t.y - vbase;
      int r = atomicAdd(&lcnt[li], 1);
      csr[bbase0 + excl[li] + r] = (int)t.x;
    }
  }
}

// ---- L2 GEMM (y: 0=hres=hpre@fc+b ; 1=h2=lrelu(hpre)@W2) + att2 ----
__global__ __launch_bounds__(512) void gemm2_k(
    const ushort* __restrict__ hpre,
    const ushort* __restrict__ fcT,            // W2T = fcT + 64*128
    const float* __restrict__ fc_b,
    const float* __restrict__ att_s2, const float* __restrict__ att_d2,
    ushort* __restrict__ hresb, ushort* __restrict__ h2bf,
    float* __restrict__ a_s, float* __restrict__ a_d, int M)
{
  constexpr int LDA = 72;
  __shared__ ushort smem[64 * LDA + 64 * LDA];
  const int tid = threadIdx.x, y = blockIdx.y;
  const ushort* B = fcT + (size_t)y * 64 * 128;
  ushort* out = y ? h2bf : hresb;
  const int row0 = blockIdx.x * 64;
  ushort* As = smem;
  ushort* Bs = smem + 64 * LDA;
  const int w = tid >> 6, l = tid & 63;
  const int wr = w >> 1, wc = w & 1;
  const int l15 = l & 15, lg = l >> 4;
  const int srow = tid >> 3, sch = tid & 7;

  int gra = row0 + srow; if (gra >= M) gra = M - 1;
  const ushort* Ap = hpre + (size_t)gra * 128 + sch * 8;
  const ushort* Bp = B + (size_t)srow * 128 + sch * 8;

  f32x4 acc[2] = {};
  float4 raC = *(const float4*)(Ap);
  float4 rbC = *(const float4*)(Bp);
  if (y) raC = lrelu_bf8(raC);
  float4 raN, rbN;

#pragma unroll
  for (int kt = 0; kt < 2; ++kt) {
    __syncthreads();
    *(float4*)&As[srow * LDA + sch * 8] = raC;
    *(float4*)&Bs[srow * LDA + sch * 8] = rbC;
    __syncthreads();
    if (kt < 1) {
      raN = *(const float4*)(Ap + 64);
      rbN = *(const float4*)(Bp + 64);
      if (y) raN = lrelu_bf8(raN);
    }

    short8 aF[2], bF[2][2];
#pragma unroll
    for (int kk = 0; kk < 2; ++kk)
      aF[kk] = *(const short8*)&As[(wr * 16 + l15) * LDA + kk * 32 + lg * 8];
#pragma unroll
    for (int n = 0; n < 2; ++n)
#pragma unroll
      for (int kk = 0; kk < 2; ++kk)
        bF[n][kk] = *(const short8*)&Bs[(wc * 32 + n * 16 + l15) * LDA + kk * 32 + lg * 8];
#pragma unroll
    for (int n = 0; n < 2; ++n)
#pragma unroll
      for (int kk = 0; kk < 2; ++kk)
        acc[n] = __builtin_amdgcn_mfma_f32_16x16x32_bf16(aF[kk], bF[n][kk], acc[n], 0, 0, 0);
    raC = raN; rbC = rbN;
  }
  __syncthreads();

  ushort* Cs = smem;
#pragma unroll
  for (int n = 0; n < 2; ++n)
#pragma unroll
    for (int j = 0; j < 4; ++j) {
      int rl = wr * 16 + lg * 4 + j;
      int col = wc * 32 + n * 16 + l15;
      float v = acc[n][j] + (y == 0 ? fc_b[col] : 0.f);
      Cs[rl * 64 + col] = rne_bf16(v);
    }
  __syncthreads();

  if (y == 1) {
    int r = tid >> 3, s = tid & 7;
    int gr = row0 + r;
    float ps = 0.f, pd = 0.f;
#pragma unroll
    for (int i = 0; i < 8; ++i) {
      int col = s * 8 + i;
      float v = bf1(Cs[r * 64 + col]);
      ps += v * att_s2[col];
      pd += v * att_d2[col];
    }
    ps += __shfl_xor(ps, 1, 64); pd += __shfl_xor(pd, 1, 64);
    ps += __shfl_xor(ps, 2, 64); pd += __shfl_xor(pd, 2, 64);
    ps += __shfl_xor(ps, 4, 64); pd += __shfl_xor(pd, 4, 64);
    if (s == 0 && gr < M) { a_s[gr] = ps; a_d[gr] = pd; }
  }

  {
    int row = tid >> 3, c16 = tid & 7;
    int gr = row0 + row;
    if (gr < M)
      *(uint4*)&out[(size_t)gr * 64 + c16 * 8] = *(const uint4*)&Cs[row * 64 + c16 * 8];
  }
}

// ---- aggregation: full-16 batches + 4-wide masked tail (wave-uniform bounds) ----
__global__ __launch_bounds__(256) void aggr1_k(const uint* __restrict__ h1u,
                                               const uint* __restrict__ xresu,
                                               const float* __restrict__ a_s,
                                               const float* __restrict__ a_d,
                                               const int* __restrict__ off,
                                               const int* __restrict__ csr,
                                               const float* __restrict__ b1,
                                               uint* __restrict__ hpreu, int n) {
  int w = threadIdx.x >> 6, l = threadIdx.x & 63;
  int d = blockIdx.x * 4 + w;
  if (d >= n) return;
  int h = l >> 4, c = l * 2;
  int le = l & 15, hb = l & 48;
  float adh = a_d[d * 4 + h];
  float ws = __expf(lrelu(a_s[d * 4 + h] + adh));   // self loop
  uint pd = h1u[(size_t)d * 64 + l];
  float lsum = ws, accx = ws * bf16_lo(pd), accy = ws * bf16_hi(pd);

  int s0 = off[d], s1 = off[d + 1];
  int p = s0;
  for (; p + 16 <= s1; p += 16) {
    int idxv = csr[p + le];
    float wv = __expf(lrelu(a_s[idxv * 4 + h] + adh));
    float wi[16]; int sv[16];
#pragma unroll
    for (int i = 0; i < 16; ++i) {
      wi[i] = __shfl(wv, hb + i, 64);
      sv[i] = __shfl(idxv, i, 64);
    }
#pragma unroll
    for (int i = 0; i < 16; ++i) {
      uint q = h1u[(size_t)sv[i] * 64 + l];
      lsum += wi[i];
      accx += wi[i] * bf16_lo(q);
      accy += wi[i] * bf16_hi(q);
    }
  }
  if (p < s1) {
    int rem = s1 - p;
    int jp = p + le;
    bool valid = jp < s1;
    int jc = valid ? jp : s1 - 1;
    int idxv = csr[jc];
    float wv = valid ? __expf(lrelu(a_s[idxv * 4 + h] + adh)) : 0.f;
    for (int i = 0; i < rem; i += 4) {
#pragma unroll
      for (int j = 0; j < 4; ++j) {
        float wib = __shfl(wv, hb + i + j, 64);
        int svb = __shfl(idxv, i + j, 64);
        uint q = h1u[(size_t)svb * 64 + l];
        lsum += wib;
        accx += wib * bf16_lo(q);
        accy += wib * bf16_hi(q);
      }
    }
  }
  float inv = 1.f / (lsum + 1e-16f);
  uint xr = xresu[(size_t)d * 64 + l];
  float vx = accx * inv + b1[c] + bf16_lo(xr);
  float vy = accy * inv + b1[c + 1] + bf16_hi(xr);
  hpreu[(size_t)d * 64 + l] = (uint)rne_bf16(vx) | ((uint)rne_bf16(vy) << 16);
}

__global__ __launch_bounds__(256) void aggr2_k(const ushort* __restrict__ h2b,
                                               const ushort* __restrict__ hresb,
                                               const float* __restrict__ a_s,
                                               const float* __restrict__ a_d,
                                               const int* __restrict__ off,
                                               const int* __restrict__ csr,
                                               const float* __restrict__ b2,
                                               float* __restrict__ out, int n) {
  int w = threadIdx.x >> 6, l = threadIdx.x & 63;
  int d = blockIdx.x * 4 + w;
  if (d >= n) return;
  int le = l & 15;
  float adh = a_d[d];
  float ws = __expf(lrelu(a_s[d] + adh));
  float lsum = ws;
  float acc = ws * bf1(h2b[(size_t)d * 64 + l]);

  int s0 = off[d], s1 = off[d + 1];
  int p = s0;
  for (; p + 16 <= s1; p += 16) {
    int idxv = csr[p + le];
    float wv = __expf(lrelu(a_s[idxv] + adh));
    float wi[16]; int sv[16];
#pragma unroll
    for (int i = 0; i < 16; ++i) {
      wi[i] = __shfl(wv, i, 64);
      sv[i] = __shfl(idxv, i, 64);
    }
#pragma unroll
    for (int i = 0; i < 16; ++i) {
      float fv = bf1(h2b[(size_t)sv[i] * 64 + l]);
      lsum += wi[i];
      acc += wi[i] * fv;
    }
  }
  if (p < s1) {
    int rem = s1 - p;
    int jp = p + le;
    bool valid = jp < s1;
    int jc = valid ? jp : s1 - 1;
    int idxv = csr[jc];
    float wv = valid ? __expf(lrelu(a_s[idxv] + adh)) : 0.f;
    for (int i = 0; i < rem; i += 4) {
#pragma unroll
      for (int j = 0; j < 4; ++j) {
        float wib = __shfl(wv, i + j, 64);
        int svb = __shfl(idxv, i + j, 64);
        float fv = bf1(h2b[(size_t)svb * 64 + l]);
        lsum += wib;
        acc += wib * fv;
      }
    }
  }
  float inv = 1.f / (lsum + 1e-16f);
  float z = acc * inv + b2[l] + bf1(hresb[(size_t)d * 64 + l]);
  out[(size_t)d * 64 + l] = lrelu(z);
}

// ---------------- launch ----------------
extern "C" void kernel_launch(void* const* d_in, const int* in_sizes, int n_in,
                              void* d_out, int out_size, void* d_ws, size_t ws_size,
                              hipStream_t stream) {
  const float* x        = (const float*)d_in[0];
  const int*   ei       = (const int*)d_in[1];
  const float* W1       = (const float*)d_in[2];
  const float* att_src1 = (const float*)d_in[3];
  const float* att_dst1 = (const float*)d_in[4];
  const float* b1       = (const float*)d_in[5];
  const float* W2       = (const float*)d_in[6];
  const float* att_src2 = (const float*)d_in[7];
  const float* att_dst2 = (const float*)d_in[8];
  const float* b2       = (const float*)d_in[9];
  const float* res1_w   = (const float*)d_in[10];
  const float* res1_b   = (const float*)d_in[11];
  const float* fc_w     = (const float*)d_in[12];
  const float* fc_b     = (const float*)d_in[13];
  float* out = (float*)d_out;

  const int N = in_sizes[0] / 256;
  const int E = in_sizes[1] / 2;
  const int nbuck = (N + 127) / 128;
  const int nEB = (E + 4095) / 4096;

  ushort* h1bf   = (ushort*)d_ws;                      // N*128
  ushort* xresbf = h1bf + (size_t)N * 128;             // N*128
  uint*   hpreu  = (uint*)(xresbf + (size_t)N * 128);  // N*64 uints
  float*  as1    = (float*)(hpreu + (size_t)N * 64);   // N*4
  float*  ad1    = as1 + (size_t)N * 4;                // N*4
  ushort* Wt1    = (ushort*)(ad1 + (size_t)N * 4);     // 256*256
  ushort* fcT    = Wt1 + 256 * 256;                    // 64*128
  ushort* W2T    = fcT + 64 * 128;                     // 64*128
  int* offp      = (int*)(W2T + 64 * 128);             // N+1
  int* csr       = offp + N + 1;                       // E
  int* bcnt      = csr + E;                            // 512
  int* bbase     = bcnt + 512;                         // 520
  uint2* tmp     = (uint2*)(((uintptr_t)(bbase + 520) + 7) & ~(uintptr_t)7);  // nbuck*BCAP
  // aliases
  ushort* h2bf   = h1bf;
  ushort* hresb  = xresbf;
  float*  as2 = as1, *ad2 = ad1;

  const int ngemm = (N + 63) / 64;

  hipMemsetAsync(bcnt, 0, 512 * 4, stream);
  prep_all_k<<<nEB, 256, 0, stream>>>(ei, E, nEB, bcnt, tmp, nbuck,
                                      W1, res1_w, fc_w, W2, Wt1, fcT, W2T);
  scan_buckets_k<<<1, 512, 0, stream>>>(bcnt, bbase, offp, nbuck, N);

  gemm1_k<<<dim3(ngemm, 2), 512, 0, stream>>>(x, Wt1, res1_b, att_src1, att_dst1,
                                              h1bf, xresbf, as1, ad1,
                                              tmp, bcnt, bbase, offp, csr, nbuck, N);

  aggr1_k<<<(N + 3) / 4, 256, 0, stream>>>((const uint*)h1bf, (const uint*)xresbf, as1, ad1,
                                           offp, csr, b1, hpreu, N);

  gemm2_k<<<dim3(ngemm, 2), 512, 0, stream>>>(
      (const ushort*)hpreu, fcT, fc_b,
      att_src2, att_dst2, hresb, h2bf, as2, ad2, N);

  aggr2_k<<<(N + 3) / 4, 256, 0, stream>>>(h2bf, hresb, as2, ad2, offp, csr, b2, out, N);
}